// Round 8
// baseline (345.664 us; speedup 1.0000x reference)
//
#include <hip/hip_runtime.h>

#define D 256
#define SCAN_THREADS 1024
#define CAP 32
#define MAXOVF 4096
#define BM 64

typedef float f32x4 __attribute__((ext_vector_type(4)));
typedef short s16x8 __attribute__((ext_vector_type(8)));

__device__ inline unsigned int f2bf(float x) {
    unsigned int u = __float_as_uint(x);
    return (u + 0x7FFFu + ((u >> 16) & 1u)) >> 16;  // RNE, low 16 bits valid
}
__device__ inline float bflo(unsigned int u) { return __uint_as_float(u << 16); }
__device__ inline float bfhi(unsigned int u) { return __uint_as_float(u & 0xFFFF0000u); }

// ================= small utility kernels =================

__global__ void k_zero(int* __restrict__ p, int n) {
    int i = blockIdx.x * blockDim.x + threadIdx.x;
    if (i < n) p[i] = 0;
}

// feat fp32 -> bf16 (packed), 8 elems/thread
__global__ __launch_bounds__(256) void k_f2b(const float* __restrict__ f,
                                             unsigned short* __restrict__ fb, long n8) {
    for (long i = blockIdx.x * 256L + threadIdx.x; i < n8; i += (long)gridDim.x * 256) {
        const float4* p = reinterpret_cast<const float4*>(f + i * 8);
        float4 a = p[0], b = p[1];
        uint4 u;
        u.x = f2bf(a.x) | (f2bf(a.y) << 16);
        u.y = f2bf(a.z) | (f2bf(a.w) << 16);
        u.z = f2bf(b.x) | (f2bf(b.y) << 16);
        u.w = f2bf(b.z) | (f2bf(b.w) << 16);
        reinterpret_cast<uint4*>(fb)[i] = u;
    }
}

// W[k][col] fp32 -> wTs: per-ks staged-B LDS image (8 blocks x 16KB).
__global__ __launch_bounds__(256) void k_wTs(const float* __restrict__ W,
                                             unsigned short* __restrict__ wTs) {
    int col = blockIdx.x;   // 0..255
    int k = threadIdx.x;    // 0..255
    unsigned short v = (unsigned short)f2bf(W[(size_t)k * D + col]);
    int ks = k >> 5;
    int byte = ((col << 6) + (((k >> 3) & 3) << 4) + ((k & 7) << 1)) ^ ((col & 7) << 4);
    *reinterpret_cast<unsigned short*>(
        reinterpret_cast<char*>(wTs) + (size_t)ks * 16384 + byte) = v;
}

// ================= capacity-bucket build =================
// 8 edges per thread: batched loads -> 8 independent atomics -> 8 writes.
// One latency-chain per 8 edges instead of per edge.
__global__ __launch_bounds__(256) void k_fillcap(const int* __restrict__ src,
                                                 const int* __restrict__ dst,
                                                 int* __restrict__ counts,
                                                 int* __restrict__ buckets,
                                                 int* __restrict__ ovf,
                                                 int* __restrict__ ovf_cnt, int E) {
    const long tid = blockIdx.x * 256L + threadIdx.x;
    const long nthreads = (long)gridDim.x * 256;
    const long e8 = E >> 3;
    for (long g = tid; g < e8; g += nthreads) {
        const long base = g * 8;
        int4 s0 = *reinterpret_cast<const int4*>(src + base);
        int4 s1 = *reinterpret_cast<const int4*>(src + base + 4);
        int4 d0 = *reinterpret_cast<const int4*>(dst + base);
        int4 d1 = *reinterpret_cast<const int4*>(dst + base + 4);
        int dd[8] = {d0.x, d0.y, d0.z, d0.w, d1.x, d1.y, d1.z, d1.w};
        int ss[8] = {s0.x, s0.y, s0.z, s0.w, s1.x, s1.y, s1.z, s1.w};
        int pos[8];
        #pragma unroll
        for (int q = 0; q < 8; ++q) pos[q] = atomicAdd(&counts[dd[q]], 1);
        #pragma unroll
        for (int q = 0; q < 8; ++q) {
            if (pos[q] < CAP) {
                buckets[(size_t)dd[q] * CAP + pos[q]] = ss[q];
            } else {
                int o = atomicAdd(ovf_cnt, 1);
                if (o < MAXOVF) {
                    ovf[2 * o + 0] = ss[q];
                    ovf[2 * o + 1] = dd[q];
                }
            }
        }
    }
    // tail
    for (long e = e8 * 8 + tid; e < E; e += nthreads) {
        int d = dst[e];
        int pos = atomicAdd(&counts[d], 1);
        if (pos < CAP) {
            buckets[(size_t)d * CAP + pos] = src[e];
        } else {
            int o = atomicAdd(ovf_cnt, 1);
            if (o < MAXOVF) {
                ovf[2 * o + 0] = src[e];
                ovf[2 * o + 1] = d;
            }
        }
    }
}

// ================= gathers (one wave per node) =================

#define GAT_BODY(LOAD, ACCUM)                                                  \
    int j = 0;                                                                 \
    for (; j + 16 <= cnt; j += 16) {                                           \
        int s[16];                                                             \
        _Pragma("unroll") for (int q = 0; q < 16; ++q) s[q] = bk[j + q];       \
        LOAD(16)                                                               \
        ACCUM(16)                                                              \
    }                                                                          \
    for (; j + 8 <= cnt; j += 8) {                                             \
        int s[8];                                                              \
        _Pragma("unroll") for (int q = 0; q < 8; ++q) s[q] = bk[j + q];        \
        LOAD(8)                                                                \
        ACCUM(8)                                                               \
    }

// Tier A: bf16 feat reads, fp32 accum, swizzled bf16 agg write to ws.
__global__ __launch_bounds__(256) void g_bf_aggb(const unsigned short* __restrict__ fb,
                                                 const int* __restrict__ counts,
                                                 const int* __restrict__ buckets,
                                                 const int* __restrict__ ovf,
                                                 const int* __restrict__ ovf_cnt,
                                                 unsigned short* __restrict__ aggb, int N) {
    int node = (int)((blockIdx.x * (long)blockDim.x + threadIdx.x) >> 6);
    int ln = threadIdx.x & 63;
    if (node >= N) return;
    int cnt_raw = counts[node];
    int cnt = cnt_raw > CAP ? CAP : cnt_raw;
    const int* bk = buckets + (size_t)node * CAP;
    uint2 u = reinterpret_cast<const uint2*>(fb + (size_t)node * D)[ln];
    float4 acc;
    acc.x = bflo(u.x); acc.y = bfhi(u.x); acc.z = bflo(u.y); acc.w = bfhi(u.y);
#define BLOAD(W_)                                                              \
    uint2 v[W_];                                                               \
    _Pragma("unroll") for (int q = 0; q < W_; ++q)                             \
        v[q] = reinterpret_cast<const uint2*>(fb + (size_t)s[q] * D)[ln];
#define BACC(W_)                                                               \
    _Pragma("unroll") for (int q = 0; q < W_; ++q) {                           \
        acc.x += bflo(v[q].x); acc.y += bfhi(v[q].x);                          \
        acc.z += bflo(v[q].y); acc.w += bfhi(v[q].y);                          \
    }
    GAT_BODY(BLOAD, BACC)
    for (; j < cnt; ++j) {
        uint2 v = reinterpret_cast<const uint2*>(fb + (size_t)bk[j] * D)[ln];
        acc.x += bflo(v.x); acc.y += bfhi(v.x);
        acc.z += bflo(v.y); acc.w += bfhi(v.y);
    }
    if (cnt_raw > CAP) {  // astronomically rare; exact cleanup
        int m = *ovf_cnt;
        if (m > MAXOVF) m = MAXOVF;
        for (int e = 0; e < m; ++e) {
            if (ovf[2 * e + 1] == node) {
                uint2 v = reinterpret_cast<const uint2*>(fb + (size_t)ovf[2 * e] * D)[ln];
                acc.x += bflo(v.x); acc.y += bfhi(v.x);
                acc.z += bflo(v.y); acc.w += bfhi(v.y);
            }
        }
    }
    uint2 w;
    w.x = f2bf(acc.x) | (f2bf(acc.y) << 16);
    w.y = f2bf(acc.z) | (f2bf(acc.w) << 16);
    unsigned short* rowp = aggb + (size_t)node * D;
    int us = (ln * 4) ^ ((node & 7) << 3);
    *reinterpret_cast<uint2*>(rowp + us) = w;
}

// Tier B: bf16 feat reads, fp32 agg write to d_out.
__global__ __launch_bounds__(256) void g_bf_out(const unsigned short* __restrict__ fb,
                                                const int* __restrict__ counts,
                                                const int* __restrict__ buckets,
                                                const int* __restrict__ ovf,
                                                const int* __restrict__ ovf_cnt,
                                                float* __restrict__ out, int N) {
    int node = (int)((blockIdx.x * (long)blockDim.x + threadIdx.x) >> 6);
    int ln = threadIdx.x & 63;
    if (node >= N) return;
    int cnt_raw = counts[node];
    int cnt = cnt_raw > CAP ? CAP : cnt_raw;
    const int* bk = buckets + (size_t)node * CAP;
    uint2 u = reinterpret_cast<const uint2*>(fb + (size_t)node * D)[ln];
    float4 acc;
    acc.x = bflo(u.x); acc.y = bfhi(u.x); acc.z = bflo(u.y); acc.w = bfhi(u.y);
    GAT_BODY(BLOAD, BACC)
    for (; j < cnt; ++j) {
        uint2 v = reinterpret_cast<const uint2*>(fb + (size_t)bk[j] * D)[ln];
        acc.x += bflo(v.x); acc.y += bfhi(v.x);
        acc.z += bflo(v.y); acc.w += bfhi(v.y);
    }
    if (cnt_raw > CAP) {
        int m = *ovf_cnt;
        if (m > MAXOVF) m = MAXOVF;
        for (int e = 0; e < m; ++e) {
            if (ovf[2 * e + 1] == node) {
                uint2 v = reinterpret_cast<const uint2*>(fb + (size_t)ovf[2 * e] * D)[ln];
                acc.x += bflo(v.x); acc.y += bfhi(v.x);
                acc.z += bflo(v.y); acc.w += bfhi(v.y);
            }
        }
    }
    reinterpret_cast<float4*>(out + (size_t)node * D)[ln] = acc;
}

// Tier C: fp32 feat reads, fp32 agg write to d_out.
__global__ __launch_bounds__(256) void g_f32_out(const float* __restrict__ feat,
                                                 const int* __restrict__ counts,
                                                 const int* __restrict__ buckets,
                                                 const int* __restrict__ ovf,
                                                 const int* __restrict__ ovf_cnt,
                                                 float* __restrict__ out, int N) {
    int node = (int)((blockIdx.x * (long)blockDim.x + threadIdx.x) >> 6);
    int ln = threadIdx.x & 63;
    if (node >= N) return;
    int cnt_raw = counts[node];
    int cnt = cnt_raw > CAP ? CAP : cnt_raw;
    const int* bk = buckets + (size_t)node * CAP;
    float4 acc = reinterpret_cast<const float4*>(feat + (size_t)node * D)[ln];
#define FLOAD(W_)                                                              \
    float4 v[W_];                                                              \
    _Pragma("unroll") for (int q = 0; q < W_; ++q)                             \
        v[q] = reinterpret_cast<const float4*>(feat + (size_t)s[q] * D)[ln];
#define FACC(W_)                                                               \
    _Pragma("unroll") for (int q = 0; q < W_; ++q) {                           \
        acc.x += v[q].x; acc.y += v[q].y; acc.z += v[q].z; acc.w += v[q].w;    \
    }
    GAT_BODY(FLOAD, FACC)
    for (; j < cnt; ++j) {
        float4 v = reinterpret_cast<const float4*>(feat + (size_t)bk[j] * D)[ln];
        acc.x += v.x; acc.y += v.y; acc.z += v.z; acc.w += v.w;
    }
    if (cnt_raw > CAP) {
        int m = *ovf_cnt;
        if (m > MAXOVF) m = MAXOVF;
        for (int e = 0; e < m; ++e) {
            if (ovf[2 * e + 1] == node) {
                float4 v = reinterpret_cast<const float4*>(feat + (size_t)ovf[2 * e] * D)[ln];
                acc.x += v.x; acc.y += v.y; acc.z += v.z; acc.w += v.w;
            }
        }
    }
    reinterpret_cast<float4*>(out + (size_t)node * D)[ln] = acc;
}

// ================= CSR build (fallback path) =================

__global__ void k_hist(const int* __restrict__ dst, int* __restrict__ counts, int E) {
    for (int e = blockIdx.x * blockDim.x + threadIdx.x; e < E;
         e += gridDim.x * blockDim.x)
        atomicAdd(&counts[dst[e]], 1);
}

__global__ __launch_bounds__(SCAN_THREADS) void k_scan(const int* __restrict__ counts,
                                                       int* __restrict__ offsets,
                                                       int* __restrict__ cursor,
                                                       int N) {
    __shared__ int s[SCAN_THREADS];
    const int t = threadIdx.x;
    const int chunk = (N + SCAN_THREADS - 1) / SCAN_THREADS;
    const int lo = t * chunk;
    const int hi = min(N, lo + chunk);
    int local = 0;
    for (int i = lo; i < hi; ++i) local += counts[i];
    s[t] = local;
    __syncthreads();
    for (int str = 1; str < SCAN_THREADS; str <<= 1) {
        int v = (t >= str) ? s[t - str] : 0;
        __syncthreads();
        s[t] += v;
        __syncthreads();
    }
    int run = s[t] - local;
    for (int i = lo; i < hi; ++i) {
        offsets[i] = run;
        cursor[i] = run;
        run += counts[i];
    }
    if (t == SCAN_THREADS - 1) offsets[N] = s[SCAN_THREADS - 1];
}

__global__ void k_fill(const int* __restrict__ src, const int* __restrict__ dst,
                       int* __restrict__ cursor, int* __restrict__ buckets, int E) {
    for (int e = blockIdx.x * blockDim.x + threadIdx.x; e < E;
         e += gridDim.x * blockDim.x) {
        int pos = atomicAdd(&cursor[dst[e]], 1);
        buckets[pos] = src[e];
    }
}

__global__ __launch_bounds__(256) void k_gather_csr(const float* __restrict__ feat,
                                                    const int* __restrict__ offsets,
                                                    const int* __restrict__ buckets,
                                                    float* __restrict__ out, int N) {
    int wave = (int)((blockIdx.x * (long)blockDim.x + threadIdx.x) >> 6);
    int lane = threadIdx.x & 63;
    if (wave >= N) return;
    const int off = offsets[wave];
    const int end = offsets[wave + 1];
    float4 acc = reinterpret_cast<const float4*>(feat + (size_t)wave * D)[lane];
    int j = off;
    for (; j + 8 <= end; j += 8) {
        int s[8];
        #pragma unroll
        for (int q = 0; q < 8; ++q) s[q] = buckets[j + q];
        float4 v[8];
        #pragma unroll
        for (int q = 0; q < 8; ++q)
            v[q] = reinterpret_cast<const float4*>(feat + (size_t)s[q] * D)[lane];
        #pragma unroll
        for (int q = 0; q < 8; ++q) {
            acc.x += v[q].x; acc.y += v[q].y; acc.z += v[q].z; acc.w += v[q].w;
        }
    }
    for (; j < end; ++j) {
        float4 v = reinterpret_cast<const float4*>(feat + (size_t)buckets[j] * D)[lane];
        acc.x += v.x; acc.y += v.y; acc.z += v.z; acc.w += v.w;
    }
    reinterpret_cast<float4*>(out + (size_t)wave * D)[lane] = acc;
}

// ================= atomic scatter (last-resort) =================

__global__ __launch_bounds__(256) void gc_copy(const float* __restrict__ feat,
                                               float* __restrict__ agg, long n4) {
    long i = (long)blockIdx.x * blockDim.x + threadIdx.x;
    if (i < n4)
        reinterpret_cast<float4*>(agg)[i] = reinterpret_cast<const float4*>(feat)[i];
}

__global__ __launch_bounds__(256) void gc_scatter(const float* __restrict__ feat,
                                                  const int* __restrict__ src,
                                                  const int* __restrict__ dst,
                                                  float* __restrict__ agg, int n_edges) {
    int wave = (int)((blockIdx.x * (long)blockDim.x + threadIdx.x) >> 6);
    int lane = threadIdx.x & 63;
    if (wave >= n_edges) return;
    int s = src[wave];
    int d = dst[wave];
    const float4 v = reinterpret_cast<const float4*>(feat + (size_t)s * D)[lane];
    float* p = agg + (size_t)d * D + (size_t)lane * 4;
    atomicAdd(p + 0, v.x);
    atomicAdd(p + 1, v.y);
    atomicAdd(p + 2, v.z);
    atomicAdd(p + 3, v.w);
}

// ================= MFMA GEMMs (B staged per-ks into LDS) =================

__device__ inline void gload16(const char* g, const unsigned char* lds) {
    __builtin_amdgcn_global_load_lds(
        (const __attribute__((address_space(1))) void*)g,
        (__attribute__((address_space(3))) void*)lds, 16, 0, 0);
}

// Tier A: A staged via global_load_lds from swizzled bf16 agg in ws.
__global__ __launch_bounds__(256) void gemm_mfma_b(const unsigned short* __restrict__ aggb,
                                                   const unsigned short* __restrict__ wTs,
                                                   float* __restrict__ out, int n_rows) {
    __shared__ __align__(16) unsigned char s_a[BM * 512];  // 64 rows x 256 bf16
    __shared__ __align__(16) unsigned char s_b[16384];     // one ks-slice of B
    const int t = threadIdx.x;
    const int row0 = blockIdx.x * BM;
    const int wv = t >> 6;
    const int l = t & 63;
    const char* wb = reinterpret_cast<const char*>(wTs);

    const char* gbase = reinterpret_cast<const char*>(aggb) + (size_t)row0 * 512;
    #pragma unroll
    for (int q = 0; q < 8; ++q) {
        int off = wv * 8192 + q * 1024;
        gload16(gbase + off + l * 16, s_a + off);
    }
    #pragma unroll
    for (int i = 0; i < 4; ++i) {
        int off = wv * 4096 + i * 1024;
        gload16(wb + off + l * 16, s_b + off);
    }
    __syncthreads();

    f32x4 acc[16];
    #pragma unroll
    for (int ct = 0; ct < 16; ++ct) acc[ct] = (f32x4){0.f, 0.f, 0.f, 0.f};

    const int lr = wv * 16 + (l & 15);
    const int g = l >> 4;
    for (int ks = 0; ks < 8; ++ks) {
        const int kb = ks * 32 + g * 8;
        const int ab = (lr * 512 + kb * 2) ^ ((lr & 7) << 4);
        s16x8 af = *reinterpret_cast<const s16x8*>(s_a + ab);
        #pragma unroll
        for (int ct = 0; ct < 16; ++ct) {
            int col = ct * 16 + (l & 15);
            int bb = (col * 64 + g * 16) ^ ((col & 7) << 4);
            s16x8 bf = *reinterpret_cast<const s16x8*>(s_b + bb);
            acc[ct] = __builtin_amdgcn_mfma_f32_16x16x32_bf16(af, bf, acc[ct], 0, 0, 0);
        }
        __syncthreads();  // all waves done reading s_b
        if (ks < 7) {
            #pragma unroll
            for (int i = 0; i < 4; ++i) {
                int off = wv * 4096 + i * 1024;
                gload16(wb + (size_t)(ks + 1) * 16384 + off + l * 16, s_b + off);
            }
            __syncthreads();
        }
    }

    const int rbase = row0 + wv * 16 + (l >> 4) * 4;
    const int cb = l & 15;
    #pragma unroll
    for (int ct = 0; ct < 16; ++ct) {
        #pragma unroll
        for (int r = 0; r < 4; ++r) {
            int row = rbase + r;
            if (row < n_rows)
                out[(size_t)row * D + ct * 16 + cb] = fmaxf(acc[ct][r], 0.f);
        }
    }
}

// Tiers B/C/CSR: A read fp32 from out (in-place), converted + swizzled reg->LDS.
__global__ __launch_bounds__(256) void gemm_mfma(const unsigned short* __restrict__ wTs,
                                                 float* __restrict__ out, int n_rows) {
    __shared__ __align__(16) unsigned char s_a[BM * 512];
    __shared__ __align__(16) unsigned char s_b[16384];
    const int t = threadIdx.x;
    const int row0 = blockIdx.x * BM;
    const int wv = t >> 6;
    const int l = t & 63;
    const char* wb = reinterpret_cast<const char*>(wTs);

    #pragma unroll
    for (int i = 0; i < 4; ++i) {
        int off = wv * 4096 + i * 1024;
        gload16(wb + off + l * 16, s_b + off);
    }
    #pragma unroll
    for (int i = 0; i < 16; ++i) {
        int f4 = t + 256 * i;
        int row = f4 >> 6;
        int kc = f4 & 63;
        int grow = row0 + row;
        if (grow >= n_rows) grow = n_rows - 1;
        float4 v = *reinterpret_cast<const float4*>(out + (size_t)grow * D + kc * 4);
        uint2 u;
        u.x = f2bf(v.x) | (f2bf(v.y) << 16);
        u.y = f2bf(v.z) | (f2bf(v.w) << 16);
        int byte = (row * 512 + kc * 8) ^ ((row & 7) << 4);
        *reinterpret_cast<uint2*>(s_a + byte) = u;
    }
    __syncthreads();

    f32x4 acc[16];
    #pragma unroll
    for (int ct = 0; ct < 16; ++ct) acc[ct] = (f32x4){0.f, 0.f, 0.f, 0.f};

    const int lr = wv * 16 + (l & 15);
    const int g = l >> 4;
    for (int ks = 0; ks < 8; ++ks) {
        const int kb = ks * 32 + g * 8;
        const int ab = (lr * 512 + kb * 2) ^ ((lr & 7) << 4);
        s16x8 af = *reinterpret_cast<const s16x8*>(s_a + ab);
        #pragma unroll
        for (int ct = 0; ct < 16; ++ct) {
            int col = ct * 16 + (l & 15);
            int bb = (col * 64 + g * 16) ^ ((col & 7) << 4);
            s16x8 bf = *reinterpret_cast<const s16x8*>(s_b + bb);
            acc[ct] = __builtin_amdgcn_mfma_f32_16x16x32_bf16(af, bf, acc[ct], 0, 0, 0);
        }
        __syncthreads();
        if (ks < 7) {
            #pragma unroll
            for (int i = 0; i < 4; ++i) {
                int off = wv * 4096 + i * 1024;
                gload16(wb + (size_t)(ks + 1) * 16384 + off + l * 16, s_b + off);
            }
            __syncthreads();
        }
    }

    const int rbase = row0 + wv * 16 + (l >> 4) * 4;
    const int cb = l & 15;
    #pragma unroll
    for (int ct = 0; ct < 16; ++ct) {
        #pragma unroll
        for (int r = 0; r < 4; ++r) {
            int row = rbase + r;
            if (row < n_rows)
                out[(size_t)row * D + ct * 16 + cb] = fmaxf(acc[ct][r], 0.f);
        }
    }
}

// legacy fp32 GEMM (no-workspace fallback)
__global__ __launch_bounds__(256) void gemm_relu(const float* __restrict__ Wm,
                                                 float* __restrict__ out, int n_rows) {
    __shared__ float s_a[32][D];
    const int row0 = blockIdx.x * 32;
    const int c = threadIdx.x;
    {
        const float4* gsrc = reinterpret_cast<const float4*>(out + (size_t)row0 * D);
        float4* ldst = reinterpret_cast<float4*>(&s_a[0][0]);
        #pragma unroll
        for (int i = 0; i < 8; ++i)
            ldst[threadIdx.x + i * 256] = gsrc[threadIdx.x + i * 256];
    }
    __syncthreads();
    float acc[32];
    #pragma unroll
    for (int r = 0; r < 32; ++r) acc[r] = 0.f;
    #pragma unroll 4
    for (int k = 0; k < D; ++k) {
        float w = Wm[(size_t)k * D + c];
        #pragma unroll
        for (int r = 0; r < 32; ++r) acc[r] += s_a[r][k] * w;
    }
    #pragma unroll
    for (int r = 0; r < 32; ++r) {
        int row = row0 + r;
        if (row < n_rows) out[(size_t)row * D + c] = fmaxf(acc[r], 0.f);
    }
}

extern "C" void kernel_launch(void* const* d_in, const int* in_sizes, int n_in,
                              void* d_out, int out_size, void* d_ws, size_t ws_size,
                              hipStream_t stream) {
    const float* feat = (const float*)d_in[0];
    const float* W    = (const float*)d_in[1];
    const int*   src  = (const int*)d_in[2];
    const int*   dst  = (const int*)d_in[3];
    float* out = (float*)d_out;

    const int N = in_sizes[0] / D;  // 100000
    const int E = in_sizes[2];      // 1600000
    const int Npad = ((N + BM - 1) / BM) * BM;
    auto al = [](size_t x) { return (x + 255) & ~(size_t)255; };

    const size_t cap_bytes = ((size_t)N + 1 + 2 * MAXOVF + (size_t)N * CAP) * 4;
    const size_t featb_off = al(cap_bytes);
    const size_t featb_sz  = (size_t)N * D * 2;
    const size_t wt_off    = al(featb_off + featb_sz);
    const size_t wt_sz     = (size_t)D * D * 2;   // wTs: 8 x 16KB
    const size_t aggb_off  = al(wt_off + wt_sz);
    const size_t aggb_sz   = (size_t)Npad * D * 2;

    const size_t need_A   = aggb_off + aggb_sz;
    const size_t need_B   = wt_off + wt_sz;
    const size_t need_C   = cap_bytes;            // wTs aliases buckets
    const size_t need_csr = ((size_t)3 * N + 1 + (size_t)E) * 4;

    const int gemm_blocks = (N + BM - 1) / BM;
    const int gat_blocks = (N + 3) / 4;
    const int fill_blocks = (int)(((E >> 3) + 255) / 256) + 1;

    if (ws_size >= need_C) {
        char* base = (char*)d_ws;
        int* counts  = (int*)base;
        int* ovf_cnt = counts + N;
        int* ovf     = ovf_cnt + 1;
        int* buckets = ovf + 2 * MAXOVF;

        k_zero<<<(N + 1 + 255) / 256, 256, 0, stream>>>(counts, N + 1);

        if (ws_size >= need_A) {
            unsigned short* featb = (unsigned short*)(base + featb_off);
            unsigned short* wTs   = (unsigned short*)(base + wt_off);
            unsigned short* aggb  = (unsigned short*)(base + aggb_off);
            k_f2b<<<2048, 256, 0, stream>>>(feat, featb, (long)N * D / 8);
            k_wTs<<<D, 256, 0, stream>>>(W, wTs);
            k_fillcap<<<fill_blocks, 256, 0, stream>>>(src, dst, counts, buckets, ovf, ovf_cnt, E);
            g_bf_aggb<<<gat_blocks, 256, 0, stream>>>(featb, counts, buckets, ovf, ovf_cnt, aggb, N);
            gemm_mfma_b<<<gemm_blocks, 256, 0, stream>>>(aggb, wTs, out, N);
        } else if (ws_size >= need_B) {
            unsigned short* featb = (unsigned short*)(base + featb_off);
            unsigned short* wTs   = (unsigned short*)(base + wt_off);
            k_f2b<<<2048, 256, 0, stream>>>(feat, featb, (long)N * D / 8);
            k_wTs<<<D, 256, 0, stream>>>(W, wTs);
            k_fillcap<<<fill_blocks, 256, 0, stream>>>(src, dst, counts, buckets, ovf, ovf_cnt, E);
            g_bf_out<<<gat_blocks, 256, 0, stream>>>(featb, counts, buckets, ovf, ovf_cnt, out, N);
            gemm_mfma<<<gemm_blocks, 256, 0, stream>>>(wTs, out, N);
        } else {
            unsigned short* wTs = (unsigned short*)(((uintptr_t)buckets + 255) & ~(uintptr_t)255);
            k_fillcap<<<fill_blocks, 256, 0, stream>>>(src, dst, counts, buckets, ovf, ovf_cnt, E);
            g_f32_out<<<gat_blocks, 256, 0, stream>>>(feat, counts, buckets, ovf, ovf_cnt, out, N);
            k_wTs<<<D, 256, 0, stream>>>(W, wTs);
            gemm_mfma<<<gemm_blocks, 256, 0, stream>>>(wTs, out, N);
        }
    } else if (ws_size >= need_csr) {
        int* counts  = (int*)d_ws;
        int* offsets = counts + N;
        int* cursor  = offsets + N + 1;
        int* buckets = cursor + N;

        k_zero<<<(N + 255) / 256, 256, 0, stream>>>(counts, N);
        k_hist<<<2048, 256, 0, stream>>>(dst, counts, E);
        k_scan<<<1, SCAN_THREADS, 0, stream>>>(counts, offsets, cursor, N);
        k_fill<<<2048, 256, 0, stream>>>(src, dst, cursor, buckets, E);
        k_gather_csr<<<gat_blocks, 256, 0, stream>>>(feat, offsets, buckets, out, N);
        unsigned short* wTs =
            (unsigned short*)(((uintptr_t)buckets + 255) & ~(uintptr_t)255);
        k_wTs<<<D, 256, 0, stream>>>(W, wTs);
        gemm_mfma<<<gemm_blocks, 256, 0, stream>>>(wTs, out, N);
    } else {
        long n4 = (long)N * D / 4;
        gc_copy<<<(int)((n4 + 255) / 256), 256, 0, stream>>>(feat, out, n4);
        gc_scatter<<<(E + 3) / 4, 256, 0, stream>>>(feat, src, dst, out, E);
        gemm_relu<<<(N + 31) / 32, 256, 0, stream>>>(W, out, N);
    }
}

// Round 9
// 258.324 us; speedup vs baseline: 1.3381x; 1.3381x over previous
//
#include <hip/hip_runtime.h>

#define D 256
#define SCAN_THREADS 1024
#define CAP 32
#define MAXOVF 4096
#define BM 64

// range-partition params
#define RN 128          // nodes per range
#define RSH 7
#define SCAP 4096       // stream capacity per range (mean 2048)
#define PCH 8192        // edges per k_part block
#define PTH 512         // k_part threads
#define NRANGES_MAX 1024

typedef float f32x4 __attribute__((ext_vector_type(4)));
typedef short s16x8 __attribute__((ext_vector_type(8)));

__device__ inline unsigned int f2bf(float x) {
    unsigned int u = __float_as_uint(x);
    return (u + 0x7FFFu + ((u >> 16) & 1u)) >> 16;  // RNE, low 16 bits valid
}
__device__ inline float bflo(unsigned int u) { return __uint_as_float(u << 16); }
__device__ inline float bfhi(unsigned int u) { return __uint_as_float(u & 0xFFFF0000u); }

// ================= small utility kernels =================

__global__ void k_zero(int* __restrict__ p, int n) {
    int i = blockIdx.x * blockDim.x + threadIdx.x;
    if (i < n) p[i] = 0;
}

__global__ __launch_bounds__(256) void k_f2b(const float* __restrict__ f,
                                             unsigned short* __restrict__ fb, long n8) {
    for (long i = blockIdx.x * 256L + threadIdx.x; i < n8; i += (long)gridDim.x * 256) {
        const float4* p = reinterpret_cast<const float4*>(f + i * 8);
        float4 a = p[0], b = p[1];
        uint4 u;
        u.x = f2bf(a.x) | (f2bf(a.y) << 16);
        u.y = f2bf(a.z) | (f2bf(a.w) << 16);
        u.z = f2bf(b.x) | (f2bf(b.y) << 16);
        u.w = f2bf(b.z) | (f2bf(b.w) << 16);
        reinterpret_cast<uint4*>(fb)[i] = u;
    }
}

// W[k][col] fp32 -> wTs: per-ks staged-B LDS image (8 blocks x 16KB).
__global__ __launch_bounds__(256) void k_wTs(const float* __restrict__ W,
                                             unsigned short* __restrict__ wTs) {
    int col = blockIdx.x;   // 0..255
    int k = threadIdx.x;    // 0..255
    unsigned short v = (unsigned short)f2bf(W[(size_t)k * D + col]);
    int ks = k >> 5;
    int byte = ((col << 6) + (((k >> 3) & 3) << 4) + ((k & 7) << 1)) ^ ((col & 7) << 4);
    *reinterpret_cast<unsigned short*>(
        reinterpret_cast<char*>(wTs) + (size_t)ks * 16384 + byte) = v;
}

// ================= phase 1: range partition (dense appends) =================
__global__ __launch_bounds__(PTH) void k_part(const int* __restrict__ src,
                                              const int* __restrict__ dst,
                                              int* __restrict__ gcur,
                                              int* __restrict__ streams,
                                              int* __restrict__ ovf,
                                              int* __restrict__ ovf_cnt,
                                              int E, int nranges) {
    __shared__ int hist[NRANGES_MAX];
    __shared__ int base[NRANGES_MAX];
    __shared__ int off[NRANGES_MAX];
    const int t = threadIdx.x;
    const long e0 = (long)blockIdx.x * PCH;
    for (int i = t; i < nranges; i += PTH) hist[i] = 0;
    __syncthreads();
    int md[PCH / PTH], ms[PCH / PTH];
    #pragma unroll
    for (int i = 0; i < PCH / PTH; ++i) {
        long e = e0 + (long)i * PTH + t;
        if (e < E) {
            md[i] = dst[e];
            ms[i] = src[e];
            atomicAdd(&hist[md[i] >> RSH], 1);
        } else {
            md[i] = -1;
        }
    }
    __syncthreads();
    for (int i = t; i < nranges; i += PTH) {
        int h = hist[i];
        base[i] = h ? atomicAdd(&gcur[i], h) : 0;
        off[i] = 0;
    }
    __syncthreads();
    #pragma unroll
    for (int i = 0; i < PCH / PTH; ++i) {
        if (md[i] >= 0) {
            int r = md[i] >> RSH;
            int p = base[r] + atomicAdd(&off[r], 1);
            if (p < SCAP) {
                streams[(size_t)r * SCAP + p] = (ms[i] << RSH) | (md[i] & (RN - 1));
            } else {
                int o = atomicAdd(ovf_cnt, 1);
                if (o < MAXOVF) { ovf[2 * o] = ms[i]; ovf[2 * o + 1] = md[i]; }
            }
        }
    }
}

// ================= phase 2: LDS counting-sort + fused gather =================
// One block per range: sort its stream by local node in LDS, then 8 waves
// gather 16 nodes each; bf16 rows, fp32 accum, swizzled bf16 aggb write.
__global__ __launch_bounds__(512) void k_sg(const unsigned short* __restrict__ featb,
                                            const int* __restrict__ gcur,
                                            const int* __restrict__ streams,
                                            const int* __restrict__ ovf,
                                            const int* __restrict__ ovf_cnt,
                                            unsigned short* __restrict__ aggb, int N) {
    __shared__ int hist[RN], basei[RN], off[RN], scn[RN];
    __shared__ int elist[SCAP];
    const int r = blockIdx.x;
    const int t = threadIdx.x;
    const int node0 = r << RSH;
    int cnt = gcur[r];
    if (cnt > SCAP) cnt = SCAP;
    if (t < RN) { hist[t] = 0; off[t] = 0; }
    __syncthreads();
    int ent[SCAP / 512];
    #pragma unroll
    for (int i = 0; i < SCAP / 512; ++i) {
        int p = t + i * 512;
        if (p < cnt) {
            ent[i] = streams[(size_t)r * SCAP + p];
            atomicAdd(&hist[ent[i] & (RN - 1)], 1);
        } else {
            ent[i] = -1;
        }
    }
    __syncthreads();
    if (t < RN) scn[t] = hist[t];
    __syncthreads();
    for (int st = 1; st < RN; st <<= 1) {
        int v = 0;
        if (t < RN && t >= st) v = scn[t - st];
        __syncthreads();
        if (t < RN) scn[t] += v;
        __syncthreads();
    }
    if (t < RN) basei[t] = scn[t] - hist[t];
    __syncthreads();
    #pragma unroll
    for (int i = 0; i < SCAP / 512; ++i) {
        if (ent[i] >= 0) {
            int ln_ = ent[i] & (RN - 1);
            int p = basei[ln_] + atomicAdd(&off[ln_], 1);
            elist[p] = ent[i] >> RSH;
        }
    }
    __syncthreads();
    int ovfn = *ovf_cnt;
    if (ovfn > MAXOVF) ovfn = MAXOVF;
    const int wv = t >> 6;   // 0..7
    const int l = t & 63;
    for (int k = 0; k < RN / 8; ++k) {
        int ln_ = wv * (RN / 8) + k;
        int node = node0 + ln_;
        if (node >= N) continue;
        int cb = hist[ln_];
        int bb = basei[ln_];
        uint2 u = reinterpret_cast<const uint2*>(featb + (size_t)node * D)[l];
        float4 acc;
        acc.x = bflo(u.x); acc.y = bfhi(u.x); acc.z = bflo(u.y); acc.w = bfhi(u.y);
        int j = 0;
        for (; j + 16 <= cb; j += 16) {
            int s[16];
            #pragma unroll
            for (int q = 0; q < 16; ++q) s[q] = elist[bb + j + q];
            uint2 v[16];
            #pragma unroll
            for (int q = 0; q < 16; ++q)
                v[q] = reinterpret_cast<const uint2*>(featb + (size_t)s[q] * D)[l];
            #pragma unroll
            for (int q = 0; q < 16; ++q) {
                acc.x += bflo(v[q].x); acc.y += bfhi(v[q].x);
                acc.z += bflo(v[q].y); acc.w += bfhi(v[q].y);
            }
        }
        for (; j + 8 <= cb; j += 8) {
            int s[8];
            #pragma unroll
            for (int q = 0; q < 8; ++q) s[q] = elist[bb + j + q];
            uint2 v[8];
            #pragma unroll
            for (int q = 0; q < 8; ++q)
                v[q] = reinterpret_cast<const uint2*>(featb + (size_t)s[q] * D)[l];
            #pragma unroll
            for (int q = 0; q < 8; ++q) {
                acc.x += bflo(v[q].x); acc.y += bfhi(v[q].x);
                acc.z += bflo(v[q].y); acc.w += bfhi(v[q].y);
            }
        }
        for (; j < cb; ++j) {
            uint2 v = reinterpret_cast<const uint2*>(featb + (size_t)elist[bb + j] * D)[l];
            acc.x += bflo(v.x); acc.y += bfhi(v.x);
            acc.z += bflo(v.y); acc.w += bfhi(v.y);
        }
        if (ovfn > 0) {
            for (int e = 0; e < ovfn; ++e) {
                if (ovf[2 * e + 1] == node) {
                    uint2 v = reinterpret_cast<const uint2*>(featb + (size_t)ovf[2 * e] * D)[l];
                    acc.x += bflo(v.x); acc.y += bfhi(v.x);
                    acc.z += bflo(v.y); acc.w += bfhi(v.y);
                }
            }
        }
        uint2 w;
        w.x = f2bf(acc.x) | (f2bf(acc.y) << 16);
        w.y = f2bf(acc.z) | (f2bf(acc.w) << 16);
        unsigned short* rowp = aggb + (size_t)node * D;
        int us = (l * 4) ^ ((node & 7) << 3);
        *reinterpret_cast<uint2*>(rowp + us) = w;
    }
}

// ================= capacity-bucket build (fallback, round-7 form) =========
__global__ void k_fillcap(const int* __restrict__ src, const int* __restrict__ dst,
                          int* __restrict__ counts, int* __restrict__ buckets,
                          int* __restrict__ ovf, int* __restrict__ ovf_cnt, int E) {
    for (int e = blockIdx.x * blockDim.x + threadIdx.x; e < E;
         e += gridDim.x * blockDim.x) {
        int d = dst[e];
        int pos = atomicAdd(&counts[d], 1);
        if (pos < CAP) {
            buckets[(size_t)d * CAP + pos] = src[e];
        } else {
            int o = atomicAdd(ovf_cnt, 1);
            if (o < MAXOVF) {
                ovf[2 * o + 0] = src[e];
                ovf[2 * o + 1] = d;
            }
        }
    }
}

// ================= gathers (fallback tiers) =================

#define GAT_BODY(LOAD, ACCUM)                                                  \
    int j = 0;                                                                 \
    for (; j + 16 <= cnt; j += 16) {                                           \
        int s[16];                                                             \
        _Pragma("unroll") for (int q = 0; q < 16; ++q) s[q] = bk[j + q];       \
        LOAD(16)                                                               \
        ACCUM(16)                                                              \
    }                                                                          \
    for (; j + 8 <= cnt; j += 8) {                                             \
        int s[8];                                                              \
        _Pragma("unroll") for (int q = 0; q < 8; ++q) s[q] = bk[j + q];        \
        LOAD(8)                                                                \
        ACCUM(8)                                                               \
    }

__global__ __launch_bounds__(256) void g_bf_aggb(const unsigned short* __restrict__ fb,
                                                 const int* __restrict__ counts,
                                                 const int* __restrict__ buckets,
                                                 const int* __restrict__ ovf,
                                                 const int* __restrict__ ovf_cnt,
                                                 unsigned short* __restrict__ aggb, int N) {
    int node = (int)((blockIdx.x * (long)blockDim.x + threadIdx.x) >> 6);
    int ln = threadIdx.x & 63;
    if (node >= N) return;
    int cnt_raw = counts[node];
    int cnt = cnt_raw > CAP ? CAP : cnt_raw;
    const int* bk = buckets + (size_t)node * CAP;
    uint2 u = reinterpret_cast<const uint2*>(fb + (size_t)node * D)[ln];
    float4 acc;
    acc.x = bflo(u.x); acc.y = bfhi(u.x); acc.z = bflo(u.y); acc.w = bfhi(u.y);
#define BLOAD(W_)                                                              \
    uint2 v[W_];                                                               \
    _Pragma("unroll") for (int q = 0; q < W_; ++q)                             \
        v[q] = reinterpret_cast<const uint2*>(fb + (size_t)s[q] * D)[ln];
#define BACC(W_)                                                               \
    _Pragma("unroll") for (int q = 0; q < W_; ++q) {                           \
        acc.x += bflo(v[q].x); acc.y += bfhi(v[q].x);                          \
        acc.z += bflo(v[q].y); acc.w += bfhi(v[q].y);                          \
    }
    GAT_BODY(BLOAD, BACC)
    for (; j < cnt; ++j) {
        uint2 v = reinterpret_cast<const uint2*>(fb + (size_t)bk[j] * D)[ln];
        acc.x += bflo(v.x); acc.y += bfhi(v.x);
        acc.z += bflo(v.y); acc.w += bfhi(v.y);
    }
    if (cnt_raw > CAP) {
        int m = *ovf_cnt;
        if (m > MAXOVF) m = MAXOVF;
        for (int e = 0; e < m; ++e) {
            if (ovf[2 * e + 1] == node) {
                uint2 v = reinterpret_cast<const uint2*>(fb + (size_t)ovf[2 * e] * D)[ln];
                acc.x += bflo(v.x); acc.y += bfhi(v.x);
                acc.z += bflo(v.y); acc.w += bfhi(v.y);
            }
        }
    }
    uint2 w;
    w.x = f2bf(acc.x) | (f2bf(acc.y) << 16);
    w.y = f2bf(acc.z) | (f2bf(acc.w) << 16);
    unsigned short* rowp = aggb + (size_t)node * D;
    int us = (ln * 4) ^ ((node & 7) << 3);
    *reinterpret_cast<uint2*>(rowp + us) = w;
}

__global__ __launch_bounds__(256) void g_bf_out(const unsigned short* __restrict__ fb,
                                                const int* __restrict__ counts,
                                                const int* __restrict__ buckets,
                                                const int* __restrict__ ovf,
                                                const int* __restrict__ ovf_cnt,
                                                float* __restrict__ out, int N) {
    int node = (int)((blockIdx.x * (long)blockDim.x + threadIdx.x) >> 6);
    int ln = threadIdx.x & 63;
    if (node >= N) return;
    int cnt_raw = counts[node];
    int cnt = cnt_raw > CAP ? CAP : cnt_raw;
    const int* bk = buckets + (size_t)node * CAP;
    uint2 u = reinterpret_cast<const uint2*>(fb + (size_t)node * D)[ln];
    float4 acc;
    acc.x = bflo(u.x); acc.y = bfhi(u.x); acc.z = bflo(u.y); acc.w = bfhi(u.y);
    GAT_BODY(BLOAD, BACC)
    for (; j < cnt; ++j) {
        uint2 v = reinterpret_cast<const uint2*>(fb + (size_t)bk[j] * D)[ln];
        acc.x += bflo(v.x); acc.y += bfhi(v.x);
        acc.z += bflo(v.y); acc.w += bfhi(v.y);
    }
    if (cnt_raw > CAP) {
        int m = *ovf_cnt;
        if (m > MAXOVF) m = MAXOVF;
        for (int e = 0; e < m; ++e) {
            if (ovf[2 * e + 1] == node) {
                uint2 v = reinterpret_cast<const uint2*>(fb + (size_t)ovf[2 * e] * D)[ln];
                acc.x += bflo(v.x); acc.y += bfhi(v.x);
                acc.z += bflo(v.y); acc.w += bfhi(v.y);
            }
        }
    }
    reinterpret_cast<float4*>(out + (size_t)node * D)[ln] = acc;
}

__global__ __launch_bounds__(256) void g_f32_out(const float* __restrict__ feat,
                                                 const int* __restrict__ counts,
                                                 const int* __restrict__ buckets,
                                                 const int* __restrict__ ovf,
                                                 const int* __restrict__ ovf_cnt,
                                                 float* __restrict__ out, int N) {
    int node = (int)((blockIdx.x * (long)blockDim.x + threadIdx.x) >> 6);
    int ln = threadIdx.x & 63;
    if (node >= N) return;
    int cnt_raw = counts[node];
    int cnt = cnt_raw > CAP ? CAP : cnt_raw;
    const int* bk = buckets + (size_t)node * CAP;
    float4 acc = reinterpret_cast<const float4*>(feat + (size_t)node * D)[ln];
#define FLOAD(W_)                                                              \
    float4 v[W_];                                                              \
    _Pragma("unroll") for (int q = 0; q < W_; ++q)                             \
        v[q] = reinterpret_cast<const float4*>(feat + (size_t)s[q] * D)[ln];
#define FACC(W_)                                                               \
    _Pragma("unroll") for (int q = 0; q < W_; ++q) {                           \
        acc.x += v[q].x; acc.y += v[q].y; acc.z += v[q].z; acc.w += v[q].w;    \
    }
    GAT_BODY(FLOAD, FACC)
    for (; j < cnt; ++j) {
        float4 v = reinterpret_cast<const float4*>(feat + (size_t)bk[j] * D)[ln];
        acc.x += v.x; acc.y += v.y; acc.z += v.z; acc.w += v.w;
    }
    if (cnt_raw > CAP) {
        int m = *ovf_cnt;
        if (m > MAXOVF) m = MAXOVF;
        for (int e = 0; e < m; ++e) {
            if (ovf[2 * e + 1] == node) {
                float4 v = reinterpret_cast<const float4*>(feat + (size_t)ovf[2 * e] * D)[ln];
                acc.x += v.x; acc.y += v.y; acc.z += v.z; acc.w += v.w;
            }
        }
    }
    reinterpret_cast<float4*>(out + (size_t)node * D)[ln] = acc;
}

// ================= CSR build (fallback path) =================

__global__ void k_hist(const int* __restrict__ dst, int* __restrict__ counts, int E) {
    for (int e = blockIdx.x * blockDim.x + threadIdx.x; e < E;
         e += gridDim.x * blockDim.x)
        atomicAdd(&counts[dst[e]], 1);
}

__global__ __launch_bounds__(SCAN_THREADS) void k_scan(const int* __restrict__ counts,
                                                       int* __restrict__ offsets,
                                                       int* __restrict__ cursor,
                                                       int N) {
    __shared__ int s[SCAN_THREADS];
    const int t = threadIdx.x;
    const int chunk = (N + SCAN_THREADS - 1) / SCAN_THREADS;
    const int lo = t * chunk;
    const int hi = min(N, lo + chunk);
    int local = 0;
    for (int i = lo; i < hi; ++i) local += counts[i];
    s[t] = local;
    __syncthreads();
    for (int str = 1; str < SCAN_THREADS; str <<= 1) {
        int v = (t >= str) ? s[t - str] : 0;
        __syncthreads();
        s[t] += v;
        __syncthreads();
    }
    int run = s[t] - local;
    for (int i = lo; i < hi; ++i) {
        offsets[i] = run;
        cursor[i] = run;
        run += counts[i];
    }
    if (t == SCAN_THREADS - 1) offsets[N] = s[SCAN_THREADS - 1];
}

__global__ void k_fill(const int* __restrict__ src, const int* __restrict__ dst,
                       int* __restrict__ cursor, int* __restrict__ buckets, int E) {
    for (int e = blockIdx.x * blockDim.x + threadIdx.x; e < E;
         e += gridDim.x * blockDim.x) {
        int pos = atomicAdd(&cursor[dst[e]], 1);
        buckets[pos] = src[e];
    }
}

__global__ __launch_bounds__(256) void k_gather_csr(const float* __restrict__ feat,
                                                    const int* __restrict__ offsets,
                                                    const int* __restrict__ buckets,
                                                    float* __restrict__ out, int N) {
    int wave = (int)((blockIdx.x * (long)blockDim.x + threadIdx.x) >> 6);
    int lane = threadIdx.x & 63;
    if (wave >= N) return;
    const int off = offsets[wave];
    const int end = offsets[wave + 1];
    float4 acc = reinterpret_cast<const float4*>(feat + (size_t)wave * D)[lane];
    int j = off;
    for (; j + 8 <= end; j += 8) {
        int s[8];
        #pragma unroll
        for (int q = 0; q < 8; ++q) s[q] = buckets[j + q];
        float4 v[8];
        #pragma unroll
        for (int q = 0; q < 8; ++q)
            v[q] = reinterpret_cast<const float4*>(feat + (size_t)s[q] * D)[lane];
        #pragma unroll
        for (int q = 0; q < 8; ++q) {
            acc.x += v[q].x; acc.y += v[q].y; acc.z += v[q].z; acc.w += v[q].w;
        }
    }
    for (; j < end; ++j) {
        float4 v = reinterpret_cast<const float4*>(feat + (size_t)buckets[j] * D)[lane];
        acc.x += v.x; acc.y += v.y; acc.z += v.z; acc.w += v.w;
    }
    reinterpret_cast<float4*>(out + (size_t)wave * D)[lane] = acc;
}

// ================= atomic scatter (last-resort) =================

__global__ __launch_bounds__(256) void gc_copy(const float* __restrict__ feat,
                                               float* __restrict__ agg, long n4) {
    long i = (long)blockIdx.x * blockDim.x + threadIdx.x;
    if (i < n4)
        reinterpret_cast<float4*>(agg)[i] = reinterpret_cast<const float4*>(feat)[i];
}

__global__ __launch_bounds__(256) void gc_scatter(const float* __restrict__ feat,
                                                  const int* __restrict__ src,
                                                  const int* __restrict__ dst,
                                                  float* __restrict__ agg, int n_edges) {
    int wave = (int)((blockIdx.x * (long)blockDim.x + threadIdx.x) >> 6);
    int lane = threadIdx.x & 63;
    if (wave >= n_edges) return;
    int s = src[wave];
    int d = dst[wave];
    const float4 v = reinterpret_cast<const float4*>(feat + (size_t)s * D)[lane];
    float* p = agg + (size_t)d * D + (size_t)lane * 4;
    atomicAdd(p + 0, v.x);
    atomicAdd(p + 1, v.y);
    atomicAdd(p + 2, v.z);
    atomicAdd(p + 3, v.w);
}

// ================= MFMA GEMMs (B staged per-ks into LDS) =================

__device__ inline void gload16(const char* g, const unsigned char* lds) {
    __builtin_amdgcn_global_load_lds(
        (const __attribute__((address_space(1))) void*)g,
        (__attribute__((address_space(3))) void*)lds, 16, 0, 0);
}

__global__ __launch_bounds__(256) void gemm_mfma_b(const unsigned short* __restrict__ aggb,
                                                   const unsigned short* __restrict__ wTs,
                                                   float* __restrict__ out, int n_rows) {
    __shared__ __align__(16) unsigned char s_a[BM * 512];
    __shared__ __align__(16) unsigned char s_b[16384];
    const int t = threadIdx.x;
    const int row0 = blockIdx.x * BM;
    const int wv = t >> 6;
    const int l = t & 63;
    const char* wb = reinterpret_cast<const char*>(wTs);

    const char* gbase = reinterpret_cast<const char*>(aggb) + (size_t)row0 * 512;
    #pragma unroll
    for (int q = 0; q < 8; ++q) {
        int off = wv * 8192 + q * 1024;
        gload16(gbase + off + l * 16, s_a + off);
    }
    #pragma unroll
    for (int i = 0; i < 4; ++i) {
        int off = wv * 4096 + i * 1024;
        gload16(wb + off + l * 16, s_b + off);
    }
    __syncthreads();

    f32x4 acc[16];
    #pragma unroll
    for (int ct = 0; ct < 16; ++ct) acc[ct] = (f32x4){0.f, 0.f, 0.f, 0.f};

    const int lr = wv * 16 + (l & 15);
    const int g = l >> 4;
    for (int ks = 0; ks < 8; ++ks) {
        const int kb = ks * 32 + g * 8;
        const int ab = (lr * 512 + kb * 2) ^ ((lr & 7) << 4);
        s16x8 af = *reinterpret_cast<const s16x8*>(s_a + ab);
        #pragma unroll
        for (int ct = 0; ct < 16; ++ct) {
            int col = ct * 16 + (l & 15);
            int bb = (col * 64 + g * 16) ^ ((col & 7) << 4);
            s16x8 bf = *reinterpret_cast<const s16x8*>(s_b + bb);
            acc[ct] = __builtin_amdgcn_mfma_f32_16x16x32_bf16(af, bf, acc[ct], 0, 0, 0);
        }
        __syncthreads();
        if (ks < 7) {
            #pragma unroll
            for (int i = 0; i < 4; ++i) {
                int off = wv * 4096 + i * 1024;
                gload16(wb + (size_t)(ks + 1) * 16384 + off + l * 16, s_b + off);
            }
            __syncthreads();
        }
    }

    const int rbase = row0 + wv * 16 + (l >> 4) * 4;
    const int cb = l & 15;
    #pragma unroll
    for (int ct = 0; ct < 16; ++ct) {
        #pragma unroll
        for (int r = 0; r < 4; ++r) {
            int row = rbase + r;
            if (row < n_rows)
                out[(size_t)row * D + ct * 16 + cb] = fmaxf(acc[ct][r], 0.f);
        }
    }
}

__global__ __launch_bounds__(256) void gemm_mfma(const unsigned short* __restrict__ wTs,
                                                 float* __restrict__ out, int n_rows) {
    __shared__ __align__(16) unsigned char s_a[BM * 512];
    __shared__ __align__(16) unsigned char s_b[16384];
    const int t = threadIdx.x;
    const int row0 = blockIdx.x * BM;
    const int wv = t >> 6;
    const int l = t & 63;
    const char* wb = reinterpret_cast<const char*>(wTs);

    #pragma unroll
    for (int i = 0; i < 4; ++i) {
        int off = wv * 4096 + i * 1024;
        gload16(wb + off + l * 16, s_b + off);
    }
    #pragma unroll
    for (int i = 0; i < 16; ++i) {
        int f4 = t + 256 * i;
        int row = f4 >> 6;
        int kc = f4 & 63;
        int grow = row0 + row;
        if (grow >= n_rows) grow = n_rows - 1;
        float4 v = *reinterpret_cast<const float4*>(out + (size_t)grow * D + kc * 4);
        uint2 u;
        u.x = f2bf(v.x) | (f2bf(v.y) << 16);
        u.y = f2bf(v.z) | (f2bf(v.w) << 16);
        int byte = (row * 512 + kc * 8) ^ ((row & 7) << 4);
        *reinterpret_cast<uint2*>(s_a + byte) = u;
    }
    __syncthreads();

    f32x4 acc[16];
    #pragma unroll
    for (int ct = 0; ct < 16; ++ct) acc[ct] = (f32x4){0.f, 0.f, 0.f, 0.f};

    const int lr = wv * 16 + (l & 15);
    const int g = l >> 4;
    for (int ks = 0; ks < 8; ++ks) {
        const int kb = ks * 32 + g * 8;
        const int ab = (lr * 512 + kb * 2) ^ ((lr & 7) << 4);
        s16x8 af = *reinterpret_cast<const s16x8*>(s_a + ab);
        #pragma unroll
        for (int ct = 0; ct < 16; ++ct) {
            int col = ct * 16 + (l & 15);
            int bb = (col * 64 + g * 16) ^ ((col & 7) << 4);
            s16x8 bf = *reinterpret_cast<const s16x8*>(s_b + bb);
            acc[ct] = __builtin_amdgcn_mfma_f32_16x16x32_bf16(af, bf, acc[ct], 0, 0, 0);
        }
        __syncthreads();
        if (ks < 7) {
            #pragma unroll
            for (int i = 0; i < 4; ++i) {
                int off = wv * 4096 + i * 1024;
                gload16(wb + (size_t)(ks + 1) * 16384 + off + l * 16, s_b + off);
            }
            __syncthreads();
        }
    }

    const int rbase = row0 + wv * 16 + (l >> 4) * 4;
    const int cb = l & 15;
    #pragma unroll
    for (int ct = 0; ct < 16; ++ct) {
        #pragma unroll
        for (int r = 0; r < 4; ++r) {
            int row = rbase + r;
            if (row < n_rows)
                out[(size_t)row * D + ct * 16 + cb] = fmaxf(acc[ct][r], 0.f);
        }
    }
}

// legacy fp32 GEMM (no-workspace fallback)
__global__ __launch_bounds__(256) void gemm_relu(const float* __restrict__ Wm,
                                                 float* __restrict__ out, int n_rows) {
    __shared__ float s_a[32][D];
    const int row0 = blockIdx.x * 32;
    const int c = threadIdx.x;
    {
        const float4* gsrc = reinterpret_cast<const float4*>(out + (size_t)row0 * D);
        float4* ldst = reinterpret_cast<float4*>(&s_a[0][0]);
        #pragma unroll
        for (int i = 0; i < 8; ++i)
            ldst[threadIdx.x + i * 256] = gsrc[threadIdx.x + i * 256];
    }
    __syncthreads();
    float acc[32];
    #pragma unroll
    for (int r = 0; r < 32; ++r) acc[r] = 0.f;
    #pragma unroll 4
    for (int k = 0; k < D; ++k) {
        float w = Wm[(size_t)k * D + c];
        #pragma unroll
        for (int r = 0; r < 32; ++r) acc[r] += s_a[r][k] * w;
    }
    #pragma unroll
    for (int r = 0; r < 32; ++r) {
        int row = row0 + r;
        if (row < n_rows) out[(size_t)row * D + c] = fmaxf(acc[r], 0.f);
    }
}

extern "C" void kernel_launch(void* const* d_in, const int* in_sizes, int n_in,
                              void* d_out, int out_size, void* d_ws, size_t ws_size,
                              hipStream_t stream) {
    const float* feat = (const float*)d_in[0];
    const float* W    = (const float*)d_in[1];
    const int*   src  = (const int*)d_in[2];
    const int*   dst  = (const int*)d_in[3];
    float* out = (float*)d_out;

    const int N = in_sizes[0] / D;  // 100000
    const int E = in_sizes[2];      // 1600000
    const int Npad = ((N + BM - 1) / BM) * BM;
    auto al = [](size_t x) { return (x + 255) & ~(size_t)255; };

    const int nranges = (N + RN - 1) / RN;
    const int gemm_blocks = (N + BM - 1) / BM;
    const int gat_blocks = (N + 3) / 4;

    // ---- new tier A2 layout: gcur | ovf_cnt | ovf | streams | featb | wTs | aggb
    const size_t hdr_bytes   = ((size_t)nranges + 1 + 2 * MAXOVF) * 4;
    const size_t strm_off    = al(hdr_bytes);
    const size_t strm_sz     = (size_t)nranges * SCAP * 4;
    const size_t a2_featb_off = al(strm_off + strm_sz);
    const size_t featb_sz    = (size_t)N * D * 2;
    const size_t a2_wt_off   = al(a2_featb_off + featb_sz);
    const size_t wt_sz       = (size_t)D * D * 2;
    const size_t a2_aggb_off = al(a2_wt_off + wt_sz);
    const size_t aggb_sz     = (size_t)Npad * D * 2;
    const size_t need_A2     = a2_aggb_off + aggb_sz;

    // ---- old tier layouts
    const size_t cap_bytes = ((size_t)N + 1 + 2 * MAXOVF + (size_t)N * CAP) * 4;
    const size_t featb_off = al(cap_bytes);
    const size_t wt_off    = al(featb_off + featb_sz);
    const size_t aggb_off  = al(wt_off + wt_sz);
    const size_t need_A    = aggb_off + aggb_sz;
    const size_t need_B    = wt_off + wt_sz;
    const size_t need_C    = cap_bytes;
    const size_t need_csr  = ((size_t)3 * N + 1 + (size_t)E) * 4;

    if (ws_size >= need_A2 && nranges <= NRANGES_MAX) {
        char* base = (char*)d_ws;
        int* gcur    = (int*)base;
        int* ovf_cnt = gcur + nranges;
        int* ovf     = ovf_cnt + 1;
        int* streams = (int*)(base + strm_off);
        unsigned short* featb = (unsigned short*)(base + a2_featb_off);
        unsigned short* wTs   = (unsigned short*)(base + a2_wt_off);
        unsigned short* aggb  = (unsigned short*)(base + a2_aggb_off);

        k_zero<<<(nranges + 1 + 255) / 256, 256, 0, stream>>>(gcur, nranges + 1);
        k_f2b<<<2048, 256, 0, stream>>>(feat, featb, (long)N * D / 8);
        k_wTs<<<D, 256, 0, stream>>>(W, wTs);
        k_part<<<(E + PCH - 1) / PCH, PTH, 0, stream>>>(src, dst, gcur, streams,
                                                        ovf, ovf_cnt, E, nranges);
        k_sg<<<nranges, 512, 0, stream>>>(featb, gcur, streams, ovf, ovf_cnt, aggb, N);
        gemm_mfma_b<<<gemm_blocks, 256, 0, stream>>>(aggb, wTs, out, N);
    } else if (ws_size >= need_C) {
        char* base = (char*)d_ws;
        int* counts  = (int*)base;
        int* ovf_cnt = counts + N;
        int* ovf     = ovf_cnt + 1;
        int* buckets = ovf + 2 * MAXOVF;

        k_zero<<<(N + 1 + 255) / 256, 256, 0, stream>>>(counts, N + 1);

        if (ws_size >= need_A) {
            unsigned short* featb = (unsigned short*)(base + featb_off);
            unsigned short* wTs   = (unsigned short*)(base + wt_off);
            unsigned short* aggb  = (unsigned short*)(base + aggb_off);
            k_f2b<<<2048, 256, 0, stream>>>(feat, featb, (long)N * D / 8);
            k_wTs<<<D, 256, 0, stream>>>(W, wTs);
            k_fillcap<<<2048, 256, 0, stream>>>(src, dst, counts, buckets, ovf, ovf_cnt, E);
            g_bf_aggb<<<gat_blocks, 256, 0, stream>>>(featb, counts, buckets, ovf, ovf_cnt, aggb, N);
            gemm_mfma_b<<<gemm_blocks, 256, 0, stream>>>(aggb, wTs, out, N);
        } else if (ws_size >= need_B) {
            unsigned short* featb = (unsigned short*)(base + featb_off);
            unsigned short* wTs   = (unsigned short*)(base + wt_off);
            k_f2b<<<2048, 256, 0, stream>>>(feat, featb, (long)N * D / 8);
            k_wTs<<<D, 256, 0, stream>>>(W, wTs);
            k_fillcap<<<2048, 256, 0, stream>>>(src, dst, counts, buckets, ovf, ovf_cnt, E);
            g_bf_out<<<gat_blocks, 256, 0, stream>>>(featb, counts, buckets, ovf, ovf_cnt, out, N);
            gemm_mfma<<<gemm_blocks, 256, 0, stream>>>(wTs, out, N);
        } else {
            unsigned short* wTs = (unsigned short*)(((uintptr_t)buckets + 255) & ~(uintptr_t)255);
            k_fillcap<<<2048, 256, 0, stream>>>(src, dst, counts, buckets, ovf, ovf_cnt, E);
            g_f32_out<<<gat_blocks, 256, 0, stream>>>(feat, counts, buckets, ovf, ovf_cnt, out, N);
            k_wTs<<<D, 256, 0, stream>>>(W, wTs);
            gemm_mfma<<<gemm_blocks, 256, 0, stream>>>(wTs, out, N);
        }
    } else if (ws_size >= need_csr) {
        int* counts  = (int*)d_ws;
        int* offsets = counts + N;
        int* cursor  = offsets + N + 1;
        int* buckets = cursor + N;

        k_zero<<<(N + 255) / 256, 256, 0, stream>>>(counts, N);
        k_hist<<<2048, 256, 0, stream>>>(dst, counts, E);
        k_scan<<<1, SCAN_THREADS, 0, stream>>>(counts, offsets, cursor, N);
        k_fill<<<2048, 256, 0, stream>>>(src, dst, cursor, buckets, E);
        k_gather_csr<<<gat_blocks, 256, 0, stream>>>(feat, offsets, buckets, out, N);
        unsigned short* wTs =
            (unsigned short*)(((uintptr_t)buckets + 255) & ~(uintptr_t)255);
        k_wTs<<<D, 256, 0, stream>>>(W, wTs);
        gemm_mfma<<<gemm_blocks, 256, 0, stream>>>(wTs, out, N);
    } else {
        long n4 = (long)N * D / 4;
        gc_copy<<<(int)((n4 + 255) / 256), 256, 0, stream>>>(feat, out, n4);
        gc_scatter<<<(E + 3) / 4, 256, 0, stream>>>(feat, src, dst, out, E);
        gemm_relu<<<(N + 31) / 32, 256, 0, stream>>>(W, out, N);
    }
}

// Round 10
// 254.098 us; speedup vs baseline: 1.3604x; 1.0166x over previous
//
#include <hip/hip_runtime.h>

#define D 256
#define SCAN_THREADS 1024
#define CAP 32
#define MAXOVF 4096
#define BM 64

// range-partition params
#define RN 64           // nodes per range
#define RSH 6
#define SCAP 2048       // stream capacity per range (mean 1024)
#define PCH 8192        // edges per k_part block
#define PTH 512         // k_part threads
#define NRANGES_MAX 2048
#define SGT 256         // k_sg threads (4 waves)

typedef float f32x4 __attribute__((ext_vector_type(4)));
typedef short s16x8 __attribute__((ext_vector_type(8)));

__device__ inline unsigned int f2bf(float x) {
    unsigned int u = __float_as_uint(x);
    return (u + 0x7FFFu + ((u >> 16) & 1u)) >> 16;  // RNE, low 16 bits valid
}
__device__ inline float bflo(unsigned int u) { return __uint_as_float(u << 16); }
__device__ inline float bfhi(unsigned int u) { return __uint_as_float(u & 0xFFFF0000u); }

// ================= small utility kernels =================

__global__ void k_zero(int* __restrict__ p, int n) {
    int i = blockIdx.x * blockDim.x + threadIdx.x;
    if (i < n) p[i] = 0;
}

__global__ __launch_bounds__(256) void k_f2b(const float* __restrict__ f,
                                             unsigned short* __restrict__ fb, long n8) {
    for (long i = blockIdx.x * 256L + threadIdx.x; i < n8; i += (long)gridDim.x * 256) {
        const float4* p = reinterpret_cast<const float4*>(f + i * 8);
        float4 a = p[0], b = p[1];
        uint4 u;
        u.x = f2bf(a.x) | (f2bf(a.y) << 16);
        u.y = f2bf(a.z) | (f2bf(a.w) << 16);
        u.z = f2bf(b.x) | (f2bf(b.y) << 16);
        u.w = f2bf(b.z) | (f2bf(b.w) << 16);
        reinterpret_cast<uint4*>(fb)[i] = u;
    }
}

// W[k][col] fp32 -> wTs: per-ks staged-B LDS image (8 blocks x 16KB).
__global__ __launch_bounds__(256) void k_wTs(const float* __restrict__ W,
                                             unsigned short* __restrict__ wTs) {
    int col = blockIdx.x;   // 0..255
    int k = threadIdx.x;    // 0..255
    unsigned short v = (unsigned short)f2bf(W[(size_t)k * D + col]);
    int ks = k >> 5;
    int byte = ((col << 6) + (((k >> 3) & 3) << 4) + ((k & 7) << 1)) ^ ((col & 7) << 4);
    *reinterpret_cast<unsigned short*>(
        reinterpret_cast<char*>(wTs) + (size_t)ks * 16384 + byte) = v;
}

// ================= phase 1: range partition (dense appends) =================
__global__ __launch_bounds__(PTH) void k_part(const int* __restrict__ src,
                                              const int* __restrict__ dst,
                                              int* __restrict__ gcur,
                                              int* __restrict__ streams,
                                              int* __restrict__ ovf,
                                              int* __restrict__ ovf_cnt,
                                              int E, int nranges) {
    __shared__ int hist[NRANGES_MAX];
    __shared__ int base[NRANGES_MAX];
    __shared__ int off[NRANGES_MAX];
    const int t = threadIdx.x;
    const long e0 = (long)blockIdx.x * PCH;
    for (int i = t; i < nranges; i += PTH) hist[i] = 0;
    __syncthreads();
    int md[PCH / PTH], ms[PCH / PTH];
    #pragma unroll
    for (int i = 0; i < PCH / PTH; ++i) {
        long e = e0 + (long)i * PTH + t;
        if (e < E) {
            md[i] = dst[e];
            ms[i] = src[e];
            atomicAdd(&hist[md[i] >> RSH], 1);
        } else {
            md[i] = -1;
        }
    }
    __syncthreads();
    for (int i = t; i < nranges; i += PTH) {
        int h = hist[i];
        base[i] = h ? atomicAdd(&gcur[i], h) : 0;
        off[i] = 0;
    }
    __syncthreads();
    #pragma unroll
    for (int i = 0; i < PCH / PTH; ++i) {
        if (md[i] >= 0) {
            int r = md[i] >> RSH;
            int p = base[r] + atomicAdd(&off[r], 1);
            if (p < SCAP) {
                streams[(size_t)r * SCAP + p] = (ms[i] << RSH) | (md[i] & (RN - 1));
            } else {
                int o = atomicAdd(ovf_cnt, 1);
                if (o < MAXOVF) { ovf[2 * o] = ms[i]; ovf[2 * o + 1] = md[i]; }
            }
        }
    }
}

// ================= phase 2: LDS counting-sort + fused gather =================
// One block (256 thr, 4 waves) per range of 64 nodes.
__global__ __launch_bounds__(SGT) void k_sg(const unsigned short* __restrict__ featb,
                                            const int* __restrict__ gcur,
                                            const int* __restrict__ streams,
                                            const int* __restrict__ ovf,
                                            const int* __restrict__ ovf_cnt,
                                            unsigned short* __restrict__ aggb, int N) {
    __shared__ int hist[RN], basei[RN], off[RN], scn[RN];
    __shared__ int elist[SCAP];
    const int r = blockIdx.x;
    const int t = threadIdx.x;
    const int node0 = r << RSH;
    int cnt = gcur[r];
    if (cnt > SCAP) cnt = SCAP;
    if (t < RN) { hist[t] = 0; off[t] = 0; }
    __syncthreads();
    int ent[SCAP / SGT];
    #pragma unroll
    for (int i = 0; i < SCAP / SGT; ++i) {
        int p = t + i * SGT;
        if (p < cnt) {
            ent[i] = streams[(size_t)r * SCAP + p];
            atomicAdd(&hist[ent[i] & (RN - 1)], 1);
        } else {
            ent[i] = -1;
        }
    }
    __syncthreads();
    if (t < RN) scn[t] = hist[t];
    __syncthreads();
    for (int st = 1; st < RN; st <<= 1) {
        int v = 0;
        if (t < RN && t >= st) v = scn[t - st];
        __syncthreads();
        if (t < RN) scn[t] += v;
        __syncthreads();
    }
    if (t < RN) basei[t] = scn[t] - hist[t];
    __syncthreads();
    #pragma unroll
    for (int i = 0; i < SCAP / SGT; ++i) {
        if (ent[i] >= 0) {
            int ln_ = ent[i] & (RN - 1);
            int p = basei[ln_] + atomicAdd(&off[ln_], 1);
            elist[p] = ent[i] >> RSH;
        }
    }
    __syncthreads();
    int ovfn = *ovf_cnt;
    if (ovfn > MAXOVF) ovfn = MAXOVF;
    const int wv = t >> 6;   // 0..3
    const int l = t & 63;
    for (int k = 0; k < RN / 4; ++k) {
        int ln_ = wv * (RN / 4) + k;
        int node = node0 + ln_;
        if (node >= N) continue;
        int cb = hist[ln_];
        int bb = basei[ln_];
        uint2 u = reinterpret_cast<const uint2*>(featb + (size_t)node * D)[l];
        float4 acc;
        acc.x = bflo(u.x); acc.y = bfhi(u.x); acc.z = bflo(u.y); acc.w = bfhi(u.y);
        int j = 0;
        for (; j + 16 <= cb; j += 16) {
            int s[16];
            #pragma unroll
            for (int q = 0; q < 16; ++q) s[q] = elist[bb + j + q];
            uint2 v[16];
            #pragma unroll
            for (int q = 0; q < 16; ++q)
                v[q] = reinterpret_cast<const uint2*>(featb + (size_t)s[q] * D)[l];
            #pragma unroll
            for (int q = 0; q < 16; ++q) {
                acc.x += bflo(v[q].x); acc.y += bfhi(v[q].x);
                acc.z += bflo(v[q].y); acc.w += bfhi(v[q].y);
            }
        }
        for (; j + 8 <= cb; j += 8) {
            int s[8];
            #pragma unroll
            for (int q = 0; q < 8; ++q) s[q] = elist[bb + j + q];
            uint2 v[8];
            #pragma unroll
            for (int q = 0; q < 8; ++q)
                v[q] = reinterpret_cast<const uint2*>(featb + (size_t)s[q] * D)[l];
            #pragma unroll
            for (int q = 0; q < 8; ++q) {
                acc.x += bflo(v[q].x); acc.y += bfhi(v[q].x);
                acc.z += bflo(v[q].y); acc.w += bfhi(v[q].y);
            }
        }
        for (; j < cb; ++j) {
            uint2 v = reinterpret_cast<const uint2*>(featb + (size_t)elist[bb + j] * D)[l];
            acc.x += bflo(v.x); acc.y += bfhi(v.x);
            acc.z += bflo(v.y); acc.w += bfhi(v.y);
        }
        if (ovfn > 0) {
            for (int e = 0; e < ovfn; ++e) {
                if (ovf[2 * e + 1] == node) {
                    uint2 v = reinterpret_cast<const uint2*>(featb + (size_t)ovf[2 * e] * D)[l];
                    acc.x += bflo(v.x); acc.y += bfhi(v.x);
                    acc.z += bflo(v.y); acc.w += bfhi(v.y);
                }
            }
        }
        uint2 w;
        w.x = f2bf(acc.x) | (f2bf(acc.y) << 16);
        w.y = f2bf(acc.z) | (f2bf(acc.w) << 16);
        unsigned short* rowp = aggb + (size_t)node * D;
        int us = (l * 4) ^ ((node & 7) << 3);
        *reinterpret_cast<uint2*>(rowp + us) = w;
    }
}

// ================= capacity-bucket build (fallback) =========
__global__ void k_fillcap(const int* __restrict__ src, const int* __restrict__ dst,
                          int* __restrict__ counts, int* __restrict__ buckets,
                          int* __restrict__ ovf, int* __restrict__ ovf_cnt, int E) {
    for (int e = blockIdx.x * blockDim.x + threadIdx.x; e < E;
         e += gridDim.x * blockDim.x) {
        int d = dst[e];
        int pos = atomicAdd(&counts[d], 1);
        if (pos < CAP) {
            buckets[(size_t)d * CAP + pos] = src[e];
        } else {
            int o = atomicAdd(ovf_cnt, 1);
            if (o < MAXOVF) {
                ovf[2 * o + 0] = src[e];
                ovf[2 * o + 1] = d;
            }
        }
    }
}

// ================= gathers (fallback tiers) =================

#define GAT_BODY(LOAD, ACCUM)                                                  \
    int j = 0;                                                                 \
    for (; j + 16 <= cnt; j += 16) {                                           \
        int s[16];                                                             \
        _Pragma("unroll") for (int q = 0; q < 16; ++q) s[q] = bk[j + q];       \
        LOAD(16)                                                               \
        ACCUM(16)                                                              \
    }                                                                          \
    for (; j + 8 <= cnt; j += 8) {                                             \
        int s[8];                                                              \
        _Pragma("unroll") for (int q = 0; q < 8; ++q) s[q] = bk[j + q];        \
        LOAD(8)                                                                \
        ACCUM(8)                                                               \
    }

__global__ __launch_bounds__(256) void g_bf_aggb(const unsigned short* __restrict__ fb,
                                                 const int* __restrict__ counts,
                                                 const int* __restrict__ buckets,
                                                 const int* __restrict__ ovf,
                                                 const int* __restrict__ ovf_cnt,
                                                 unsigned short* __restrict__ aggb, int N) {
    int node = (int)((blockIdx.x * (long)blockDim.x + threadIdx.x) >> 6);
    int ln = threadIdx.x & 63;
    if (node >= N) return;
    int cnt_raw = counts[node];
    int cnt = cnt_raw > CAP ? CAP : cnt_raw;
    const int* bk = buckets + (size_t)node * CAP;
    uint2 u = reinterpret_cast<const uint2*>(fb + (size_t)node * D)[ln];
    float4 acc;
    acc.x = bflo(u.x); acc.y = bfhi(u.x); acc.z = bflo(u.y); acc.w = bfhi(u.y);
#define BLOAD(W_)                                                              \
    uint2 v[W_];                                                               \
    _Pragma("unroll") for (int q = 0; q < W_; ++q)                             \
        v[q] = reinterpret_cast<const uint2*>(fb + (size_t)s[q] * D)[ln];
#define BACC(W_)                                                               \
    _Pragma("unroll") for (int q = 0; q < W_; ++q) {                           \
        acc.x += bflo(v[q].x); acc.y += bfhi(v[q].x);                          \
        acc.z += bflo(v[q].y); acc.w += bfhi(v[q].y);                          \
    }
    GAT_BODY(BLOAD, BACC)
    for (; j < cnt; ++j) {
        uint2 v = reinterpret_cast<const uint2*>(fb + (size_t)bk[j] * D)[ln];
        acc.x += bflo(v.x); acc.y += bfhi(v.x);
        acc.z += bflo(v.y); acc.w += bfhi(v.y);
    }
    if (cnt_raw > CAP) {
        int m = *ovf_cnt;
        if (m > MAXOVF) m = MAXOVF;
        for (int e = 0; e < m; ++e) {
            if (ovf[2 * e + 1] == node) {
                uint2 v = reinterpret_cast<const uint2*>(fb + (size_t)ovf[2 * e] * D)[ln];
                acc.x += bflo(v.x); acc.y += bfhi(v.x);
                acc.z += bflo(v.y); acc.w += bfhi(v.y);
            }
        }
    }
    uint2 w;
    w.x = f2bf(acc.x) | (f2bf(acc.y) << 16);
    w.y = f2bf(acc.z) | (f2bf(acc.w) << 16);
    unsigned short* rowp = aggb + (size_t)node * D;
    int us = (ln * 4) ^ ((node & 7) << 3);
    *reinterpret_cast<uint2*>(rowp + us) = w;
}

__global__ __launch_bounds__(256) void g_bf_out(const unsigned short* __restrict__ fb,
                                                const int* __restrict__ counts,
                                                const int* __restrict__ buckets,
                                                const int* __restrict__ ovf,
                                                const int* __restrict__ ovf_cnt,
                                                float* __restrict__ out, int N) {
    int node = (int)((blockIdx.x * (long)blockDim.x + threadIdx.x) >> 6);
    int ln = threadIdx.x & 63;
    if (node >= N) return;
    int cnt_raw = counts[node];
    int cnt = cnt_raw > CAP ? CAP : cnt_raw;
    const int* bk = buckets + (size_t)node * CAP;
    uint2 u = reinterpret_cast<const uint2*>(fb + (size_t)node * D)[ln];
    float4 acc;
    acc.x = bflo(u.x); acc.y = bfhi(u.x); acc.z = bflo(u.y); acc.w = bfhi(u.y);
    GAT_BODY(BLOAD, BACC)
    for (; j < cnt; ++j) {
        uint2 v = reinterpret_cast<const uint2*>(fb + (size_t)bk[j] * D)[ln];
        acc.x += bflo(v.x); acc.y += bfhi(v.x);
        acc.z += bflo(v.y); acc.w += bfhi(v.y);
    }
    if (cnt_raw > CAP) {
        int m = *ovf_cnt;
        if (m > MAXOVF) m = MAXOVF;
        for (int e = 0; e < m; ++e) {
            if (ovf[2 * e + 1] == node) {
                uint2 v = reinterpret_cast<const uint2*>(fb + (size_t)ovf[2 * e] * D)[ln];
                acc.x += bflo(v.x); acc.y += bfhi(v.x);
                acc.z += bflo(v.y); acc.w += bfhi(v.y);
            }
        }
    }
    reinterpret_cast<float4*>(out + (size_t)node * D)[ln] = acc;
}

__global__ __launch_bounds__(256) void g_f32_out(const float* __restrict__ feat,
                                                 const int* __restrict__ counts,
                                                 const int* __restrict__ buckets,
                                                 const int* __restrict__ ovf,
                                                 const int* __restrict__ ovf_cnt,
                                                 float* __restrict__ out, int N) {
    int node = (int)((blockIdx.x * (long)blockDim.x + threadIdx.x) >> 6);
    int ln = threadIdx.x & 63;
    if (node >= N) return;
    int cnt_raw = counts[node];
    int cnt = cnt_raw > CAP ? CAP : cnt_raw;
    const int* bk = buckets + (size_t)node * CAP;
    float4 acc = reinterpret_cast<const float4*>(feat + (size_t)node * D)[ln];
#define FLOAD(W_)                                                              \
    float4 v[W_];                                                              \
    _Pragma("unroll") for (int q = 0; q < W_; ++q)                             \
        v[q] = reinterpret_cast<const float4*>(feat + (size_t)s[q] * D)[ln];
#define FACC(W_)                                                               \
    _Pragma("unroll") for (int q = 0; q < W_; ++q) {                           \
        acc.x += v[q].x; acc.y += v[q].y; acc.z += v[q].z; acc.w += v[q].w;    \
    }
    GAT_BODY(FLOAD, FACC)
    for (; j < cnt; ++j) {
        float4 v = reinterpret_cast<const float4*>(feat + (size_t)bk[j] * D)[ln];
        acc.x += v.x; acc.y += v.y; acc.z += v.z; acc.w += v.w;
    }
    if (cnt_raw > CAP) {
        int m = *ovf_cnt;
        if (m > MAXOVF) m = MAXOVF;
        for (int e = 0; e < m; ++e) {
            if (ovf[2 * e + 1] == node) {
                float4 v = reinterpret_cast<const float4*>(feat + (size_t)ovf[2 * e] * D)[ln];
                acc.x += v.x; acc.y += v.y; acc.z += v.z; acc.w += v.w;
            }
        }
    }
    reinterpret_cast<float4*>(out + (size_t)node * D)[ln] = acc;
}

// ================= CSR build (fallback path) =================

__global__ void k_hist(const int* __restrict__ dst, int* __restrict__ counts, int E) {
    for (int e = blockIdx.x * blockDim.x + threadIdx.x; e < E;
         e += gridDim.x * blockDim.x)
        atomicAdd(&counts[dst[e]], 1);
}

__global__ __launch_bounds__(SCAN_THREADS) void k_scan(const int* __restrict__ counts,
                                                       int* __restrict__ offsets,
                                                       int* __restrict__ cursor,
                                                       int N) {
    __shared__ int s[SCAN_THREADS];
    const int t = threadIdx.x;
    const int chunk = (N + SCAN_THREADS - 1) / SCAN_THREADS;
    const int lo = t * chunk;
    const int hi = min(N, lo + chunk);
    int local = 0;
    for (int i = lo; i < hi; ++i) local += counts[i];
    s[t] = local;
    __syncthreads();
    for (int str = 1; str < SCAN_THREADS; str <<= 1) {
        int v = (t >= str) ? s[t - str] : 0;
        __syncthreads();
        s[t] += v;
        __syncthreads();
    }
    int run = s[t] - local;
    for (int i = lo; i < hi; ++i) {
        offsets[i] = run;
        cursor[i] = run;
        run += counts[i];
    }
    if (t == SCAN_THREADS - 1) offsets[N] = s[SCAN_THREADS - 1];
}

__global__ void k_fill(const int* __restrict__ src, const int* __restrict__ dst,
                       int* __restrict__ cursor, int* __restrict__ buckets, int E) {
    for (int e = blockIdx.x * blockDim.x + threadIdx.x; e < E;
         e += gridDim.x * blockDim.x) {
        int pos = atomicAdd(&cursor[dst[e]], 1);
        buckets[pos] = src[e];
    }
}

__global__ __launch_bounds__(256) void k_gather_csr(const float* __restrict__ feat,
                                                    const int* __restrict__ offsets,
                                                    const int* __restrict__ buckets,
                                                    float* __restrict__ out, int N) {
    int wave = (int)((blockIdx.x * (long)blockDim.x + threadIdx.x) >> 6);
    int lane = threadIdx.x & 63;
    if (wave >= N) return;
    const int off = offsets[wave];
    const int end = offsets[wave + 1];
    float4 acc = reinterpret_cast<const float4*>(feat + (size_t)wave * D)[lane];
    int j = off;
    for (; j + 8 <= end; j += 8) {
        int s[8];
        #pragma unroll
        for (int q = 0; q < 8; ++q) s[q] = buckets[j + q];
        float4 v[8];
        #pragma unroll
        for (int q = 0; q < 8; ++q)
            v[q] = reinterpret_cast<const float4*>(feat + (size_t)s[q] * D)[lane];
        #pragma unroll
        for (int q = 0; q < 8; ++q) {
            acc.x += v[q].x; acc.y += v[q].y; acc.z += v[q].z; acc.w += v[q].w;
        }
    }
    for (; j < end; ++j) {
        float4 v = reinterpret_cast<const float4*>(feat + (size_t)buckets[j] * D)[lane];
        acc.x += v.x; acc.y += v.y; acc.z += v.z; acc.w += v.w;
    }
    reinterpret_cast<float4*>(out + (size_t)wave * D)[lane] = acc;
}

// ================= atomic scatter (last-resort) =================

__global__ __launch_bounds__(256) void gc_copy(const float* __restrict__ feat,
                                               float* __restrict__ agg, long n4) {
    long i = (long)blockIdx.x * blockDim.x + threadIdx.x;
    if (i < n4)
        reinterpret_cast<float4*>(agg)[i] = reinterpret_cast<const float4*>(feat)[i];
}

__global__ __launch_bounds__(256) void gc_scatter(const float* __restrict__ feat,
                                                  const int* __restrict__ src,
                                                  const int* __restrict__ dst,
                                                  float* __restrict__ agg, int n_edges) {
    int wave = (int)((blockIdx.x * (long)blockDim.x + threadIdx.x) >> 6);
    int lane = threadIdx.x & 63;
    if (wave >= n_edges) return;
    int s = src[wave];
    int d = dst[wave];
    const float4 v = reinterpret_cast<const float4*>(feat + (size_t)s * D)[lane];
    float* p = agg + (size_t)d * D + (size_t)lane * 4;
    atomicAdd(p + 0, v.x);
    atomicAdd(p + 1, v.y);
    atomicAdd(p + 2, v.z);
    atomicAdd(p + 3, v.w);
}

// ================= MFMA GEMMs (B staged per-ks into LDS) =================

__device__ inline void gload16(const char* g, const unsigned char* lds) {
    __builtin_amdgcn_global_load_lds(
        (const __attribute__((address_space(1))) void*)g,
        (__attribute__((address_space(3))) void*)lds, 16, 0, 0);
}

__global__ __launch_bounds__(256) void gemm_mfma_b(const unsigned short* __restrict__ aggb,
                                                   const unsigned short* __restrict__ wTs,
                                                   float* __restrict__ out, int n_rows) {
    __shared__ __align__(16) unsigned char s_a[BM * 512];
    __shared__ __align__(16) unsigned char s_b[16384];
    const int t = threadIdx.x;
    const int row0 = blockIdx.x * BM;
    const int wv = t >> 6;
    const int l = t & 63;
    const char* wb = reinterpret_cast<const char*>(wTs);

    const char* gbase = reinterpret_cast<const char*>(aggb) + (size_t)row0 * 512;
    #pragma unroll
    for (int q = 0; q < 8; ++q) {
        int off = wv * 8192 + q * 1024;
        gload16(gbase + off + l * 16, s_a + off);
    }
    #pragma unroll
    for (int i = 0; i < 4; ++i) {
        int off = wv * 4096 + i * 1024;
        gload16(wb + off + l * 16, s_b + off);
    }
    __syncthreads();

    f32x4 acc[16];
    #pragma unroll
    for (int ct = 0; ct < 16; ++ct) acc[ct] = (f32x4){0.f, 0.f, 0.f, 0.f};

    const int lr = wv * 16 + (l & 15);
    const int g = l >> 4;
    for (int ks = 0; ks < 8; ++ks) {
        const int kb = ks * 32 + g * 8;
        const int ab = (lr * 512 + kb * 2) ^ ((lr & 7) << 4);
        s16x8 af = *reinterpret_cast<const s16x8*>(s_a + ab);
        #pragma unroll
        for (int ct = 0; ct < 16; ++ct) {
            int col = ct * 16 + (l & 15);
            int bb = (col * 64 + g * 16) ^ ((col & 7) << 4);
            s16x8 bf = *reinterpret_cast<const s16x8*>(s_b + bb);
            acc[ct] = __builtin_amdgcn_mfma_f32_16x16x32_bf16(af, bf, acc[ct], 0, 0, 0);
        }
        __syncthreads();
        if (ks < 7) {
            #pragma unroll
            for (int i = 0; i < 4; ++i) {
                int off = wv * 4096 + i * 1024;
                gload16(wb + (size_t)(ks + 1) * 16384 + off + l * 16, s_b + off);
            }
            __syncthreads();
        }
    }

    const int rbase = row0 + wv * 16 + (l >> 4) * 4;
    const int cb = l & 15;
    #pragma unroll
    for (int ct = 0; ct < 16; ++ct) {
        #pragma unroll
        for (int r = 0; r < 4; ++r) {
            int row = rbase + r;
            if (row < n_rows)
                out[(size_t)row * D + ct * 16 + cb] = fmaxf(acc[ct][r], 0.f);
        }
    }
}

__global__ __launch_bounds__(256) void gemm_mfma(const unsigned short* __restrict__ wTs,
                                                 float* __restrict__ out, int n_rows) {
    __shared__ __align__(16) unsigned char s_a[BM * 512];
    __shared__ __align__(16) unsigned char s_b[16384];
    const int t = threadIdx.x;
    const int row0 = blockIdx.x * BM;
    const int wv = t >> 6;
    const int l = t & 63;
    const char* wb = reinterpret_cast<const char*>(wTs);

    #pragma unroll
    for (int i = 0; i < 4; ++i) {
        int off = wv * 4096 + i * 1024;
        gload16(wb + off + l * 16, s_b + off);
    }
    #pragma unroll
    for (int i = 0; i < 16; ++i) {
        int f4 = t + 256 * i;
        int row = f4 >> 6;
        int kc = f4 & 63;
        int grow = row0 + row;
        if (grow >= n_rows) grow = n_rows - 1;
        float4 v = *reinterpret_cast<const float4*>(out + (size_t)grow * D + kc * 4);
        uint2 u;
        u.x = f2bf(v.x) | (f2bf(v.y) << 16);
        u.y = f2bf(v.z) | (f2bf(v.w) << 16);
        int byte = (row * 512 + kc * 8) ^ ((row & 7) << 4);
        *reinterpret_cast<uint2*>(s_a + byte) = u;
    }
    __syncthreads();

    f32x4 acc[16];
    #pragma unroll
    for (int ct = 0; ct < 16; ++ct) acc[ct] = (f32x4){0.f, 0.f, 0.f, 0.f};

    const int lr = wv * 16 + (l & 15);
    const int g = l >> 4;
    for (int ks = 0; ks < 8; ++ks) {
        const int kb = ks * 32 + g * 8;
        const int ab = (lr * 512 + kb * 2) ^ ((lr & 7) << 4);
        s16x8 af = *reinterpret_cast<const s16x8*>(s_a + ab);
        #pragma unroll
        for (int ct = 0; ct < 16; ++ct) {
            int col = ct * 16 + (l & 15);
            int bb = (col * 64 + g * 16) ^ ((col & 7) << 4);
            s16x8 bf = *reinterpret_cast<const s16x8*>(s_b + bb);
            acc[ct] = __builtin_amdgcn_mfma_f32_16x16x32_bf16(af, bf, acc[ct], 0, 0, 0);
        }
        __syncthreads();
        if (ks < 7) {
            #pragma unroll
            for (int i = 0; i < 4; ++i) {
                int off = wv * 4096 + i * 1024;
                gload16(wb + (size_t)(ks + 1) * 16384 + off + l * 16, s_b + off);
            }
            __syncthreads();
        }
    }

    const int rbase = row0 + wv * 16 + (l >> 4) * 4;
    const int cb = l & 15;
    #pragma unroll
    for (int ct = 0; ct < 16; ++ct) {
        #pragma unroll
        for (int r = 0; r < 4; ++r) {
            int row = rbase + r;
            if (row < n_rows)
                out[(size_t)row * D + ct * 16 + cb] = fmaxf(acc[ct][r], 0.f);
        }
    }
}

// legacy fp32 GEMM (no-workspace fallback)
__global__ __launch_bounds__(256) void gemm_relu(const float* __restrict__ Wm,
                                                 float* __restrict__ out, int n_rows) {
    __shared__ float s_a[32][D];
    const int row0 = blockIdx.x * 32;
    const int c = threadIdx.x;
    {
        const float4* gsrc = reinterpret_cast<const float4*>(out + (size_t)row0 * D);
        float4* ldst = reinterpret_cast<float4*>(&s_a[0][0]);
        #pragma unroll
        for (int i = 0; i < 8; ++i)
            ldst[threadIdx.x + i * 256] = gsrc[threadIdx.x + i * 256];
    }
    __syncthreads();
    float acc[32];
    #pragma unroll
    for (int r = 0; r < 32; ++r) acc[r] = 0.f;
    #pragma unroll 4
    for (int k = 0; k < D; ++k) {
        float w = Wm[(size_t)k * D + c];
        #pragma unroll
        for (int r = 0; r < 32; ++r) acc[r] += s_a[r][k] * w;
    }
    #pragma unroll
    for (int r = 0; r < 32; ++r) {
        int row = row0 + r;
        if (row < n_rows) out[(size_t)row * D + c] = fmaxf(acc[r], 0.f);
    }
}

extern "C" void kernel_launch(void* const* d_in, const int* in_sizes, int n_in,
                              void* d_out, int out_size, void* d_ws, size_t ws_size,
                              hipStream_t stream) {
    const float* feat = (const float*)d_in[0];
    const float* W    = (const float*)d_in[1];
    const int*   src  = (const int*)d_in[2];
    const int*   dst  = (const int*)d_in[3];
    float* out = (float*)d_out;

    const int N = in_sizes[0] / D;  // 100000
    const int E = in_sizes[2];      // 1600000
    const int Npad = ((N + BM - 1) / BM) * BM;
    auto al = [](size_t x) { return (x + 255) & ~(size_t)255; };

    const int nranges = (N + RN - 1) / RN;
    const int gemm_blocks = (N + BM - 1) / BM;
    const int gat_blocks = (N + 3) / 4;

    // ---- tier A2 layout: gcur | ovf_cnt | ovf | streams | featb | wTs | aggb
    const size_t hdr_bytes   = ((size_t)nranges + 1 + 2 * MAXOVF) * 4;
    const size_t strm_off    = al(hdr_bytes);
    const size_t strm_sz     = (size_t)nranges * SCAP * 4;
    const size_t a2_featb_off = al(strm_off + strm_sz);
    const size_t featb_sz    = (size_t)N * D * 2;
    const size_t a2_wt_off   = al(a2_featb_off + featb_sz);
    const size_t wt_sz       = (size_t)D * D * 2;
    const size_t a2_aggb_off = al(a2_wt_off + wt_sz);
    const size_t aggb_sz     = (size_t)Npad * D * 2;
    const size_t need_A2     = a2_aggb_off + aggb_sz;

    // ---- old tier layouts
    const size_t cap_bytes = ((size_t)N + 1 + 2 * MAXOVF + (size_t)N * CAP) * 4;
    const size_t featb_off = al(cap_bytes);
    const size_t wt_off    = al(featb_off + featb_sz);
    const size_t aggb_off  = al(wt_off + wt_sz);
    const size_t need_A    = aggb_off + aggb_sz;
    const size_t need_B    = wt_off + wt_sz;
    const size_t need_C    = cap_bytes;
    const size_t need_csr  = ((size_t)3 * N + 1 + (size_t)E) * 4;

    if (ws_size >= need_A2 && nranges <= NRANGES_MAX) {
        char* base = (char*)d_ws;
        int* gcur    = (int*)base;
        int* ovf_cnt = gcur + nranges;
        int* ovf     = ovf_cnt + 1;
        int* streams = (int*)(base + strm_off);
        unsigned short* featb = (unsigned short*)(base + a2_featb_off);
        unsigned short* wTs   = (unsigned short*)(base + a2_wt_off);
        unsigned short* aggb  = (unsigned short*)(base + a2_aggb_off);

        k_zero<<<(nranges + 1 + 255) / 256, 256, 0, stream>>>(gcur, nranges + 1);
        k_f2b<<<2048, 256, 0, stream>>>(feat, featb, (long)N * D / 8);
        k_wTs<<<D, 256, 0, stream>>>(W, wTs);
        k_part<<<(E + PCH - 1) / PCH, PTH, 0, stream>>>(src, dst, gcur, streams,
                                                        ovf, ovf_cnt, E, nranges);
        k_sg<<<nranges, SGT, 0, stream>>>(featb, gcur, streams, ovf, ovf_cnt, aggb, N);
        gemm_mfma_b<<<gemm_blocks, 256, 0, stream>>>(aggb, wTs, out, N);
    } else if (ws_size >= need_C) {
        char* base = (char*)d_ws;
        int* counts  = (int*)base;
        int* ovf_cnt = counts + N;
        int* ovf     = ovf_cnt + 1;
        int* buckets = ovf + 2 * MAXOVF;

        k_zero<<<(N + 1 + 255) / 256, 256, 0, stream>>>(counts, N + 1);

        if (ws_size >= need_A) {
            unsigned short* featb = (unsigned short*)(base + featb_off);
            unsigned short* wTs   = (unsigned short*)(base + wt_off);
            unsigned short* aggb  = (unsigned short*)(base + aggb_off);
            k_f2b<<<2048, 256, 0, stream>>>(feat, featb, (long)N * D / 8);
            k_wTs<<<D, 256, 0, stream>>>(W, wTs);
            k_fillcap<<<2048, 256, 0, stream>>>(src, dst, counts, buckets, ovf, ovf_cnt, E);
            g_bf_aggb<<<gat_blocks, 256, 0, stream>>>(featb, counts, buckets, ovf, ovf_cnt, aggb, N);
            gemm_mfma_b<<<gemm_blocks, 256, 0, stream>>>(aggb, wTs, out, N);
        } else if (ws_size >= need_B) {
            unsigned short* featb = (unsigned short*)(base + featb_off);
            unsigned short* wTs   = (unsigned short*)(base + wt_off);
            k_f2b<<<2048, 256, 0, stream>>>(feat, featb, (long)N * D / 8);
            k_wTs<<<D, 256, 0, stream>>>(W, wTs);
            k_fillcap<<<2048, 256, 0, stream>>>(src, dst, counts, buckets, ovf, ovf_cnt, E);
            g_bf_out<<<gat_blocks, 256, 0, stream>>>(featb, counts, buckets, ovf, ovf_cnt, out, N);
            gemm_mfma<<<gemm_blocks, 256, 0, stream>>>(wTs, out, N);
        } else {
            unsigned short* wTs = (unsigned short*)(((uintptr_t)buckets + 255) & ~(uintptr_t)255);
            k_fillcap<<<2048, 256, 0, stream>>>(src, dst, counts, buckets, ovf, ovf_cnt, E);
            g_f32_out<<<gat_blocks, 256, 0, stream>>>(feat, counts, buckets, ovf, ovf_cnt, out, N);
            k_wTs<<<D, 256, 0, stream>>>(W, wTs);
            gemm_mfma<<<gemm_blocks, 256, 0, stream>>>(wTs, out, N);
        }
    } else if (ws_size >= need_csr) {
        int* counts  = (int*)d_ws;
        int* offsets = counts + N;
        int* cursor  = offsets + N + 1;
        int* buckets = cursor + N;

        k_zero<<<(N + 255) / 256, 256, 0, stream>>>(counts, N);
        k_hist<<<2048, 256, 0, stream>>>(dst, counts, E);
        k_scan<<<1, SCAN_THREADS, 0, stream>>>(counts, offsets, cursor, N);
        k_fill<<<2048, 256, 0, stream>>>(src, dst, cursor, buckets, E);
        k_gather_csr<<<gat_blocks, 256, 0, stream>>>(feat, offsets, buckets, out, N);
        unsigned short* wTs =
            (unsigned short*)(((uintptr_t)buckets + 255) & ~(uintptr_t)255);
        k_wTs<<<D, 256, 0, stream>>>(W, wTs);
        gemm_mfma<<<gemm_blocks, 256, 0, stream>>>(wTs, out, N);
    } else {
        long n4 = (long)N * D / 4;
        gc_copy<<<(int)((n4 + 255) / 256), 256, 0, stream>>>(feat, out, n4);
        gc_scatter<<<(E + 3) / 4, 256, 0, stream>>>(feat, src, dst, out, E);
        gemm_relu<<<(N + 31) / 32, 256, 0, stream>>>(W, out, N);
    }
}

// Round 11
// 231.070 us; speedup vs baseline: 1.4959x; 1.0997x over previous
//
#include <hip/hip_runtime.h>

#define D 256
#define SCAN_THREADS 1024
#define CAP 32
#define MAXOVF 4096
#define BM 64

// range-partition params
#define RN 32           // nodes per range
#define RSH 5
#define SCAP 1024       // stream capacity per range (mean 512)
#define PCH 8192        // edges per k_part block
#define PTH 512         // k_part threads
#define NRANGES_MAX 4096
#define SGT 256         // k_sg threads (4 waves)

typedef float f32x4 __attribute__((ext_vector_type(4)));
typedef short s16x8 __attribute__((ext_vector_type(8)));

__device__ inline unsigned int f2bf(float x) {
    unsigned int u = __float_as_uint(x);
    return (u + 0x7FFFu + ((u >> 16) & 1u)) >> 16;  // RNE, low 16 bits valid
}
__device__ inline float bflo(unsigned int u) { return __uint_as_float(u << 16); }
__device__ inline float bfhi(unsigned int u) { return __uint_as_float(u & 0xFFFF0000u); }

// ================= merged prologue: wTs + gcur-zero + f2b =================
// blocks [0,256): build wTs (col = bid). blocks [256,272): zero gcur.
// ALL blocks: grid-stride f2b of feat -> featb.
__global__ __launch_bounds__(256) void k_pre(const float* __restrict__ feat,
                                             unsigned short* __restrict__ featb,
                                             const float* __restrict__ W,
                                             unsigned short* __restrict__ wTs,
                                             int* __restrict__ gcur, int nz, long n8) {
    const int bid = blockIdx.x;
    const int t = threadIdx.x;
    if (bid < 256) {
        unsigned short v = (unsigned short)f2bf(W[(size_t)t * D + bid]);
        int ks = t >> 5;
        int byte = ((bid << 6) + (((t >> 3) & 3) << 4) + ((t & 7) << 1)) ^ ((bid & 7) << 4);
        *reinterpret_cast<unsigned short*>(
            reinterpret_cast<char*>(wTs) + (size_t)ks * 16384 + byte) = v;
    } else if (bid < 272) {
        int i = (bid - 256) * 256 + t;
        if (i < nz) gcur[i] = 0;
    }
    for (long i = bid * 256L + t; i < n8; i += (long)gridDim.x * 256) {
        const float4* p = reinterpret_cast<const float4*>(feat + i * 8);
        float4 a = p[0], b = p[1];
        uint4 u;
        u.x = f2bf(a.x) | (f2bf(a.y) << 16);
        u.y = f2bf(a.z) | (f2bf(a.w) << 16);
        u.z = f2bf(b.x) | (f2bf(b.y) << 16);
        u.w = f2bf(b.z) | (f2bf(b.w) << 16);
        reinterpret_cast<uint4*>(featb)[i] = u;
    }
}

// ================= standalone utility kernels (fallback tiers) =============

__global__ void k_zero(int* __restrict__ p, int n) {
    int i = blockIdx.x * blockDim.x + threadIdx.x;
    if (i < n) p[i] = 0;
}

__global__ __launch_bounds__(256) void k_f2b(const float* __restrict__ f,
                                             unsigned short* __restrict__ fb, long n8) {
    for (long i = blockIdx.x * 256L + threadIdx.x; i < n8; i += (long)gridDim.x * 256) {
        const float4* p = reinterpret_cast<const float4*>(f + i * 8);
        float4 a = p[0], b = p[1];
        uint4 u;
        u.x = f2bf(a.x) | (f2bf(a.y) << 16);
        u.y = f2bf(a.z) | (f2bf(a.w) << 16);
        u.z = f2bf(b.x) | (f2bf(b.y) << 16);
        u.w = f2bf(b.z) | (f2bf(b.w) << 16);
        reinterpret_cast<uint4*>(fb)[i] = u;
    }
}

__global__ __launch_bounds__(256) void k_wTs(const float* __restrict__ W,
                                             unsigned short* __restrict__ wTs) {
    int col = blockIdx.x;
    int k = threadIdx.x;
    unsigned short v = (unsigned short)f2bf(W[(size_t)k * D + col]);
    int ks = k >> 5;
    int byte = ((col << 6) + (((k >> 3) & 3) << 4) + ((k & 7) << 1)) ^ ((col & 7) << 4);
    *reinterpret_cast<unsigned short*>(
        reinterpret_cast<char*>(wTs) + (size_t)ks * 16384 + byte) = v;
}

// ================= phase 1: range partition (dense appends) =================
__global__ __launch_bounds__(PTH) void k_part(const int* __restrict__ src,
                                              const int* __restrict__ dst,
                                              int* __restrict__ gcur,
                                              int* __restrict__ streams,
                                              int* __restrict__ ovf,
                                              int* __restrict__ ovf_cnt,
                                              int E, int nranges) {
    __shared__ int hist[NRANGES_MAX];
    __shared__ int base[NRANGES_MAX];
    __shared__ int off[NRANGES_MAX];
    const int t = threadIdx.x;
    const long e0 = (long)blockIdx.x * PCH;
    for (int i = t; i < nranges; i += PTH) hist[i] = 0;
    __syncthreads();
    int md[PCH / PTH], ms[PCH / PTH];
    #pragma unroll
    for (int i = 0; i < PCH / PTH; ++i) {
        long e = e0 + (long)i * PTH + t;
        if (e < E) {
            md[i] = dst[e];
            ms[i] = src[e];
            atomicAdd(&hist[md[i] >> RSH], 1);
        } else {
            md[i] = -1;
        }
    }
    __syncthreads();
    for (int i = t; i < nranges; i += PTH) {
        int h = hist[i];
        base[i] = h ? atomicAdd(&gcur[i], h) : 0;
        off[i] = 0;
    }
    __syncthreads();
    #pragma unroll
    for (int i = 0; i < PCH / PTH; ++i) {
        if (md[i] >= 0) {
            int r = md[i] >> RSH;
            int p = base[r] + atomicAdd(&off[r], 1);
            if (p < SCAP) {
                streams[(size_t)r * SCAP + p] = (ms[i] << RSH) | (md[i] & (RN - 1));
            } else {
                int o = atomicAdd(ovf_cnt, 1);
                if (o < MAXOVF) { ovf[2 * o] = ms[i]; ovf[2 * o + 1] = md[i]; }
            }
        }
    }
}

// ================= phase 2: LDS counting-sort + fused gather =================
// One block (256 thr, 4 waves) per range of 32 nodes; wave handles 8 nodes.
__global__ __launch_bounds__(SGT) void k_sg(const unsigned short* __restrict__ featb,
                                            const int* __restrict__ gcur,
                                            const int* __restrict__ streams,
                                            const int* __restrict__ ovf,
                                            const int* __restrict__ ovf_cnt,
                                            unsigned short* __restrict__ aggb, int N) {
    __shared__ int hist[RN], basei[RN], off[RN], scn[RN];
    __shared__ int elist[SCAP];
    const int r = blockIdx.x;
    const int t = threadIdx.x;
    const int node0 = r << RSH;
    int cnt = gcur[r];
    if (cnt > SCAP) cnt = SCAP;
    if (t < RN) { hist[t] = 0; off[t] = 0; }
    __syncthreads();
    int ent[SCAP / SGT];
    #pragma unroll
    for (int i = 0; i < SCAP / SGT; ++i) {
        int p = t + i * SGT;
        if (p < cnt) {
            ent[i] = streams[(size_t)r * SCAP + p];
            atomicAdd(&hist[ent[i] & (RN - 1)], 1);
        } else {
            ent[i] = -1;
        }
    }
    __syncthreads();
    if (t < RN) scn[t] = hist[t];
    __syncthreads();
    for (int st = 1; st < RN; st <<= 1) {
        int v = 0;
        if (t < RN && t >= st) v = scn[t - st];
        __syncthreads();
        if (t < RN) scn[t] += v;
        __syncthreads();
    }
    if (t < RN) basei[t] = scn[t] - hist[t];
    __syncthreads();
    #pragma unroll
    for (int i = 0; i < SCAP / SGT; ++i) {
        if (ent[i] >= 0) {
            int ln_ = ent[i] & (RN - 1);
            int p = basei[ln_] + atomicAdd(&off[ln_], 1);
            elist[p] = ent[i] >> RSH;
        }
    }
    __syncthreads();
    int ovfn = *ovf_cnt;
    if (ovfn > MAXOVF) ovfn = MAXOVF;
    const int wv = t >> 6;   // 0..3
    const int l = t & 63;
    for (int k = 0; k < RN / 4; ++k) {
        int ln_ = wv * (RN / 4) + k;
        int node = node0 + ln_;
        if (node >= N) continue;
        int cb = hist[ln_];
        int bb = basei[ln_];
        uint2 u = reinterpret_cast<const uint2*>(featb + (size_t)node * D)[l];
        float4 acc;
        acc.x = bflo(u.x); acc.y = bfhi(u.x); acc.z = bflo(u.y); acc.w = bfhi(u.y);
        int j = 0;
        for (; j + 16 <= cb; j += 16) {
            int s[16];
            #pragma unroll
            for (int q = 0; q < 16; ++q) s[q] = elist[bb + j + q];
            uint2 v[16];
            #pragma unroll
            for (int q = 0; q < 16; ++q)
                v[q] = reinterpret_cast<const uint2*>(featb + (size_t)s[q] * D)[l];
            #pragma unroll
            for (int q = 0; q < 16; ++q) {
                acc.x += bflo(v[q].x); acc.y += bfhi(v[q].x);
                acc.z += bflo(v[q].y); acc.w += bfhi(v[q].y);
            }
        }
        for (; j + 8 <= cb; j += 8) {
            int s[8];
            #pragma unroll
            for (int q = 0; q < 8; ++q) s[q] = elist[bb + j + q];
            uint2 v[8];
            #pragma unroll
            for (int q = 0; q < 8; ++q)
                v[q] = reinterpret_cast<const uint2*>(featb + (size_t)s[q] * D)[l];
            #pragma unroll
            for (int q = 0; q < 8; ++q) {
                acc.x += bflo(v[q].x); acc.y += bfhi(v[q].x);
                acc.z += bflo(v[q].y); acc.w += bfhi(v[q].y);
            }
        }
        for (; j < cb; ++j) {
            uint2 v = reinterpret_cast<const uint2*>(featb + (size_t)elist[bb + j] * D)[l];
            acc.x += bflo(v.x); acc.y += bfhi(v.x);
            acc.z += bflo(v.y); acc.w += bfhi(v.y);
        }
        if (ovfn > 0) {
            for (int e = 0; e < ovfn; ++e) {
                if (ovf[2 * e + 1] == node) {
                    uint2 v = reinterpret_cast<const uint2*>(featb + (size_t)ovf[2 * e] * D)[l];
                    acc.x += bflo(v.x); acc.y += bfhi(v.x);
                    acc.z += bflo(v.y); acc.w += bfhi(v.y);
                }
            }
        }
        uint2 w;
        w.x = f2bf(acc.x) | (f2bf(acc.y) << 16);
        w.y = f2bf(acc.z) | (f2bf(acc.w) << 16);
        unsigned short* rowp = aggb + (size_t)node * D;
        int us = (l * 4) ^ ((node & 7) << 3);
        *reinterpret_cast<uint2*>(rowp + us) = w;
    }
}

// ================= capacity-bucket build (fallback) =========
__global__ void k_fillcap(const int* __restrict__ src, const int* __restrict__ dst,
                          int* __restrict__ counts, int* __restrict__ buckets,
                          int* __restrict__ ovf, int* __restrict__ ovf_cnt, int E) {
    for (int e = blockIdx.x * blockDim.x + threadIdx.x; e < E;
         e += gridDim.x * blockDim.x) {
        int d = dst[e];
        int pos = atomicAdd(&counts[d], 1);
        if (pos < CAP) {
            buckets[(size_t)d * CAP + pos] = src[e];
        } else {
            int o = atomicAdd(ovf_cnt, 1);
            if (o < MAXOVF) {
                ovf[2 * o + 0] = src[e];
                ovf[2 * o + 1] = d;
            }
        }
    }
}

// ================= gathers (fallback tiers) =================

#define GAT_BODY(LOAD, ACCUM)                                                  \
    int j = 0;                                                                 \
    for (; j + 16 <= cnt; j += 16) {                                           \
        int s[16];                                                             \
        _Pragma("unroll") for (int q = 0; q < 16; ++q) s[q] = bk[j + q];       \
        LOAD(16)                                                               \
        ACCUM(16)                                                              \
    }                                                                          \
    for (; j + 8 <= cnt; j += 8) {                                             \
        int s[8];                                                              \
        _Pragma("unroll") for (int q = 0; q < 8; ++q) s[q] = bk[j + q];        \
        LOAD(8)                                                                \
        ACCUM(8)                                                               \
    }

__global__ __launch_bounds__(256) void g_bf_aggb(const unsigned short* __restrict__ fb,
                                                 const int* __restrict__ counts,
                                                 const int* __restrict__ buckets,
                                                 const int* __restrict__ ovf,
                                                 const int* __restrict__ ovf_cnt,
                                                 unsigned short* __restrict__ aggb, int N) {
    int node = (int)((blockIdx.x * (long)blockDim.x + threadIdx.x) >> 6);
    int ln = threadIdx.x & 63;
    if (node >= N) return;
    int cnt_raw = counts[node];
    int cnt = cnt_raw > CAP ? CAP : cnt_raw;
    const int* bk = buckets + (size_t)node * CAP;
    uint2 u = reinterpret_cast<const uint2*>(fb + (size_t)node * D)[ln];
    float4 acc;
    acc.x = bflo(u.x); acc.y = bfhi(u.x); acc.z = bflo(u.y); acc.w = bfhi(u.y);
#define BLOAD(W_)                                                              \
    uint2 v[W_];                                                               \
    _Pragma("unroll") for (int q = 0; q < W_; ++q)                             \
        v[q] = reinterpret_cast<const uint2*>(fb + (size_t)s[q] * D)[ln];
#define BACC(W_)                                                               \
    _Pragma("unroll") for (int q = 0; q < W_; ++q) {                           \
        acc.x += bflo(v[q].x); acc.y += bfhi(v[q].x);                          \
        acc.z += bflo(v[q].y); acc.w += bfhi(v[q].y);                          \
    }
    GAT_BODY(BLOAD, BACC)
    for (; j < cnt; ++j) {
        uint2 v = reinterpret_cast<const uint2*>(fb + (size_t)bk[j] * D)[ln];
        acc.x += bflo(v.x); acc.y += bfhi(v.x);
        acc.z += bflo(v.y); acc.w += bfhi(v.y);
    }
    if (cnt_raw > CAP) {
        int m = *ovf_cnt;
        if (m > MAXOVF) m = MAXOVF;
        for (int e = 0; e < m; ++e) {
            if (ovf[2 * e + 1] == node) {
                uint2 v = reinterpret_cast<const uint2*>(fb + (size_t)ovf[2 * e] * D)[ln];
                acc.x += bflo(v.x); acc.y += bfhi(v.x);
                acc.z += bflo(v.y); acc.w += bfhi(v.y);
            }
        }
    }
    uint2 w;
    w.x = f2bf(acc.x) | (f2bf(acc.y) << 16);
    w.y = f2bf(acc.z) | (f2bf(acc.w) << 16);
    unsigned short* rowp = aggb + (size_t)node * D;
    int us = (ln * 4) ^ ((node & 7) << 3);
    *reinterpret_cast<uint2*>(rowp + us) = w;
}

__global__ __launch_bounds__(256) void g_f32_out(const float* __restrict__ feat,
                                                 const int* __restrict__ counts,
                                                 const int* __restrict__ buckets,
                                                 const int* __restrict__ ovf,
                                                 const int* __restrict__ ovf_cnt,
                                                 float* __restrict__ out, int N) {
    int node = (int)((blockIdx.x * (long)blockDim.x + threadIdx.x) >> 6);
    int ln = threadIdx.x & 63;
    if (node >= N) return;
    int cnt_raw = counts[node];
    int cnt = cnt_raw > CAP ? CAP : cnt_raw;
    const int* bk = buckets + (size_t)node * CAP;
    float4 acc = reinterpret_cast<const float4*>(feat + (size_t)node * D)[ln];
#define FLOAD(W_)                                                              \
    float4 v[W_];                                                              \
    _Pragma("unroll") for (int q = 0; q < W_; ++q)                             \
        v[q] = reinterpret_cast<const float4*>(feat + (size_t)s[q] * D)[ln];
#define FACC(W_)                                                               \
    _Pragma("unroll") for (int q = 0; q < W_; ++q) {                           \
        acc.x += v[q].x; acc.y += v[q].y; acc.z += v[q].z; acc.w += v[q].w;    \
    }
    GAT_BODY(FLOAD, FACC)
    for (; j < cnt; ++j) {
        float4 v = reinterpret_cast<const float4*>(feat + (size_t)bk[j] * D)[ln];
        acc.x += v.x; acc.y += v.y; acc.z += v.z; acc.w += v.w;
    }
    if (cnt_raw > CAP) {
        int m = *ovf_cnt;
        if (m > MAXOVF) m = MAXOVF;
        for (int e = 0; e < m; ++e) {
            if (ovf[2 * e + 1] == node) {
                float4 v = reinterpret_cast<const float4*>(feat + (size_t)ovf[2 * e] * D)[ln];
                acc.x += v.x; acc.y += v.y; acc.z += v.z; acc.w += v.w;
            }
        }
    }
    reinterpret_cast<float4*>(out + (size_t)node * D)[ln] = acc;
}

// ================= atomic scatter (last-resort) =================

__global__ __launch_bounds__(256) void gc_copy(const float* __restrict__ feat,
                                               float* __restrict__ agg, long n4) {
    long i = (long)blockIdx.x * blockDim.x + threadIdx.x;
    if (i < n4)
        reinterpret_cast<float4*>(agg)[i] = reinterpret_cast<const float4*>(feat)[i];
}

__global__ __launch_bounds__(256) void gc_scatter(const float* __restrict__ feat,
                                                  const int* __restrict__ src,
                                                  const int* __restrict__ dst,
                                                  float* __restrict__ agg, int n_edges) {
    int wave = (int)((blockIdx.x * (long)blockDim.x + threadIdx.x) >> 6);
    int lane = threadIdx.x & 63;
    if (wave >= n_edges) return;
    int s = src[wave];
    int d = dst[wave];
    const float4 v = reinterpret_cast<const float4*>(feat + (size_t)s * D)[lane];
    float* p = agg + (size_t)d * D + (size_t)lane * 4;
    atomicAdd(p + 0, v.x);
    atomicAdd(p + 1, v.y);
    atomicAdd(p + 2, v.z);
    atomicAdd(p + 3, v.w);
}

// ================= MFMA GEMMs (B staged per-ks into LDS) =================

__device__ inline void gload16(const char* g, const unsigned char* lds) {
    __builtin_amdgcn_global_load_lds(
        (const __attribute__((address_space(1))) void*)g,
        (__attribute__((address_space(3))) void*)lds, 16, 0, 0);
}

__global__ __launch_bounds__(256) void gemm_mfma_b(const unsigned short* __restrict__ aggb,
                                                   const unsigned short* __restrict__ wTs,
                                                   float* __restrict__ out, int n_rows) {
    __shared__ __align__(16) unsigned char s_a[BM * 512];
    __shared__ __align__(16) unsigned char s_b[16384];
    const int t = threadIdx.x;
    const int row0 = blockIdx.x * BM;
    const int wv = t >> 6;
    const int l = t & 63;
    const char* wb = reinterpret_cast<const char*>(wTs);

    const char* gbase = reinterpret_cast<const char*>(aggb) + (size_t)row0 * 512;
    #pragma unroll
    for (int q = 0; q < 8; ++q) {
        int off = wv * 8192 + q * 1024;
        gload16(gbase + off + l * 16, s_a + off);
    }
    #pragma unroll
    for (int i = 0; i < 4; ++i) {
        int off = wv * 4096 + i * 1024;
        gload16(wb + off + l * 16, s_b + off);
    }
    __syncthreads();

    f32x4 acc[16];
    #pragma unroll
    for (int ct = 0; ct < 16; ++ct) acc[ct] = (f32x4){0.f, 0.f, 0.f, 0.f};

    const int lr = wv * 16 + (l & 15);
    const int g = l >> 4;
    for (int ks = 0; ks < 8; ++ks) {
        const int kb = ks * 32 + g * 8;
        const int ab = (lr * 512 + kb * 2) ^ ((lr & 7) << 4);
        s16x8 af = *reinterpret_cast<const s16x8*>(s_a + ab);
        #pragma unroll
        for (int ct = 0; ct < 16; ++ct) {
            int col = ct * 16 + (l & 15);
            int bb = (col * 64 + g * 16) ^ ((col & 7) << 4);
            s16x8 bf = *reinterpret_cast<const s16x8*>(s_b + bb);
            acc[ct] = __builtin_amdgcn_mfma_f32_16x16x32_bf16(af, bf, acc[ct], 0, 0, 0);
        }
        __syncthreads();
        if (ks < 7) {
            #pragma unroll
            for (int i = 0; i < 4; ++i) {
                int off = wv * 4096 + i * 1024;
                gload16(wb + (size_t)(ks + 1) * 16384 + off + l * 16, s_b + off);
            }
            __syncthreads();
        }
    }

    const int rbase = row0 + wv * 16 + (l >> 4) * 4;
    const int cb = l & 15;
    #pragma unroll
    for (int ct = 0; ct < 16; ++ct) {
        #pragma unroll
        for (int r = 0; r < 4; ++r) {
            int row = rbase + r;
            if (row < n_rows)
                out[(size_t)row * D + ct * 16 + cb] = fmaxf(acc[ct][r], 0.f);
        }
    }
}

__global__ __launch_bounds__(256) void gemm_mfma(const unsigned short* __restrict__ wTs,
                                                 float* __restrict__ out, int n_rows) {
    __shared__ __align__(16) unsigned char s_a[BM * 512];
    __shared__ __align__(16) unsigned char s_b[16384];
    const int t = threadIdx.x;
    const int row0 = blockIdx.x * BM;
    const int wv = t >> 6;
    const int l = t & 63;
    const char* wb = reinterpret_cast<const char*>(wTs);

    #pragma unroll
    for (int i = 0; i < 4; ++i) {
        int off = wv * 4096 + i * 1024;
        gload16(wb + off + l * 16, s_b + off);
    }
    #pragma unroll
    for (int i = 0; i < 16; ++i) {
        int f4 = t + 256 * i;
        int row = f4 >> 6;
        int kc = f4 & 63;
        int grow = row0 + row;
        if (grow >= n_rows) grow = n_rows - 1;
        float4 v = *reinterpret_cast<const float4*>(out + (size_t)grow * D + kc * 4);
        uint2 u;
        u.x = f2bf(v.x) | (f2bf(v.y) << 16);
        u.y = f2bf(v.z) | (f2bf(v.w) << 16);
        int byte = (row * 512 + kc * 8) ^ ((row & 7) << 4);
        *reinterpret_cast<uint2*>(s_a + byte) = u;
    }
    __syncthreads();

    f32x4 acc[16];
    #pragma unroll
    for (int ct = 0; ct < 16; ++ct) acc[ct] = (f32x4){0.f, 0.f, 0.f, 0.f};

    const int lr = wv * 16 + (l & 15);
    const int g = l >> 4;
    for (int ks = 0; ks < 8; ++ks) {
        const int kb = ks * 32 + g * 8;
        const int ab = (lr * 512 + kb * 2) ^ ((lr & 7) << 4);
        s16x8 af = *reinterpret_cast<const s16x8*>(s_a + ab);
        #pragma unroll
        for (int ct = 0; ct < 16; ++ct) {
            int col = ct * 16 + (l & 15);
            int bb = (col * 64 + g * 16) ^ ((col & 7) << 4);
            s16x8 bf = *reinterpret_cast<const s16x8*>(s_b + bb);
            acc[ct] = __builtin_amdgcn_mfma_f32_16x16x32_bf16(af, bf, acc[ct], 0, 0, 0);
        }
        __syncthreads();
        if (ks < 7) {
            #pragma unroll
            for (int i = 0; i < 4; ++i) {
                int off = wv * 4096 + i * 1024;
                gload16(wb + (size_t)(ks + 1) * 16384 + off + l * 16, s_b + off);
            }
            __syncthreads();
        }
    }

    const int rbase = row0 + wv * 16 + (l >> 4) * 4;
    const int cb = l & 15;
    #pragma unroll
    for (int ct = 0; ct < 16; ++ct) {
        #pragma unroll
        for (int r = 0; r < 4; ++r) {
            int row = rbase + r;
            if (row < n_rows)
                out[(size_t)row * D + ct * 16 + cb] = fmaxf(acc[ct][r], 0.f);
        }
    }
}

// legacy fp32 GEMM (no-workspace fallback)
__global__ __launch_bounds__(256) void gemm_relu(const float* __restrict__ Wm,
                                                 float* __restrict__ out, int n_rows) {
    __shared__ float s_a[32][D];
    const int row0 = blockIdx.x * 32;
    const int c = threadIdx.x;
    {
        const float4* gsrc = reinterpret_cast<const float4*>(out + (size_t)row0 * D);
        float4* ldst = reinterpret_cast<float4*>(&s_a[0][0]);
        #pragma unroll
        for (int i = 0; i < 8; ++i)
            ldst[threadIdx.x + i * 256] = gsrc[threadIdx.x + i * 256];
    }
    __syncthreads();
    float acc[32];
    #pragma unroll
    for (int r = 0; r < 32; ++r) acc[r] = 0.f;
    #pragma unroll 4
    for (int k = 0; k < D; ++k) {
        float w = Wm[(size_t)k * D + c];
        #pragma unroll
        for (int r = 0; r < 32; ++r) acc[r] += s_a[r][k] * w;
    }
    #pragma unroll
    for (int r = 0; r < 32; ++r) {
        int row = row0 + r;
        if (row < n_rows) out[(size_t)row * D + c] = fmaxf(acc[r], 0.f);
    }
}

extern "C" void kernel_launch(void* const* d_in, const int* in_sizes, int n_in,
                              void* d_out, int out_size, void* d_ws, size_t ws_size,
                              hipStream_t stream) {
    const float* feat = (const float*)d_in[0];
    const float* W    = (const float*)d_in[1];
    const int*   src  = (const int*)d_in[2];
    const int*   dst  = (const int*)d_in[3];
    float* out = (float*)d_out;

    const int N = in_sizes[0] / D;  // 100000
    const int E = in_sizes[2];      // 1600000
    const int Npad = ((N + BM - 1) / BM) * BM;
    auto al = [](size_t x) { return (x + 255) & ~(size_t)255; };

    const int nranges = (N + RN - 1) / RN;   // 3125
    const int gemm_blocks = (N + BM - 1) / BM;
    const int gat_blocks = (N + 3) / 4;

    // ---- tier A2 layout: gcur | ovf_cnt | ovf | streams | featb | wTs | aggb
    const size_t hdr_bytes   = ((size_t)nranges + 1 + 2 * MAXOVF) * 4;
    const size_t strm_off    = al(hdr_bytes);
    const size_t strm_sz     = (size_t)nranges * SCAP * 4;
    const size_t a2_featb_off = al(strm_off + strm_sz);
    const size_t featb_sz    = (size_t)N * D * 2;
    const size_t a2_wt_off   = al(a2_featb_off + featb_sz);
    const size_t wt_sz       = (size_t)D * D * 2;
    const size_t a2_aggb_off = al(a2_wt_off + wt_sz);
    const size_t aggb_sz     = (size_t)Npad * D * 2;
    const size_t need_A2     = a2_aggb_off + aggb_sz;

    // ---- fallback tier layouts
    const size_t cap_bytes = ((size_t)N + 1 + 2 * MAXOVF + (size_t)N * CAP) * 4;
    const size_t featb_off = al(cap_bytes);
    const size_t wt_off    = al(featb_off + featb_sz);
    const size_t aggb_off  = al(wt_off + wt_sz);
    const size_t need_A    = aggb_off + aggb_sz;

    if (ws_size >= need_A2 && nranges <= NRANGES_MAX) {
        char* base = (char*)d_ws;
        int* gcur    = (int*)base;
        int* ovf_cnt = gcur + nranges;
        int* ovf     = ovf_cnt + 1;
        int* streams = (int*)(base + strm_off);
        unsigned short* featb = (unsigned short*)(base + a2_featb_off);
        unsigned short* wTs   = (unsigned short*)(base + a2_wt_off);
        unsigned short* aggb  = (unsigned short*)(base + a2_aggb_off);

        k_pre<<<2048, 256, 0, stream>>>(feat, featb, W, wTs, gcur, nranges + 1,
                                        (long)N * D / 8);
        k_part<<<(E + PCH - 1) / PCH, PTH, 0, stream>>>(src, dst, gcur, streams,
                                                        ovf, ovf_cnt, E, nranges);
        k_sg<<<nranges, SGT, 0, stream>>>(featb, gcur, streams, ovf, ovf_cnt, aggb, N);
        gemm_mfma_b<<<gemm_blocks, 256, 0, stream>>>(aggb, wTs, out, N);
    } else if (ws_size >= need_A) {
        char* base = (char*)d_ws;
        int* counts  = (int*)base;
        int* ovf_cnt = counts + N;
        int* ovf     = ovf_cnt + 1;
        int* buckets = ovf + 2 * MAXOVF;
        unsigned short* featb = (unsigned short*)(base + featb_off);
        unsigned short* wTs   = (unsigned short*)(base + wt_off);
        unsigned short* aggb  = (unsigned short*)(base + aggb_off);

        k_zero<<<(N + 1 + 255) / 256, 256, 0, stream>>>(counts, N + 1);
        k_f2b<<<2048, 256, 0, stream>>>(feat, featb, (long)N * D / 8);
        k_wTs<<<D, 256, 0, stream>>>(W, wTs);
        k_fillcap<<<2048, 256, 0, stream>>>(src, dst, counts, buckets, ovf, ovf_cnt, E);
        g_bf_aggb<<<gat_blocks, 256, 0, stream>>>(featb, counts, buckets, ovf, ovf_cnt, aggb, N);
        gemm_mfma_b<<<gemm_blocks, 256, 0, stream>>>(aggb, wTs, out, N);
    } else if (ws_size >= cap_bytes) {
        char* base = (char*)d_ws;
        int* counts  = (int*)base;
        int* ovf_cnt = counts + N;
        int* ovf     = ovf_cnt + 1;
        int* buckets = ovf + 2 * MAXOVF;
        unsigned short* wTs = (unsigned short*)(((uintptr_t)buckets + 255) & ~(uintptr_t)255);

        k_zero<<<(N + 1 + 255) / 256, 256, 0, stream>>>(counts, N + 1);
        k_fillcap<<<2048, 256, 0, stream>>>(src, dst, counts, buckets, ovf, ovf_cnt, E);
        g_f32_out<<<gat_blocks, 256, 0, stream>>>(feat, counts, buckets, ovf, ovf_cnt, out, N);
        k_wTs<<<D, 256, 0, stream>>>(W, wTs);
        gemm_mfma<<<gemm_blocks, 256, 0, stream>>>(wTs, out, N);
    } else {
        long n4 = (long)N * D / 4;
        gc_copy<<<(int)((n4 + 255) / 256), 256, 0, stream>>>(feat, out, n4);
        gc_scatter<<<(E + 3) / 4, 256, 0, stream>>>(feat, src, dst, out, E);
        gemm_relu<<<(N + 31) / 32, 256, 0, stream>>>(W, out, N);
    }
}

// Round 12
// 215.252 us; speedup vs baseline: 1.6059x; 1.0735x over previous
//
#include <hip/hip_runtime.h>

#define D 256
#define CAP 32
#define MAXOVF 4096
#define BM 64

// range-partition params
#define RN 32           // nodes per range
#define RSH 5
#define SCAP 1024       // stream capacity per range (mean 512)
#define PCH 8192        // edges per k_part block
#define PTH 512         // k_part threads
#define NRANGES_MAX 4096
#define SGT 256         // k_sgg threads (4 waves)

typedef float f32x4 __attribute__((ext_vector_type(4)));
typedef short s16x8 __attribute__((ext_vector_type(8)));

__device__ inline unsigned int f2bf(float x) {
    unsigned int u = __float_as_uint(x);
    return (u + 0x7FFFu + ((u >> 16) & 1u)) >> 16;  // RNE, low 16 bits valid
}
__device__ inline float bflo(unsigned int u) { return __uint_as_float(u << 16); }
__device__ inline float bfhi(unsigned int u) { return __uint_as_float(u & 0xFFFF0000u); }

__device__ inline void gload16(const char* g, const unsigned char* lds) {
    __builtin_amdgcn_global_load_lds(
        (const __attribute__((address_space(1))) void*)g,
        (__attribute__((address_space(3))) void*)lds, 16, 0, 0);
}

// ================= merged prologue: wTs + gcur-zero + f2b =================
__global__ __launch_bounds__(256) void k_pre(const float* __restrict__ feat,
                                             unsigned short* __restrict__ featb,
                                             const float* __restrict__ W,
                                             unsigned short* __restrict__ wTs,
                                             int* __restrict__ gcur, int nz, long n8) {
    const int bid = blockIdx.x;
    const int t = threadIdx.x;
    if (bid < 256) {
        unsigned short v = (unsigned short)f2bf(W[(size_t)t * D + bid]);
        int ks = t >> 5;
        int byte = ((bid << 6) + (((t >> 3) & 3) << 4) + ((t & 7) << 1)) ^ ((bid & 7) << 4);
        *reinterpret_cast<unsigned short*>(
            reinterpret_cast<char*>(wTs) + (size_t)ks * 16384 + byte) = v;
    } else if (bid < 272) {
        int i = (bid - 256) * 256 + t;
        if (i < nz) gcur[i] = 0;
    }
    for (long i = bid * 256L + t; i < n8; i += (long)gridDim.x * 256) {
        const float4* p = reinterpret_cast<const float4*>(feat + i * 8);
        float4 a = p[0], b = p[1];
        uint4 u;
        u.x = f2bf(a.x) | (f2bf(a.y) << 16);
        u.y = f2bf(a.z) | (f2bf(a.w) << 16);
        u.z = f2bf(b.x) | (f2bf(b.y) << 16);
        u.w = f2bf(b.z) | (f2bf(b.w) << 16);
        reinterpret_cast<uint4*>(featb)[i] = u;
    }
}

// ================= standalone utility kernels (fallback tiers) =============

__global__ void k_zero(int* __restrict__ p, int n) {
    int i = blockIdx.x * blockDim.x + threadIdx.x;
    if (i < n) p[i] = 0;
}

__global__ __launch_bounds__(256) void k_f2b(const float* __restrict__ f,
                                             unsigned short* __restrict__ fb, long n8) {
    for (long i = blockIdx.x * 256L + threadIdx.x; i < n8; i += (long)gridDim.x * 256) {
        const float4* p = reinterpret_cast<const float4*>(f + i * 8);
        float4 a = p[0], b = p[1];
        uint4 u;
        u.x = f2bf(a.x) | (f2bf(a.y) << 16);
        u.y = f2bf(a.z) | (f2bf(a.w) << 16);
        u.z = f2bf(b.x) | (f2bf(b.y) << 16);
        u.w = f2bf(b.z) | (f2bf(b.w) << 16);
        reinterpret_cast<uint4*>(fb)[i] = u;
    }
}

__global__ __launch_bounds__(256) void k_wTs(const float* __restrict__ W,
                                             unsigned short* __restrict__ wTs) {
    int col = blockIdx.x;
    int k = threadIdx.x;
    unsigned short v = (unsigned short)f2bf(W[(size_t)k * D + col]);
    int ks = k >> 5;
    int byte = ((col << 6) + (((k >> 3) & 3) << 4) + ((k & 7) << 1)) ^ ((col & 7) << 4);
    *reinterpret_cast<unsigned short*>(
        reinterpret_cast<char*>(wTs) + (size_t)ks * 16384 + byte) = v;
}

// ================= phase 1: range partition (dense appends) =================
__global__ __launch_bounds__(PTH) void k_part(const int* __restrict__ src,
                                              const int* __restrict__ dst,
                                              int* __restrict__ gcur,
                                              int* __restrict__ streams,
                                              int* __restrict__ ovf,
                                              int* __restrict__ ovf_cnt,
                                              int E, int nranges) {
    __shared__ int hist[NRANGES_MAX];
    __shared__ int base[NRANGES_MAX];
    __shared__ int off[NRANGES_MAX];
    const int t = threadIdx.x;
    const long e0 = (long)blockIdx.x * PCH;
    for (int i = t; i < nranges; i += PTH) hist[i] = 0;
    __syncthreads();
    int md[PCH / PTH], ms[PCH / PTH];
    #pragma unroll
    for (int i = 0; i < PCH / PTH; ++i) {
        long e = e0 + (long)i * PTH + t;
        if (e < E) {
            md[i] = dst[e];
            ms[i] = src[e];
            atomicAdd(&hist[md[i] >> RSH], 1);
        } else {
            md[i] = -1;
        }
    }
    __syncthreads();
    for (int i = t; i < nranges; i += PTH) {
        int h = hist[i];
        base[i] = h ? atomicAdd(&gcur[i], h) : 0;
        off[i] = 0;
    }
    __syncthreads();
    #pragma unroll
    for (int i = 0; i < PCH / PTH; ++i) {
        if (md[i] >= 0) {
            int r = md[i] >> RSH;
            int p = base[r] + atomicAdd(&off[r], 1);
            if (p < SCAP) {
                streams[(size_t)r * SCAP + p] = (ms[i] << RSH) | (md[i] & (RN - 1));
            } else {
                int o = atomicAdd(ovf_cnt, 1);
                if (o < MAXOVF) { ovf[2 * o] = ms[i]; ovf[2 * o + 1] = md[i]; }
            }
        }
    }
}

// ====== phase 2: LDS counting-sort + fused gather + fused MFMA GEMM ======
// One block (256 thr, 4 waves) per range of 32 nodes. Gather accumulates
// fp32 in regs, writes bf16 swizzled into s_agg (LDS), then MFMA with
// B staged per-ks from wTs; ReLU'd fp32 written straight to out.
__global__ __launch_bounds__(SGT) void k_sgg(const unsigned short* __restrict__ featb,
                                             const int* __restrict__ gcur,
                                             const int* __restrict__ streams,
                                             const int* __restrict__ ovf,
                                             const int* __restrict__ ovf_cnt,
                                             const unsigned short* __restrict__ wTs,
                                             float* __restrict__ out, int N) {
    __shared__ int hist[RN], basei[RN], off[RN], scn[RN];
    __shared__ int elist[SCAP];                          // 4 KB
    __shared__ __align__(16) unsigned char s_agg[RN * 512];  // 16 KB
    __shared__ __align__(16) unsigned char s_b[16384];       // 16 KB
    const int r = blockIdx.x;
    const int t = threadIdx.x;
    const int node0 = r << RSH;
    const int wv = t >> 6;   // 0..3
    const int l = t & 63;
    const char* wb = reinterpret_cast<const char*>(wTs);

    // issue s_b(ks=0) staging early — completes under the sort prologue
    #pragma unroll
    for (int i = 0; i < 4; ++i) {
        int o = wv * 4096 + i * 1024;
        gload16(wb + o + l * 16, s_b + o);
    }

    // ---- sort prologue ----
    int cnt = gcur[r];
    if (cnt > SCAP) cnt = SCAP;
    if (t < RN) { hist[t] = 0; off[t] = 0; }
    __syncthreads();
    int ent[SCAP / SGT];
    #pragma unroll
    for (int i = 0; i < SCAP / SGT; ++i) {
        int p = t + i * SGT;
        if (p < cnt) {
            ent[i] = streams[(size_t)r * SCAP + p];
            atomicAdd(&hist[ent[i] & (RN - 1)], 1);
        } else {
            ent[i] = -1;
        }
    }
    __syncthreads();
    if (t < RN) scn[t] = hist[t];
    __syncthreads();
    for (int st = 1; st < RN; st <<= 1) {
        int v = 0;
        if (t < RN && t >= st) v = scn[t - st];
        __syncthreads();
        if (t < RN) scn[t] += v;
        __syncthreads();
    }
    if (t < RN) basei[t] = scn[t] - hist[t];
    __syncthreads();
    #pragma unroll
    for (int i = 0; i < SCAP / SGT; ++i) {
        if (ent[i] >= 0) {
            int ln_ = ent[i] & (RN - 1);
            int p = basei[ln_] + atomicAdd(&off[ln_], 1);
            elist[p] = ent[i] >> RSH;
        }
    }
    __syncthreads();

    // ---- gather into s_agg ----
    int ovfn = *ovf_cnt;
    if (ovfn > MAXOVF) ovfn = MAXOVF;
    for (int k = 0; k < RN / 4; ++k) {
        int ln_ = wv * (RN / 4) + k;
        int node = node0 + ln_;
        unsigned short* rowp = reinterpret_cast<unsigned short*>(s_agg) + ln_ * 256;
        int us = (l * 4) ^ ((ln_ & 7) << 3);
        if (node >= N) {  // zero pad row (keeps MFMA input finite)
            uint2 z; z.x = 0; z.y = 0;
            *reinterpret_cast<uint2*>(rowp + us) = z;
            continue;
        }
        int cb = hist[ln_];
        int bb = basei[ln_];
        uint2 u = reinterpret_cast<const uint2*>(featb + (size_t)node * D)[l];
        float4 acc;
        acc.x = bflo(u.x); acc.y = bfhi(u.x); acc.z = bflo(u.y); acc.w = bfhi(u.y);
        int j = 0;
        for (; j + 16 <= cb; j += 16) {
            int s[16];
            #pragma unroll
            for (int q = 0; q < 16; ++q) s[q] = elist[bb + j + q];
            uint2 v[16];
            #pragma unroll
            for (int q = 0; q < 16; ++q)
                v[q] = reinterpret_cast<const uint2*>(featb + (size_t)s[q] * D)[l];
            #pragma unroll
            for (int q = 0; q < 16; ++q) {
                acc.x += bflo(v[q].x); acc.y += bfhi(v[q].x);
                acc.z += bflo(v[q].y); acc.w += bfhi(v[q].y);
            }
        }
        for (; j + 8 <= cb; j += 8) {
            int s[8];
            #pragma unroll
            for (int q = 0; q < 8; ++q) s[q] = elist[bb + j + q];
            uint2 v[8];
            #pragma unroll
            for (int q = 0; q < 8; ++q)
                v[q] = reinterpret_cast<const uint2*>(featb + (size_t)s[q] * D)[l];
            #pragma unroll
            for (int q = 0; q < 8; ++q) {
                acc.x += bflo(v[q].x); acc.y += bfhi(v[q].x);
                acc.z += bflo(v[q].y); acc.w += bfhi(v[q].y);
            }
        }
        for (; j < cb; ++j) {
            uint2 v = reinterpret_cast<const uint2*>(featb + (size_t)elist[bb + j] * D)[l];
            acc.x += bflo(v.x); acc.y += bfhi(v.x);
            acc.z += bflo(v.y); acc.w += bfhi(v.y);
        }
        if (ovfn > 0) {
            for (int e = 0; e < ovfn; ++e) {
                if (ovf[2 * e + 1] == node) {
                    uint2 v = reinterpret_cast<const uint2*>(featb + (size_t)ovf[2 * e] * D)[l];
                    acc.x += bflo(v.x); acc.y += bfhi(v.x);
                    acc.z += bflo(v.y); acc.w += bfhi(v.y);
                }
            }
        }
        uint2 w;
        w.x = f2bf(acc.x) | (f2bf(acc.y) << 16);
        w.y = f2bf(acc.z) | (f2bf(acc.w) << 16);
        *reinterpret_cast<uint2*>(rowp + us) = w;
    }
    __syncthreads();

    // ---- fused GEMM: 32 rows x 256 cols, K=256 ----
    f32x4 acc[2][4];
    #pragma unroll
    for (int rt = 0; rt < 2; ++rt)
        #pragma unroll
        for (int ct = 0; ct < 4; ++ct) acc[rt][ct] = (f32x4){0.f, 0.f, 0.f, 0.f};

    const int g = l >> 4;
    const int cl = l & 15;
    for (int ks = 0; ks < 8; ++ks) {
        const int kb = ks * 32 + g * 8;
        s16x8 af[2];
        #pragma unroll
        for (int rt = 0; rt < 2; ++rt) {
            int lr = rt * 16 + cl;
            int ab = (lr * 512 + kb * 2) ^ ((lr & 7) << 4);
            af[rt] = *reinterpret_cast<const s16x8*>(s_agg + ab);
        }
        #pragma unroll
        for (int ct = 0; ct < 4; ++ct) {
            int col = wv * 64 + ct * 16 + cl;
            int bb = (col * 64 + g * 16) ^ ((col & 7) << 4);
            s16x8 bf = *reinterpret_cast<const s16x8*>(s_b + bb);
            acc[0][ct] = __builtin_amdgcn_mfma_f32_16x16x32_bf16(af[0], bf, acc[0][ct], 0, 0, 0);
            acc[1][ct] = __builtin_amdgcn_mfma_f32_16x16x32_bf16(af[1], bf, acc[1][ct], 0, 0, 0);
        }
        __syncthreads();
        if (ks < 7) {
            #pragma unroll
            for (int i = 0; i < 4; ++i) {
                int o = wv * 4096 + i * 1024;
                gload16(wb + (size_t)(ks + 1) * 16384 + o + l * 16, s_b + o);
            }
            __syncthreads();
        }
    }

    // epilogue: C/D map col=lane&15, row=(lane>>4)*4+reg
    #pragma unroll
    for (int rt = 0; rt < 2; ++rt) {
        #pragma unroll
        for (int ct = 0; ct < 4; ++ct) {
            #pragma unroll
            for (int rr = 0; rr < 4; ++rr) {
                int row = node0 + rt * 16 + (l >> 4) * 4 + rr;
                int col = wv * 64 + ct * 16 + cl;
                if (row < N)
                    out[(size_t)row * D + col] = fmaxf(acc[rt][ct][rr], 0.f);
            }
        }
    }
}

// ================= capacity-bucket build (fallback) =========
__global__ void k_fillcap(const int* __restrict__ src, const int* __restrict__ dst,
                          int* __restrict__ counts, int* __restrict__ buckets,
                          int* __restrict__ ovf, int* __restrict__ ovf_cnt, int E) {
    for (int e = blockIdx.x * blockDim.x + threadIdx.x; e < E;
         e += gridDim.x * blockDim.x) {
        int d = dst[e];
        int pos = atomicAdd(&counts[d], 1);
        if (pos < CAP) {
            buckets[(size_t)d * CAP + pos] = src[e];
        } else {
            int o = atomicAdd(ovf_cnt, 1);
            if (o < MAXOVF) {
                ovf[2 * o + 0] = src[e];
                ovf[2 * o + 1] = d;
            }
        }
    }
}

// ================= fallback gathers =================

#define GAT_BODY(LOAD, ACCUM)                                                  \
    int j = 0;                                                                 \
    for (; j + 16 <= cnt; j += 16) {                                           \
        int s[16];                                                             \
        _Pragma("unroll") for (int q = 0; q < 16; ++q) s[q] = bk[j + q];       \
        LOAD(16)                                                               \
        ACCUM(16)                                                              \
    }                                                                          \
    for (; j + 8 <= cnt; j += 8) {                                             \
        int s[8];                                                              \
        _Pragma("unroll") for (int q = 0; q < 8; ++q) s[q] = bk[j + q];        \
        LOAD(8)                                                                \
        ACCUM(8)                                                               \
    }

__global__ __launch_bounds__(256) void g_bf_aggb(const unsigned short* __restrict__ fb,
                                                 const int* __restrict__ counts,
                                                 const int* __restrict__ buckets,
                                                 const int* __restrict__ ovf,
                                                 const int* __restrict__ ovf_cnt,
                                                 unsigned short* __restrict__ aggb, int N) {
    int node = (int)((blockIdx.x * (long)blockDim.x + threadIdx.x) >> 6);
    int ln = threadIdx.x & 63;
    if (node >= N) return;
    int cnt_raw = counts[node];
    int cnt = cnt_raw > CAP ? CAP : cnt_raw;
    const int* bk = buckets + (size_t)node * CAP;
    uint2 u = reinterpret_cast<const uint2*>(fb + (size_t)node * D)[ln];
    float4 acc;
    acc.x = bflo(u.x); acc.y = bfhi(u.x); acc.z = bflo(u.y); acc.w = bfhi(u.y);
#define BLOAD(W_)                                                              \
    uint2 v[W_];                                                               \
    _Pragma("unroll") for (int q = 0; q < W_; ++q)                             \
        v[q] = reinterpret_cast<const uint2*>(fb + (size_t)s[q] * D)[ln];
#define BACC(W_)                                                               \
    _Pragma("unroll") for (int q = 0; q < W_; ++q) {                           \
        acc.x += bflo(v[q].x); acc.y += bfhi(v[q].x);                          \
        acc.z += bflo(v[q].y); acc.w += bfhi(v[q].y);                          \
    }
    GAT_BODY(BLOAD, BACC)
    for (; j < cnt; ++j) {
        uint2 v = reinterpret_cast<const uint2*>(fb + (size_t)bk[j] * D)[ln];
        acc.x += bflo(v.x); acc.y += bfhi(v.x);
        acc.z += bflo(v.y); acc.w += bfhi(v.y);
    }
    if (cnt_raw > CAP) {
        int m = *ovf_cnt;
        if (m > MAXOVF) m = MAXOVF;
        for (int e = 0; e < m; ++e) {
            if (ovf[2 * e + 1] == node) {
                uint2 v = reinterpret_cast<const uint2*>(fb + (size_t)ovf[2 * e] * D)[ln];
                acc.x += bflo(v.x); acc.y += bfhi(v.x);
                acc.z += bflo(v.y); acc.w += bfhi(v.y);
            }
        }
    }
    uint2 w;
    w.x = f2bf(acc.x) | (f2bf(acc.y) << 16);
    w.y = f2bf(acc.z) | (f2bf(acc.w) << 16);
    unsigned short* rowp = aggb + (size_t)node * D;
    int us = (ln * 4) ^ ((node & 7) << 3);
    *reinterpret_cast<uint2*>(rowp + us) = w;
}

__global__ __launch_bounds__(256) void g_f32_out(const float* __restrict__ feat,
                                                 const int* __restrict__ counts,
                                                 const int* __restrict__ buckets,
                                                 const int* __restrict__ ovf,
                                                 const int* __restrict__ ovf_cnt,
                                                 float* __restrict__ out, int N) {
    int node = (int)((blockIdx.x * (long)blockDim.x + threadIdx.x) >> 6);
    int ln = threadIdx.x & 63;
    if (node >= N) return;
    int cnt_raw = counts[node];
    int cnt = cnt_raw > CAP ? CAP : cnt_raw;
    const int* bk = buckets + (size_t)node * CAP;
    float4 acc = reinterpret_cast<const float4*>(feat + (size_t)node * D)[ln];
#define FLOAD(W_)                                                              \
    float4 v[W_];                                                              \
    _Pragma("unroll") for (int q = 0; q < W_; ++q)                             \
        v[q] = reinterpret_cast<const float4*>(feat + (size_t)s[q] * D)[ln];
#define FACC(W_)                                                               \
    _Pragma("unroll") for (int q = 0; q < W_; ++q) {                           \
        acc.x += v[q].x; acc.y += v[q].y; acc.z += v[q].z; acc.w += v[q].w;    \
    }
    GAT_BODY(FLOAD, FACC)
    for (; j < cnt; ++j) {
        float4 v = reinterpret_cast<const float4*>(feat + (size_t)bk[j] * D)[ln];
        acc.x += v.x; acc.y += v.y; acc.z += v.z; acc.w += v.w;
    }
    if (cnt_raw > CAP) {
        int m = *ovf_cnt;
        if (m > MAXOVF) m = MAXOVF;
        for (int e = 0; e < m; ++e) {
            if (ovf[2 * e + 1] == node) {
                float4 v = reinterpret_cast<const float4*>(feat + (size_t)ovf[2 * e] * D)[ln];
                acc.x += v.x; acc.y += v.y; acc.z += v.z; acc.w += v.w;
            }
        }
    }
    reinterpret_cast<float4*>(out + (size_t)node * D)[ln] = acc;
}

// ================= atomic scatter (last-resort) =================

__global__ __launch_bounds__(256) void gc_copy(const float* __restrict__ feat,
                                               float* __restrict__ agg, long n4) {
    long i = (long)blockIdx.x * blockDim.x + threadIdx.x;
    if (i < n4)
        reinterpret_cast<float4*>(agg)[i] = reinterpret_cast<const float4*>(feat)[i];
}

__global__ __launch_bounds__(256) void gc_scatter(const float* __restrict__ feat,
                                                  const int* __restrict__ src,
                                                  const int* __restrict__ dst,
                                                  float* __restrict__ agg, int n_edges) {
    int wave = (int)((blockIdx.x * (long)blockDim.x + threadIdx.x) >> 6);
    int lane = threadIdx.x & 63;
    if (wave >= n_edges) return;
    int s = src[wave];
    int d = dst[wave];
    const float4 v = reinterpret_cast<const float4*>(feat + (size_t)s * D)[lane];
    float* p = agg + (size_t)d * D + (size_t)lane * 4;
    atomicAdd(p + 0, v.x);
    atomicAdd(p + 1, v.y);
    atomicAdd(p + 2, v.z);
    atomicAdd(p + 3, v.w);
}

// ================= standalone MFMA GEMMs (fallback tiers) =================

__global__ __launch_bounds__(256) void gemm_mfma_b(const unsigned short* __restrict__ aggb,
                                                   const unsigned short* __restrict__ wTs,
                                                   float* __restrict__ out, int n_rows) {
    __shared__ __align__(16) unsigned char s_a[BM * 512];
    __shared__ __align__(16) unsigned char s_b[16384];
    const int t = threadIdx.x;
    const int row0 = blockIdx.x * BM;
    const int wv = t >> 6;
    const int l = t & 63;
    const char* wb = reinterpret_cast<const char*>(wTs);

    const char* gbase = reinterpret_cast<const char*>(aggb) + (size_t)row0 * 512;
    #pragma unroll
    for (int q = 0; q < 8; ++q) {
        int off = wv * 8192 + q * 1024;
        gload16(gbase + off + l * 16, s_a + off);
    }
    #pragma unroll
    for (int i = 0; i < 4; ++i) {
        int off = wv * 4096 + i * 1024;
        gload16(wb + off + l * 16, s_b + off);
    }
    __syncthreads();

    f32x4 acc[16];
    #pragma unroll
    for (int ct = 0; ct < 16; ++ct) acc[ct] = (f32x4){0.f, 0.f, 0.f, 0.f};

    const int lr = wv * 16 + (l & 15);
    const int g = l >> 4;
    for (int ks = 0; ks < 8; ++ks) {
        const int kb = ks * 32 + g * 8;
        const int ab = (lr * 512 + kb * 2) ^ ((lr & 7) << 4);
        s16x8 af = *reinterpret_cast<const s16x8*>(s_a + ab);
        #pragma unroll
        for (int ct = 0; ct < 16; ++ct) {
            int col = ct * 16 + (l & 15);
            int bb = (col * 64 + g * 16) ^ ((col & 7) << 4);
            s16x8 bf = *reinterpret_cast<const s16x8*>(s_b + bb);
            acc[ct] = __builtin_amdgcn_mfma_f32_16x16x32_bf16(af, bf, acc[ct], 0, 0, 0);
        }
        __syncthreads();
        if (ks < 7) {
            #pragma unroll
            for (int i = 0; i < 4; ++i) {
                int off = wv * 4096 + i * 1024;
                gload16(wb + (size_t)(ks + 1) * 16384 + off + l * 16, s_b + off);
            }
            __syncthreads();
        }
    }

    const int rbase = row0 + wv * 16 + (l >> 4) * 4;
    const int cb = l & 15;
    #pragma unroll
    for (int ct = 0; ct < 16; ++ct) {
        #pragma unroll
        for (int r = 0; r < 4; ++r) {
            int row = rbase + r;
            if (row < n_rows)
                out[(size_t)row * D + ct * 16 + cb] = fmaxf(acc[ct][r], 0.f);
        }
    }
}

__global__ __launch_bounds__(256) void gemm_mfma(const unsigned short* __restrict__ wTs,
                                                 float* __restrict__ out, int n_rows) {
    __shared__ __align__(16) unsigned char s_a[BM * 512];
    __shared__ __align__(16) unsigned char s_b[16384];
    const int t = threadIdx.x;
    const int row0 = blockIdx.x * BM;
    const int wv = t >> 6;
    const int l = t & 63;
    const char* wb = reinterpret_cast<const char*>(wTs);

    #pragma unroll
    for (int i = 0; i < 4; ++i) {
        int off = wv * 4096 + i * 1024;
        gload16(wb + off + l * 16, s_b + off);
    }
    #pragma unroll
    for (int i = 0; i < 16; ++i) {
        int f4 = t + 256 * i;
        int row = f4 >> 6;
        int kc = f4 & 63;
        int grow = row0 + row;
        if (grow >= n_rows) grow = n_rows - 1;
        float4 v = *reinterpret_cast<const float4*>(out + (size_t)grow * D + kc * 4);
        uint2 u;
        u.x = f2bf(v.x) | (f2bf(v.y) << 16);
        u.y = f2bf(v.z) | (f2bf(v.w) << 16);
        int byte = (row * 512 + kc * 8) ^ ((row & 7) << 4);
        *reinterpret_cast<uint2*>(s_a + byte) = u;
    }
    __syncthreads();

    f32x4 acc[16];
    #pragma unroll
    for (int ct = 0; ct < 16; ++ct) acc[ct] = (f32x4){0.f, 0.f, 0.f, 0.f};

    const int lr = wv * 16 + (l & 15);
    const int g = l >> 4;
    for (int ks = 0; ks < 8; ++ks) {
        const int kb = ks * 32 + g * 8;
        const int ab = (lr * 512 + kb * 2) ^ ((lr & 7) << 4);
        s16x8 af = *reinterpret_cast<const s16x8*>(s_a + ab);
        #pragma unroll
        for (int ct = 0; ct < 16; ++ct) {
            int col = ct * 16 + (l & 15);
            int bb = (col * 64 + g * 16) ^ ((col & 7) << 4);
            s16x8 bf = *reinterpret_cast<const s16x8*>(s_b + bb);
            acc[ct] = __builtin_amdgcn_mfma_f32_16x16x32_bf16(af, bf, acc[ct], 0, 0, 0);
        }
        __syncthreads();
        if (ks < 7) {
            #pragma unroll
            for (int i = 0; i < 4; ++i) {
                int off = wv * 4096 + i * 1024;
                gload16(wb + (size_t)(ks + 1) * 16384 + off + l * 16, s_b + off);
            }
            __syncthreads();
        }
    }

    const int rbase = row0 + wv * 16 + (l >> 4) * 4;
    const int cb = l & 15;
    #pragma unroll
    for (int ct = 0; ct < 16; ++ct) {
        #pragma unroll
        for (int r = 0; r < 4; ++r) {
            int row = rbase + r;
            if (row < n_rows)
                out[(size_t)row * D + ct * 16 + cb] = fmaxf(acc[ct][r], 0.f);
        }
    }
}

// legacy fp32 GEMM (no-workspace fallback)
__global__ __launch_bounds__(256) void gemm_relu(const float* __restrict__ Wm,
                                                 float* __restrict__ out, int n_rows) {
    __shared__ float s_a[32][D];
    const int row0 = blockIdx.x * 32;
    const int c = threadIdx.x;
    {
        const float4* gsrc = reinterpret_cast<const float4*>(out + (size_t)row0 * D);
        float4* ldst = reinterpret_cast<float4*>(&s_a[0][0]);
        #pragma unroll
        for (int i = 0; i < 8; ++i)
            ldst[threadIdx.x + i * 256] = gsrc[threadIdx.x + i * 256];
    }
    __syncthreads();
    float acc[32];
    #pragma unroll
    for (int r = 0; r < 32; ++r) acc[r] = 0.f;
    #pragma unroll 4
    for (int k = 0; k < D; ++k) {
        float w = Wm[(size_t)k * D + c];
        #pragma unroll
        for (int r = 0; r < 32; ++r) acc[r] += s_a[r][k] * w;
    }
    #pragma unroll
    for (int r = 0; r < 32; ++r) {
        int row = row0 + r;
        if (row < n_rows) out[(size_t)row * D + c] = fmaxf(acc[r], 0.f);
    }
}

extern "C" void kernel_launch(void* const* d_in, const int* in_sizes, int n_in,
                              void* d_out, int out_size, void* d_ws, size_t ws_size,
                              hipStream_t stream) {
    const float* feat = (const float*)d_in[0];
    const float* W    = (const float*)d_in[1];
    const int*   src  = (const int*)d_in[2];
    const int*   dst  = (const int*)d_in[3];
    float* out = (float*)d_out;

    const int N = in_sizes[0] / D;  // 100000
    const int E = in_sizes[2];      // 1600000
    const int Npad = ((N + BM - 1) / BM) * BM;
    auto al = [](size_t x) { return (x + 255) & ~(size_t)255; };

    const int nranges = (N + RN - 1) / RN;   // 3125
    const int gemm_blocks = (N + BM - 1) / BM;
    const int gat_blocks = (N + 3) / 4;

    // ---- tier A2 layout: gcur | ovf_cnt | ovf | streams | featb | wTs
    const size_t hdr_bytes   = ((size_t)nranges + 1 + 2 * MAXOVF) * 4;
    const size_t strm_off    = al(hdr_bytes);
    const size_t strm_sz     = (size_t)nranges * SCAP * 4;
    const size_t a2_featb_off = al(strm_off + strm_sz);
    const size_t featb_sz    = (size_t)N * D * 2;
    const size_t a2_wt_off   = al(a2_featb_off + featb_sz);
    const size_t wt_sz       = (size_t)D * D * 2;
    const size_t need_A2     = a2_wt_off + wt_sz;

    // ---- fallback tier layouts
    const size_t cap_bytes = ((size_t)N + 1 + 2 * MAXOVF + (size_t)N * CAP) * 4;
    const size_t featb_off = al(cap_bytes);
    const size_t wt_off    = al(featb_off + featb_sz);
    const size_t aggb_off  = al(wt_off + wt_sz);
    const size_t aggb_sz   = (size_t)Npad * D * 2;
    const size_t need_A    = aggb_off + aggb_sz;

    if (ws_size >= need_A2 && nranges <= NRANGES_MAX) {
        char* base = (char*)d_ws;
        int* gcur    = (int*)base;
        int* ovf_cnt = gcur + nranges;
        int* ovf     = ovf_cnt + 1;
        int* streams = (int*)(base + strm_off);
        unsigned short* featb = (unsigned short*)(base + a2_featb_off);
        unsigned short* wTs   = (unsigned short*)(base + a2_wt_off);

        k_pre<<<2048, 256, 0, stream>>>(feat, featb, W, wTs, gcur, nranges + 1,
                                        (long)N * D / 8);
        k_part<<<(E + PCH - 1) / PCH, PTH, 0, stream>>>(src, dst, gcur, streams,
                                                        ovf, ovf_cnt, E, nranges);
        k_sgg<<<nranges, SGT, 0, stream>>>(featb, gcur, streams, ovf, ovf_cnt,
                                           wTs, out, N);
    } else if (ws_size >= need_A) {
        char* base = (char*)d_ws;
        int* counts  = (int*)base;
        int* ovf_cnt = counts + N;
        int* ovf     = ovf_cnt + 1;
        int* buckets = ovf + 2 * MAXOVF;
        unsigned short* featb = (unsigned short*)(base + featb_off);
        unsigned short* wTs   = (unsigned short*)(base + wt_off);
        unsigned short* aggb  = (unsigned short*)(base + aggb_off);

        k_zero<<<(N + 1 + 255) / 256, 256, 0, stream>>>(counts, N + 1);
        k_f2b<<<2048, 256, 0, stream>>>(feat, featb, (long)N * D / 8);
        k_wTs<<<D, 256, 0, stream>>>(W, wTs);
        k_fillcap<<<2048, 256, 0, stream>>>(src, dst, counts, buckets, ovf, ovf_cnt, E);
        g_bf_aggb<<<gat_blocks, 256, 0, stream>>>(featb, counts, buckets, ovf, ovf_cnt, aggb, N);
        gemm_mfma_b<<<gemm_blocks, 256, 0, stream>>>(aggb, wTs, out, N);
    } else if (ws_size >= cap_bytes) {
        char* base = (char*)d_ws;
        int* counts  = (int*)base;
        int* ovf_cnt = counts + N;
        int* ovf     = ovf_cnt + 1;
        int* buckets = ovf + 2 * MAXOVF;
        unsigned short* wTs = (unsigned short*)(((uintptr_t)buckets + 255) & ~(uintptr_t)255);

        k_zero<<<(N + 1 + 255) / 256, 256, 0, stream>>>(counts, N + 1);
        k_fillcap<<<2048, 256, 0, stream>>>(src, dst, counts, buckets, ovf, ovf_cnt, E);
        g_f32_out<<<gat_blocks, 256, 0, stream>>>(feat, counts, buckets, ovf, ovf_cnt, out, N);
        k_wTs<<<D, 256, 0, stream>>>(W, wTs);
        gemm_mfma<<<gemm_blocks, 256, 0, stream>>>(wTs, out, N);
    } else {
        long n4 = (long)N * D / 4;
        gc_copy<<<(int)((n4 + 255) / 256), 256, 0, stream>>>(feat, out, n4);
        gc_scatter<<<(E + 3) / 4, 256, 0, stream>>>(feat, src, dst, out, E);
        gemm_relu<<<(N + 31) / 32, 256, 0, stream>>>(W, out, N);
    }
}

// Round 13
// 212.494 us; speedup vs baseline: 1.6267x; 1.0130x over previous
//
#include <hip/hip_runtime.h>

#define D 256
#define CAP 32
#define MAXOVF 4096
#define BM 64

// range-partition params
#define RN 32           // nodes per range
#define RSH 5
#define SCAP 1024       // stream capacity per range (mean 512)
#define PCH 8192        // edges per k_part block
#define PTH 512         // k_part threads
#define NRANGES_MAX 4096
#define SGT 256         // k_sgg threads (4 waves)

typedef float f32x4 __attribute__((ext_vector_type(4)));
typedef short s16x8 __attribute__((ext_vector_type(8)));

__device__ inline unsigned int f2bf(float x) {
    unsigned int u = __float_as_uint(x);
    return (u + 0x7FFFu + ((u >> 16) & 1u)) >> 16;  // RNE, low 16 bits valid
}
__device__ inline float bflo(unsigned int u) { return __uint_as_float(u << 16); }
__device__ inline float bfhi(unsigned int u) { return __uint_as_float(u & 0xFFFF0000u); }

__device__ inline void gload16(const char* g, const unsigned char* lds) {
    __builtin_amdgcn_global_load_lds(
        (const __attribute__((address_space(1))) void*)g,
        (__attribute__((address_space(3))) void*)lds, 16, 0, 0);
}

// ================= merged prologue: wTs + gcur-zero + f2b =================
__global__ __launch_bounds__(256) void k_pre(const float* __restrict__ feat,
                                             unsigned short* __restrict__ featb,
                                             const float* __restrict__ W,
                                             unsigned short* __restrict__ wTs,
                                             int* __restrict__ gcur, int nz, long n8) {
    const int bid = blockIdx.x;
    const int t = threadIdx.x;
    if (bid < 256) {
        unsigned short v = (unsigned short)f2bf(W[(size_t)t * D + bid]);
        int ks = t >> 5;
        int byte = ((bid << 6) + (((t >> 3) & 3) << 4) + ((t & 7) << 1)) ^ ((bid & 7) << 4);
        *reinterpret_cast<unsigned short*>(
            reinterpret_cast<char*>(wTs) + (size_t)ks * 16384 + byte) = v;
    } else if (bid < 272) {
        int i = (bid - 256) * 256 + t;
        if (i < nz) gcur[i] = 0;
    }
    for (long i = bid * 256L + t; i < n8; i += (long)gridDim.x * 256) {
        const float4* p = reinterpret_cast<const float4*>(feat + i * 8);
        float4 a = p[0], b = p[1];
        uint4 u;
        u.x = f2bf(a.x) | (f2bf(a.y) << 16);
        u.y = f2bf(a.z) | (f2bf(a.w) << 16);
        u.z = f2bf(b.x) | (f2bf(b.y) << 16);
        u.w = f2bf(b.z) | (f2bf(b.w) << 16);
        reinterpret_cast<uint4*>(featb)[i] = u;
    }
}

// ================= standalone utility kernels (fallback tiers) =============

__global__ void k_zero(int* __restrict__ p, int n) {
    int i = blockIdx.x * blockDim.x + threadIdx.x;
    if (i < n) p[i] = 0;
}

__global__ __launch_bounds__(256) void k_f2b(const float* __restrict__ f,
                                             unsigned short* __restrict__ fb, long n8) {
    for (long i = blockIdx.x * 256L + threadIdx.x; i < n8; i += (long)gridDim.x * 256) {
        const float4* p = reinterpret_cast<const float4*>(f + i * 8);
        float4 a = p[0], b = p[1];
        uint4 u;
        u.x = f2bf(a.x) | (f2bf(a.y) << 16);
        u.y = f2bf(a.z) | (f2bf(a.w) << 16);
        u.z = f2bf(b.x) | (f2bf(b.y) << 16);
        u.w = f2bf(b.z) | (f2bf(b.w) << 16);
        reinterpret_cast<uint4*>(fb)[i] = u;
    }
}

__global__ __launch_bounds__(256) void k_wTs(const float* __restrict__ W,
                                             unsigned short* __restrict__ wTs) {
    int col = blockIdx.x;
    int k = threadIdx.x;
    unsigned short v = (unsigned short)f2bf(W[(size_t)k * D + col]);
    int ks = k >> 5;
    int byte = ((col << 6) + (((k >> 3) & 3) << 4) + ((k & 7) << 1)) ^ ((col & 7) << 4);
    *reinterpret_cast<unsigned short*>(
        reinterpret_cast<char*>(wTs) + (size_t)ks * 16384 + byte) = v;
}

// ================= phase 1: range partition (dense appends) =================
__global__ __launch_bounds__(PTH) void k_part(const int* __restrict__ src,
                                              const int* __restrict__ dst,
                                              int* __restrict__ gcur,
                                              int* __restrict__ streams,
                                              int* __restrict__ ovf,
                                              int* __restrict__ ovf_cnt,
                                              int E, int nranges) {
    __shared__ int hist[NRANGES_MAX];
    __shared__ int base[NRANGES_MAX];
    __shared__ int off[NRANGES_MAX];
    const int t = threadIdx.x;
    const long e0 = (long)blockIdx.x * PCH;
    for (int i = t; i < nranges; i += PTH) hist[i] = 0;
    __syncthreads();
    int md[PCH / PTH], ms[PCH / PTH];
    #pragma unroll
    for (int i = 0; i < PCH / PTH; ++i) {
        long e = e0 + (long)i * PTH + t;
        if (e < E) {
            md[i] = dst[e];
            ms[i] = src[e];
            atomicAdd(&hist[md[i] >> RSH], 1);
        } else {
            md[i] = -1;
        }
    }
    __syncthreads();
    for (int i = t; i < nranges; i += PTH) {
        int h = hist[i];
        base[i] = h ? atomicAdd(&gcur[i], h) : 0;
        off[i] = 0;
    }
    __syncthreads();
    #pragma unroll
    for (int i = 0; i < PCH / PTH; ++i) {
        if (md[i] >= 0) {
            int r = md[i] >> RSH;
            int p = base[r] + atomicAdd(&off[r], 1);
            if (p < SCAP) {
                streams[(size_t)r * SCAP + p] = (ms[i] << RSH) | (md[i] & (RN - 1));
            } else {
                int o = atomicAdd(ovf_cnt, 1);
                if (o < MAXOVF) { ovf[2 * o] = ms[i]; ovf[2 * o + 1] = md[i]; }
            }
        }
    }
}

// ====== phase 2: LDS counting-sort + fused gather + fused MFMA GEMM ======
// One block (256 thr, 4 waves) per range of 32 nodes. Gather accumulates
// fp32 in regs, writes bf16 swizzled into s_agg (LDS); MFMA reads B-frags
// DIRECTLY from wTs (L2-resident, no LDS staging, no GEMM-loop barriers).
__global__ __launch_bounds__(SGT) void k_sgg(const unsigned short* __restrict__ featb,
                                             const int* __restrict__ gcur,
                                             const int* __restrict__ streams,
                                             const int* __restrict__ ovf,
                                             const int* __restrict__ ovf_cnt,
                                             const unsigned short* __restrict__ wTs,
                                             float* __restrict__ out, int N) {
    __shared__ int hist[RN], basei[RN], off[RN], scn[RN];
    __shared__ int elist[SCAP];                              // 4 KB
    __shared__ __align__(16) unsigned char s_agg[RN * 512];  // 16 KB
    const int r = blockIdx.x;
    const int t = threadIdx.x;
    const int node0 = r << RSH;
    const int wv = t >> 6;   // 0..3
    const int l = t & 63;
    const char* wb = reinterpret_cast<const char*>(wTs);

    // ---- sort prologue ----
    int cnt = gcur[r];
    if (cnt > SCAP) cnt = SCAP;
    if (t < RN) { hist[t] = 0; off[t] = 0; }
    __syncthreads();
    int ent[SCAP / SGT];
    #pragma unroll
    for (int i = 0; i < SCAP / SGT; ++i) {
        int p = t + i * SGT;
        if (p < cnt) {
            ent[i] = streams[(size_t)r * SCAP + p];
            atomicAdd(&hist[ent[i] & (RN - 1)], 1);
        } else {
            ent[i] = -1;
        }
    }
    __syncthreads();
    if (t < RN) scn[t] = hist[t];
    __syncthreads();
    for (int st = 1; st < RN; st <<= 1) {
        int v = 0;
        if (t < RN && t >= st) v = scn[t - st];
        __syncthreads();
        if (t < RN) scn[t] += v;
        __syncthreads();
    }
    if (t < RN) basei[t] = scn[t] - hist[t];
    __syncthreads();
    #pragma unroll
    for (int i = 0; i < SCAP / SGT; ++i) {
        if (ent[i] >= 0) {
            int ln_ = ent[i] & (RN - 1);
            int p = basei[ln_] + atomicAdd(&off[ln_], 1);
            elist[p] = ent[i] >> RSH;
        }
    }
    __syncthreads();

    // ---- gather into s_agg ----
    int ovfn = *ovf_cnt;
    if (ovfn > MAXOVF) ovfn = MAXOVF;
    for (int k = 0; k < RN / 4; ++k) {
        int ln_ = wv * (RN / 4) + k;
        int node = node0 + ln_;
        unsigned short* rowp = reinterpret_cast<unsigned short*>(s_agg) + ln_ * 256;
        int us = (l * 4) ^ ((ln_ & 7) << 3);
        if (node >= N) {  // zero pad row (keeps MFMA input finite)
            uint2 z; z.x = 0; z.y = 0;
            *reinterpret_cast<uint2*>(rowp + us) = z;
            continue;
        }
        int cb = hist[ln_];
        int bb = basei[ln_];
        uint2 u = reinterpret_cast<const uint2*>(featb + (size_t)node * D)[l];
        float4 acc;
        acc.x = bflo(u.x); acc.y = bfhi(u.x); acc.z = bflo(u.y); acc.w = bfhi(u.y);
        int j = 0;
        for (; j + 16 <= cb; j += 16) {
            int s[16];
            #pragma unroll
            for (int q = 0; q < 16; ++q) s[q] = elist[bb + j + q];
            uint2 v[16];
            #pragma unroll
            for (int q = 0; q < 16; ++q)
                v[q] = reinterpret_cast<const uint2*>(featb + (size_t)s[q] * D)[l];
            #pragma unroll
            for (int q = 0; q < 16; ++q) {
                acc.x += bflo(v[q].x); acc.y += bfhi(v[q].x);
                acc.z += bflo(v[q].y); acc.w += bfhi(v[q].y);
            }
        }
        for (; j + 8 <= cb; j += 8) {
            int s[8];
            #pragma unroll
            for (int q = 0; q < 8; ++q) s[q] = elist[bb + j + q];
            uint2 v[8];
            #pragma unroll
            for (int q = 0; q < 8; ++q)
                v[q] = reinterpret_cast<const uint2*>(featb + (size_t)s[q] * D)[l];
            #pragma unroll
            for (int q = 0; q < 8; ++q) {
                acc.x += bflo(v[q].x); acc.y += bfhi(v[q].x);
                acc.z += bflo(v[q].y); acc.w += bfhi(v[q].y);
            }
        }
        for (; j < cb; ++j) {
            uint2 v = reinterpret_cast<const uint2*>(featb + (size_t)elist[bb + j] * D)[l];
            acc.x += bflo(v.x); acc.y += bfhi(v.x);
            acc.z += bflo(v.y); acc.w += bfhi(v.y);
        }
        if (ovfn > 0) {
            for (int e = 0; e < ovfn; ++e) {
                if (ovf[2 * e + 1] == node) {
                    uint2 v = reinterpret_cast<const uint2*>(featb + (size_t)ovf[2 * e] * D)[l];
                    acc.x += bflo(v.x); acc.y += bfhi(v.x);
                    acc.z += bflo(v.y); acc.w += bfhi(v.y);
                }
            }
        }
        uint2 w;
        w.x = f2bf(acc.x) | (f2bf(acc.y) << 16);
        w.y = f2bf(acc.z) | (f2bf(acc.w) << 16);
        *reinterpret_cast<uint2*>(rowp + us) = w;
    }
    __syncthreads();  // s_agg ready; no further barriers

    // ---- fused GEMM: 32 rows x 256 cols, K=256; B direct from L2 ----
    f32x4 acc[2][4];
    #pragma unroll
    for (int rt = 0; rt < 2; ++rt)
        #pragma unroll
        for (int ct = 0; ct < 4; ++ct) acc[rt][ct] = (f32x4){0.f, 0.f, 0.f, 0.f};

    const int g = l >> 4;
    const int cl = l & 15;
    #pragma unroll
    for (int ks = 0; ks < 8; ++ks) {
        const int kb = ks * 32 + g * 8;
        // batch the 4 B-frag L2 loads first (4-deep MLP, no barrier)
        s16x8 bf[4];
        #pragma unroll
        for (int ct = 0; ct < 4; ++ct) {
            int col = wv * 64 + ct * 16 + cl;
            int bb = (col * 64 + g * 16) ^ ((col & 7) << 4);
            bf[ct] = *reinterpret_cast<const s16x8*>(wb + (size_t)ks * 16384 + bb);
        }
        s16x8 af[2];
        #pragma unroll
        for (int rt = 0; rt < 2; ++rt) {
            int lr = rt * 16 + cl;
            int ab = (lr * 512 + kb * 2) ^ ((lr & 7) << 4);
            af[rt] = *reinterpret_cast<const s16x8*>(s_agg + ab);
        }
        #pragma unroll
        for (int ct = 0; ct < 4; ++ct) {
            acc[0][ct] = __builtin_amdgcn_mfma_f32_16x16x32_bf16(af[0], bf[ct], acc[0][ct], 0, 0, 0);
            acc[1][ct] = __builtin_amdgcn_mfma_f32_16x16x32_bf16(af[1], bf[ct], acc[1][ct], 0, 0, 0);
        }
    }

    // epilogue: C/D map col=lane&15, row=(lane>>4)*4+reg
    #pragma unroll
    for (int rt = 0; rt < 2; ++rt) {
        #pragma unroll
        for (int ct = 0; ct < 4; ++ct) {
            #pragma unroll
            for (int rr = 0; rr < 4; ++rr) {
                int row = node0 + rt * 16 + (l >> 4) * 4 + rr;
                int col = wv * 64 + ct * 16 + cl;
                if (row < N)
                    out[(size_t)row * D + col] = fmaxf(acc[rt][ct][rr], 0.f);
            }
        }
    }
}

// ================= capacity-bucket build (fallback) =========
__global__ void k_fillcap(const int* __restrict__ src, const int* __restrict__ dst,
                          int* __restrict__ counts, int* __restrict__ buckets,
                          int* __restrict__ ovf, int* __restrict__ ovf_cnt, int E) {
    for (int e = blockIdx.x * blockDim.x + threadIdx.x; e < E;
         e += gridDim.x * blockDim.x) {
        int d = dst[e];
        int pos = atomicAdd(&counts[d], 1);
        if (pos < CAP) {
            buckets[(size_t)d * CAP + pos] = src[e];
        } else {
            int o = atomicAdd(ovf_cnt, 1);
            if (o < MAXOVF) {
                ovf[2 * o + 0] = src[e];
                ovf[2 * o + 1] = d;
            }
        }
    }
}

// ================= fallback gathers =================

#define GAT_BODY(LOAD, ACCUM)                                                  \
    int j = 0;                                                                 \
    for (; j + 16 <= cnt; j += 16) {                                           \
        int s[16];                                                             \
        _Pragma("unroll") for (int q = 0; q < 16; ++q) s[q] = bk[j + q];       \
        LOAD(16)                                                               \
        ACCUM(16)                                                              \
    }                                                                          \
    for (; j + 8 <= cnt; j += 8) {                                             \
        int s[8];                                                              \
        _Pragma("unroll") for (int q = 0; q < 8; ++q) s[q] = bk[j + q];        \
        LOAD(8)                                                                \
        ACCUM(8)                                                               \
    }

__global__ __launch_bounds__(256) void g_bf_aggb(const unsigned short* __restrict__ fb,
                                                 const int* __restrict__ counts,
                                                 const int* __restrict__ buckets,
                                                 const int* __restrict__ ovf,
                                                 const int* __restrict__ ovf_cnt,
                                                 unsigned short* __restrict__ aggb, int N) {
    int node = (int)((blockIdx.x * (long)blockDim.x + threadIdx.x) >> 6);
    int ln = threadIdx.x & 63;
    if (node >= N) return;
    int cnt_raw = counts[node];
    int cnt = cnt_raw > CAP ? CAP : cnt_raw;
    const int* bk = buckets + (size_t)node * CAP;
    uint2 u = reinterpret_cast<const uint2*>(fb + (size_t)node * D)[ln];
    float4 acc;
    acc.x = bflo(u.x); acc.y = bfhi(u.x); acc.z = bflo(u.y); acc.w = bfhi(u.y);
#define BLOAD(W_)                                                              \
    uint2 v[W_];                                                               \
    _Pragma("unroll") for (int q = 0; q < W_; ++q)                             \
        v[q] = reinterpret_cast<const uint2*>(fb + (size_t)s[q] * D)[ln];
#define BACC(W_)                                                               \
    _Pragma("unroll") for (int q = 0; q < W_; ++q) {                           \
        acc.x += bflo(v[q].x); acc.y += bfhi(v[q].x);                          \
        acc.z += bflo(v[q].y); acc.w += bfhi(v[q].y);                          \
    }
    GAT_BODY(BLOAD, BACC)
    for (; j < cnt; ++j) {
        uint2 v = reinterpret_cast<const uint2*>(fb + (size_t)bk[j] * D)[ln];
        acc.x += bflo(v.x); acc.y += bfhi(v.x);
        acc.z += bflo(v.y); acc.w += bfhi(v.y);
    }
    if (cnt_raw > CAP) {
        int m = *ovf_cnt;
        if (m > MAXOVF) m = MAXOVF;
        for (int e = 0; e < m; ++e) {
            if (ovf[2 * e + 1] == node) {
                uint2 v = reinterpret_cast<const uint2*>(fb + (size_t)ovf[2 * e] * D)[ln];
                acc.x += bflo(v.x); acc.y += bfhi(v.x);
                acc.z += bflo(v.y); acc.w += bfhi(v.y);
            }
        }
    }
    uint2 w;
    w.x = f2bf(acc.x) | (f2bf(acc.y) << 16);
    w.y = f2bf(acc.z) | (f2bf(acc.w) << 16);
    unsigned short* rowp = aggb + (size_t)node * D;
    int us = (ln * 4) ^ ((node & 7) << 3);
    *reinterpret_cast<uint2*>(rowp + us) = w;
}

__global__ __launch_bounds__(256) void g_f32_out(const float* __restrict__ feat,
                                                 const int* __restrict__ counts,
                                                 const int* __restrict__ buckets,
                                                 const int* __restrict__ ovf,
                                                 const int* __restrict__ ovf_cnt,
                                                 float* __restrict__ out, int N) {
    int node = (int)((blockIdx.x * (long)blockDim.x + threadIdx.x) >> 6);
    int ln = threadIdx.x & 63;
    if (node >= N) return;
    int cnt_raw = counts[node];
    int cnt = cnt_raw > CAP ? CAP : cnt_raw;
    const int* bk = buckets + (size_t)node * CAP;
    float4 acc = reinterpret_cast<const float4*>(feat + (size_t)node * D)[ln];
#define FLOAD(W_)                                                              \
    float4 v[W_];                                                              \
    _Pragma("unroll") for (int q = 0; q < W_; ++q)                             \
        v[q] = reinterpret_cast<const float4*>(feat + (size_t)s[q] * D)[ln];
#define FACC(W_)                                                               \
    _Pragma("unroll") for (int q = 0; q < W_; ++q) {                           \
        acc.x += v[q].x; acc.y += v[q].y; acc.z += v[q].z; acc.w += v[q].w;    \
    }
    GAT_BODY(FLOAD, FACC)
    for (; j < cnt; ++j) {
        float4 v = reinterpret_cast<const float4*>(feat + (size_t)bk[j] * D)[ln];
        acc.x += v.x; acc.y += v.y; acc.z += v.z; acc.w += v.w;
    }
    if (cnt_raw > CAP) {
        int m = *ovf_cnt;
        if (m > MAXOVF) m = MAXOVF;
        for (int e = 0; e < m; ++e) {
            if (ovf[2 * e + 1] == node) {
                float4 v = reinterpret_cast<const float4*>(feat + (size_t)ovf[2 * e] * D)[ln];
                acc.x += v.x; acc.y += v.y; acc.z += v.z; acc.w += v.w;
            }
        }
    }
    reinterpret_cast<float4*>(out + (size_t)node * D)[ln] = acc;
}

// ================= atomic scatter (last-resort) =================

__global__ __launch_bounds__(256) void gc_copy(const float* __restrict__ feat,
                                               float* __restrict__ agg, long n4) {
    long i = (long)blockIdx.x * blockDim.x + threadIdx.x;
    if (i < n4)
        reinterpret_cast<float4*>(agg)[i] = reinterpret_cast<const float4*>(feat)[i];
}

__global__ __launch_bounds__(256) void gc_scatter(const float* __restrict__ feat,
                                                  const int* __restrict__ src,
                                                  const int* __restrict__ dst,
                                                  float* __restrict__ agg, int n_edges) {
    int wave = (int)((blockIdx.x * (long)blockDim.x + threadIdx.x) >> 6);
    int lane = threadIdx.x & 63;
    if (wave >= n_edges) return;
    int s = src[wave];
    int d = dst[wave];
    const float4 v = reinterpret_cast<const float4*>(feat + (size_t)s * D)[lane];
    float* p = agg + (size_t)d * D + (size_t)lane * 4;
    atomicAdd(p + 0, v.x);
    atomicAdd(p + 1, v.y);
    atomicAdd(p + 2, v.z);
    atomicAdd(p + 3, v.w);
}

// ================= standalone MFMA GEMMs (fallback tiers) =================

__global__ __launch_bounds__(256) void gemm_mfma_b(const unsigned short* __restrict__ aggb,
                                                   const unsigned short* __restrict__ wTs,
                                                   float* __restrict__ out, int n_rows) {
    __shared__ __align__(16) unsigned char s_a[BM * 512];
    __shared__ __align__(16) unsigned char s_b[16384];
    const int t = threadIdx.x;
    const int row0 = blockIdx.x * BM;
    const int wv = t >> 6;
    const int l = t & 63;
    const char* wb = reinterpret_cast<const char*>(wTs);

    const char* gbase = reinterpret_cast<const char*>(aggb) + (size_t)row0 * 512;
    #pragma unroll
    for (int q = 0; q < 8; ++q) {
        int off = wv * 8192 + q * 1024;
        gload16(gbase + off + l * 16, s_a + off);
    }
    #pragma unroll
    for (int i = 0; i < 4; ++i) {
        int off = wv * 4096 + i * 1024;
        gload16(wb + off + l * 16, s_b + off);
    }
    __syncthreads();

    f32x4 acc[16];
    #pragma unroll
    for (int ct = 0; ct < 16; ++ct) acc[ct] = (f32x4){0.f, 0.f, 0.f, 0.f};

    const int lr = wv * 16 + (l & 15);
    const int g = l >> 4;
    for (int ks = 0; ks < 8; ++ks) {
        const int kb = ks * 32 + g * 8;
        const int ab = (lr * 512 + kb * 2) ^ ((lr & 7) << 4);
        s16x8 af = *reinterpret_cast<const s16x8*>(s_a + ab);
        #pragma unroll
        for (int ct = 0; ct < 16; ++ct) {
            int col = ct * 16 + (l & 15);
            int bb = (col * 64 + g * 16) ^ ((col & 7) << 4);
            s16x8 bf = *reinterpret_cast<const s16x8*>(s_b + bb);
            acc[ct] = __builtin_amdgcn_mfma_f32_16x16x32_bf16(af, bf, acc[ct], 0, 0, 0);
        }
        __syncthreads();
        if (ks < 7) {
            #pragma unroll
            for (int i = 0; i < 4; ++i) {
                int off = wv * 4096 + i * 1024;
                gload16(wb + (size_t)(ks + 1) * 16384 + off + l * 16, s_b + off);
            }
            __syncthreads();
        }
    }

    const int rbase = row0 + wv * 16 + (l >> 4) * 4;
    const int cb = l & 15;
    #pragma unroll
    for (int ct = 0; ct < 16; ++ct) {
        #pragma unroll
        for (int r = 0; r < 4; ++r) {
            int row = rbase + r;
            if (row < n_rows)
                out[(size_t)row * D + ct * 16 + cb] = fmaxf(acc[ct][r], 0.f);
        }
    }
}

__global__ __launch_bounds__(256) void gemm_mfma(const unsigned short* __restrict__ wTs,
                                                 float* __restrict__ out, int n_rows) {
    __shared__ __align__(16) unsigned char s_a[BM * 512];
    __shared__ __align__(16) unsigned char s_b[16384];
    const int t = threadIdx.x;
    const int row0 = blockIdx.x * BM;
    const int wv = t >> 6;
    const int l = t & 63;
    const char* wb = reinterpret_cast<const char*>(wTs);

    #pragma unroll
    for (int i = 0; i < 4; ++i) {
        int off = wv * 4096 + i * 1024;
        gload16(wb + off + l * 16, s_b + off);
    }
    #pragma unroll
    for (int i = 0; i < 16; ++i) {
        int f4 = t + 256 * i;
        int row = f4 >> 6;
        int kc = f4 & 63;
        int grow = row0 + row;
        if (grow >= n_rows) grow = n_rows - 1;
        float4 v = *reinterpret_cast<const float4*>(out + (size_t)grow * D + kc * 4);
        uint2 u;
        u.x = f2bf(v.x) | (f2bf(v.y) << 16);
        u.y = f2bf(v.z) | (f2bf(v.w) << 16);
        int byte = (row * 512 + kc * 8) ^ ((row & 7) << 4);
        *reinterpret_cast<uint2*>(s_a + byte) = u;
    }
    __syncthreads();

    f32x4 acc[16];
    #pragma unroll
    for (int ct = 0; ct < 16; ++ct) acc[ct] = (f32x4){0.f, 0.f, 0.f, 0.f};

    const int lr = wv * 16 + (l & 15);
    const int g = l >> 4;
    for (int ks = 0; ks < 8; ++ks) {
        const int kb = ks * 32 + g * 8;
        const int ab = (lr * 512 + kb * 2) ^ ((lr & 7) << 4);
        s16x8 af = *reinterpret_cast<const s16x8*>(s_a + ab);
        #pragma unroll
        for (int ct = 0; ct < 16; ++ct) {
            int col = ct * 16 + (l & 15);
            int bb = (col * 64 + g * 16) ^ ((col & 7) << 4);
            s16x8 bf = *reinterpret_cast<const s16x8*>(s_b + bb);
            acc[ct] = __builtin_amdgcn_mfma_f32_16x16x32_bf16(af, bf, acc[ct], 0, 0, 0);
        }
        __syncthreads();
        if (ks < 7) {
            #pragma unroll
            for (int i = 0; i < 4; ++i) {
                int off = wv * 4096 + i * 1024;
                gload16(wb + (size_t)(ks + 1) * 16384 + off + l * 16, s_b + off);
            }
            __syncthreads();
        }
    }

    const int rbase = row0 + wv * 16 + (l >> 4) * 4;
    const int cb = l & 15;
    #pragma unroll
    for (int ct = 0; ct < 16; ++ct) {
        #pragma unroll
        for (int r = 0; r < 4; ++r) {
            int row = rbase + r;
            if (row < n_rows)
                out[(size_t)row * D + ct * 16 + cb] = fmaxf(acc[ct][r], 0.f);
        }
    }
}

// legacy fp32 GEMM (no-workspace fallback)
__global__ __launch_bounds__(256) void gemm_relu(const float* __restrict__ Wm,
                                                 float* __restrict__ out, int n_rows) {
    __shared__ float s_a[32][D];
    const int row0 = blockIdx.x * 32;
    const int c = threadIdx.x;
    {
        const float4* gsrc = reinterpret_cast<const float4*>(out + (size_t)row0 * D);
        float4* ldst = reinterpret_cast<float4*>(&s_a[0][0]);
        #pragma unroll
        for (int i = 0; i < 8; ++i)
            ldst[threadIdx.x + i * 256] = gsrc[threadIdx.x + i * 256];
    }
    __syncthreads();
    float acc[32];
    #pragma unroll
    for (int r = 0; r < 32; ++r) acc[r] = 0.f;
    #pragma unroll 4
    for (int k = 0; k < D; ++k) {
        float w = Wm[(size_t)k * D + c];
        #pragma unroll
        for (int r = 0; r < 32; ++r) acc[r] += s_a[r][k] * w;
    }
    #pragma unroll
    for (int r = 0; r < 32; ++r) {
        int row = row0 + r;
        if (row < n_rows) out[(size_t)row * D + c] = fmaxf(acc[r], 0.f);
    }
}

extern "C" void kernel_launch(void* const* d_in, const int* in_sizes, int n_in,
                              void* d_out, int out_size, void* d_ws, size_t ws_size,
                              hipStream_t stream) {
    const float* feat = (const float*)d_in[0];
    const float* W    = (const float*)d_in[1];
    const int*   src  = (const int*)d_in[2];
    const int*   dst  = (const int*)d_in[3];
    float* out = (float*)d_out;

    const int N = in_sizes[0] / D;  // 100000
    const int E = in_sizes[2];      // 1600000
    const int Npad = ((N + BM - 1) / BM) * BM;
    auto al = [](size_t x) { return (x + 255) & ~(size_t)255; };

    const int nranges = (N + RN - 1) / RN;   // 3125
    const int gemm_blocks = (N + BM - 1) / BM;
    const int gat_blocks = (N + 3) / 4;

    // ---- tier A2 layout: gcur | ovf_cnt | ovf | streams | featb | wTs
    const size_t hdr_bytes   = ((size_t)nranges + 1 + 2 * MAXOVF) * 4;
    const size_t strm_off    = al(hdr_bytes);
    const size_t strm_sz     = (size_t)nranges * SCAP * 4;
    const size_t a2_featb_off = al(strm_off + strm_sz);
    const size_t featb_sz    = (size_t)N * D * 2;
    const size_t a2_wt_off   = al(a2_featb_off + featb_sz);
    const size_t wt_sz       = (size_t)D * D * 2;
    const size_t need_A2     = a2_wt_off + wt_sz;

    // ---- fallback tier layouts
    const size_t cap_bytes = ((size_t)N + 1 + 2 * MAXOVF + (size_t)N * CAP) * 4;
    const size_t featb_off = al(cap_bytes);
    const size_t wt_off    = al(featb_off + featb_sz);
    const size_t aggb_off  = al(wt_off + wt_sz);
    const size_t aggb_sz   = (size_t)Npad * D * 2;
    const size_t need_A    = aggb_off + aggb_sz;

    if (ws_size >= need_A2 && nranges <= NRANGES_MAX) {
        char* base = (char*)d_ws;
        int* gcur    = (int*)base;
        int* ovf_cnt = gcur + nranges;
        int* ovf     = ovf_cnt + 1;
        int* streams = (int*)(base + strm_off);
        unsigned short* featb = (unsigned short*)(base + a2_featb_off);
        unsigned short* wTs   = (unsigned short*)(base + a2_wt_off);

        k_pre<<<2048, 256, 0, stream>>>(feat, featb, W, wTs, gcur, nranges + 1,
                                        (long)N * D / 8);
        k_part<<<(E + PCH - 1) / PCH, PTH, 0, stream>>>(src, dst, gcur, streams,
                                                        ovf, ovf_cnt, E, nranges);
        k_sgg<<<nranges, SGT, 0, stream>>>(featb, gcur, streams, ovf, ovf_cnt,
                                           wTs, out, N);
    } else if (ws_size >= need_A) {
        char* base = (char*)d_ws;
        int* counts  = (int*)base;
        int* ovf_cnt = counts + N;
        int* ovf     = ovf_cnt + 1;
        int* buckets = ovf + 2 * MAXOVF;
        unsigned short* featb = (unsigned short*)(base + featb_off);
        unsigned short* wTs   = (unsigned short*)(base + wt_off);
        unsigned short* aggb  = (unsigned short*)(base + aggb_off);

        k_zero<<<(N + 1 + 255) / 256, 256, 0, stream>>>(counts, N + 1);
        k_f2b<<<2048, 256, 0, stream>>>(feat, featb, (long)N * D / 8);
        k_wTs<<<D, 256, 0, stream>>>(W, wTs);
        k_fillcap<<<2048, 256, 0, stream>>>(src, dst, counts, buckets, ovf, ovf_cnt, E);
        g_bf_aggb<<<gat_blocks, 256, 0, stream>>>(featb, counts, buckets, ovf, ovf_cnt, aggb, N);
        gemm_mfma_b<<<gemm_blocks, 256, 0, stream>>>(aggb, wTs, out, N);
    } else if (ws_size >= cap_bytes) {
        char* base = (char*)d_ws;
        int* counts  = (int*)base;
        int* ovf_cnt = counts + N;
        int* ovf     = ovf_cnt + 1;
        int* buckets = ovf + 2 * MAXOVF;
        unsigned short* wTs = (unsigned short*)(((uintptr_t)buckets + 255) & ~(uintptr_t)255);

        k_zero<<<(N + 1 + 255) / 256, 256, 0, stream>>>(counts, N + 1);
        k_fillcap<<<2048, 256, 0, stream>>>(src, dst, counts, buckets, ovf, ovf_cnt, E);
        g_f32_out<<<gat_blocks, 256, 0, stream>>>(feat, counts, buckets, ovf, ovf_cnt, out, N);
        k_wTs<<<D, 256, 0, stream>>>(W, wTs);
        gemm_mfma<<<gemm_blocks, 256, 0, stream>>>(wTs, out, N);
    } else {
        long n4 = (long)N * D / 4;
        gc_copy<<<(int)((n4 + 255) / 256), 256, 0, stream>>>(feat, out, n4);
        gc_scatter<<<(E + 3) / 4, 256, 0, stream>>>(feat, src, dst, out, E);
        gemm_relu<<<(N + 31) / 32, 256, 0, stream>>>(W, out, N);
    }
}

// Round 14
// 206.374 us; speedup vs baseline: 1.6749x; 1.0297x over previous
//
#include <hip/hip_runtime.h>

#define D 256
#define CAP 32
#define MAXOVF 4096
#define BM 64

// range-partition params
#define RN 32           // nodes per range
#define RSH 5
#define SCAP 1024       // stream capacity per range (mean 512)
#define PCH 8192        // edges per partition block
#define NRANGES_MAX 4096
#define SGT 256         // k_sgg threads (4 waves)
#define NPP 2048        // k_pp grid

typedef float f32x4 __attribute__((ext_vector_type(4)));
typedef short s16x8 __attribute__((ext_vector_type(8)));

__device__ inline unsigned int f2bf(float x) {
    unsigned int u = __float_as_uint(x);
    return (u + 0x7FFFu + ((u >> 16) & 1u)) >> 16;  // RNE, low 16 bits valid
}
__device__ inline float bflo(unsigned int u) { return __uint_as_float(u << 16); }
__device__ inline float bfhi(unsigned int u) { return __uint_as_float(u & 0xFFFF0000u); }

__device__ inline void gload16(const char* g, const unsigned char* lds) {
    __builtin_amdgcn_global_load_lds(
        (const __attribute__((address_space(1))) void*)g,
        (__attribute__((address_space(3))) void*)lds, 16, 0, 0);
}

// ========== merged prologue: partition ∥ wTs ∥ f2b (block-role split) ======
// blocks [0,nparts): edge partition (LDS hist, dense stream appends)
// blocks [nparts, nparts+128): wTs build (2 cols per block)
// blocks [nparts+128, NPP): featb = bf16(feat), grid-strided
__global__ __launch_bounds__(512) void k_pp(const float* __restrict__ feat,
                                            unsigned short* __restrict__ featb,
                                            const float* __restrict__ W,
                                            unsigned short* __restrict__ wTs,
                                            const int* __restrict__ src,
                                            const int* __restrict__ dst,
                                            int* __restrict__ gcur,
                                            int* __restrict__ streams,
                                            int* __restrict__ ovf,
                                            int* __restrict__ ovf_cnt,
                                            int E, int nranges, long n8) {
    __shared__ int hist[NRANGES_MAX];
    __shared__ int base[NRANGES_MAX];
    __shared__ int off[NRANGES_MAX];
    const int bid = blockIdx.x;
    const int t = threadIdx.x;
    const int nparts = (E + PCH - 1) / PCH;

    if (bid < nparts) {
        // ---- partition: 8192 edges, 16/thread ----
        const long e0 = (long)bid * PCH;
        for (int i = t; i < nranges; i += 512) hist[i] = 0;
        __syncthreads();
        int md[PCH / 512], ms[PCH / 512];
        #pragma unroll
        for (int i = 0; i < PCH / 512; ++i) {
            long e = e0 + (long)i * 512 + t;
            if (e < E) {
                md[i] = dst[e];
                ms[i] = src[e];
                atomicAdd(&hist[md[i] >> RSH], 1);
            } else {
                md[i] = -1;
            }
        }
        __syncthreads();
        for (int i = t; i < nranges; i += 512) {
            int h = hist[i];
            base[i] = h ? atomicAdd(&gcur[i], h) : 0;
            off[i] = 0;
        }
        __syncthreads();
        #pragma unroll
        for (int i = 0; i < PCH / 512; ++i) {
            if (md[i] >= 0) {
                int r = md[i] >> RSH;
                int p = base[r] + atomicAdd(&off[r], 1);
                if (p < SCAP) {
                    streams[(size_t)r * SCAP + p] = (ms[i] << RSH) | (md[i] & (RN - 1));
                } else {
                    int o = atomicAdd(ovf_cnt, 1);
                    if (o < MAXOVF) { ovf[2 * o] = ms[i]; ovf[2 * o + 1] = md[i]; }
                }
            }
        }
    } else if (bid < nparts + 128) {
        // ---- wTs: 2 cols per block ----
        int col = (bid - nparts) * 2 + (t >> 8);
        int k = t & 255;
        unsigned short v = (unsigned short)f2bf(W[(size_t)k * D + col]);
        int ks = k >> 5;
        int byte = ((col << 6) + (((k >> 3) & 3) << 4) + ((k & 7) << 1)) ^ ((col & 7) << 4);
        *reinterpret_cast<unsigned short*>(
            reinterpret_cast<char*>(wTs) + (size_t)ks * 16384 + byte) = v;
    } else {
        // ---- f2b over the remaining blocks ----
        const long fbid = bid - nparts - 128;
        const long nfb = NPP - nparts - 128;
        for (long i = fbid * 512 + t; i < n8; i += nfb * 512) {
            const float4* p = reinterpret_cast<const float4*>(feat + i * 8);
            float4 a = p[0], b = p[1];
            uint4 u;
            u.x = f2bf(a.x) | (f2bf(a.y) << 16);
            u.y = f2bf(a.z) | (f2bf(a.w) << 16);
            u.z = f2bf(b.x) | (f2bf(b.y) << 16);
            u.w = f2bf(b.z) | (f2bf(b.w) << 16);
            reinterpret_cast<uint4*>(featb)[i] = u;
        }
    }
}

// ====== phase 2: LDS counting-sort + fused gather + fused MFMA GEMM ======
__global__ __launch_bounds__(SGT) void k_sgg(const unsigned short* __restrict__ featb,
                                             const int* __restrict__ gcur,
                                             const int* __restrict__ streams,
                                             const int* __restrict__ ovf,
                                             const int* __restrict__ ovf_cnt,
                                             const unsigned short* __restrict__ wTs,
                                             float* __restrict__ out, int N) {
    __shared__ int hist[RN], basei[RN], off[RN], scn[RN];
    __shared__ int elist[SCAP];                              // 4 KB
    __shared__ __align__(16) unsigned char s_agg[RN * 512];  // 16 KB
    const int r = blockIdx.x;
    const int t = threadIdx.x;
    const int node0 = r << RSH;
    const int wv = t >> 6;   // 0..3
    const int l = t & 63;
    const char* wb = reinterpret_cast<const char*>(wTs);

    // ---- sort prologue ----
    int cnt = gcur[r];
    if (cnt > SCAP) cnt = SCAP;
    if (t < RN) { hist[t] = 0; off[t] = 0; }
    __syncthreads();
    int ent[SCAP / SGT];
    #pragma unroll
    for (int i = 0; i < SCAP / SGT; ++i) {
        int p = t + i * SGT;
        if (p < cnt) {
            ent[i] = streams[(size_t)r * SCAP + p];
            atomicAdd(&hist[ent[i] & (RN - 1)], 1);
        } else {
            ent[i] = -1;
        }
    }
    __syncthreads();
    if (t < RN) scn[t] = hist[t];
    __syncthreads();
    for (int st = 1; st < RN; st <<= 1) {
        int v = 0;
        if (t < RN && t >= st) v = scn[t - st];
        __syncthreads();
        if (t < RN) scn[t] += v;
        __syncthreads();
    }
    if (t < RN) basei[t] = scn[t] - hist[t];
    __syncthreads();
    #pragma unroll
    for (int i = 0; i < SCAP / SGT; ++i) {
        if (ent[i] >= 0) {
            int ln_ = ent[i] & (RN - 1);
            int p = basei[ln_] + atomicAdd(&off[ln_], 1);
            elist[p] = ent[i] >> RSH;
        }
    }
    __syncthreads();

    // ---- gather into s_agg ----
    int ovfn = *ovf_cnt;
    if (ovfn > MAXOVF) ovfn = MAXOVF;
    for (int k = 0; k < RN / 4; ++k) {
        int ln_ = wv * (RN / 4) + k;
        int node = node0 + ln_;
        unsigned short* rowp = reinterpret_cast<unsigned short*>(s_agg) + ln_ * 256;
        int us = (l * 4) ^ ((ln_ & 7) << 3);
        if (node >= N) {
            uint2 z; z.x = 0; z.y = 0;
            *reinterpret_cast<uint2*>(rowp + us) = z;
            continue;
        }
        int cb = hist[ln_];
        int bb = basei[ln_];
        uint2 u = reinterpret_cast<const uint2*>(featb + (size_t)node * D)[l];
        float4 acc;
        acc.x = bflo(u.x); acc.y = bfhi(u.x); acc.z = bflo(u.y); acc.w = bfhi(u.y);
        int j = 0;
        for (; j + 16 <= cb; j += 16) {
            int s[16];
            #pragma unroll
            for (int q = 0; q < 16; ++q) s[q] = elist[bb + j + q];
            uint2 v[16];
            #pragma unroll
            for (int q = 0; q < 16; ++q)
                v[q] = reinterpret_cast<const uint2*>(featb + (size_t)s[q] * D)[l];
            #pragma unroll
            for (int q = 0; q < 16; ++q) {
                acc.x += bflo(v[q].x); acc.y += bfhi(v[q].x);
                acc.z += bflo(v[q].y); acc.w += bfhi(v[q].y);
            }
        }
        for (; j + 8 <= cb; j += 8) {
            int s[8];
            #pragma unroll
            for (int q = 0; q < 8; ++q) s[q] = elist[bb + j + q];
            uint2 v[8];
            #pragma unroll
            for (int q = 0; q < 8; ++q)
                v[q] = reinterpret_cast<const uint2*>(featb + (size_t)s[q] * D)[l];
            #pragma unroll
            for (int q = 0; q < 8; ++q) {
                acc.x += bflo(v[q].x); acc.y += bfhi(v[q].x);
                acc.z += bflo(v[q].y); acc.w += bfhi(v[q].y);
            }
        }
        for (; j < cb; ++j) {
            uint2 v = reinterpret_cast<const uint2*>(featb + (size_t)elist[bb + j] * D)[l];
            acc.x += bflo(v.x); acc.y += bfhi(v.x);
            acc.z += bflo(v.y); acc.w += bfhi(v.y);
        }
        if (ovfn > 0) {
            for (int e = 0; e < ovfn; ++e) {
                if (ovf[2 * e + 1] == node) {
                    uint2 v = reinterpret_cast<const uint2*>(featb + (size_t)ovf[2 * e] * D)[l];
                    acc.x += bflo(v.x); acc.y += bfhi(v.x);
                    acc.z += bflo(v.y); acc.w += bfhi(v.y);
                }
            }
        }
        uint2 w;
        w.x = f2bf(acc.x) | (f2bf(acc.y) << 16);
        w.y = f2bf(acc.z) | (f2bf(acc.w) << 16);
        *reinterpret_cast<uint2*>(rowp + us) = w;
    }
    __syncthreads();  // s_agg ready; no further barriers

    // ---- fused GEMM: 32 rows x 256 cols, K=256; B direct from L2 ----
    f32x4 acc[2][4];
    #pragma unroll
    for (int rt = 0; rt < 2; ++rt)
        #pragma unroll
        for (int ct = 0; ct < 4; ++ct) acc[rt][ct] = (f32x4){0.f, 0.f, 0.f, 0.f};

    const int g = l >> 4;
    const int cl = l & 15;
    #pragma unroll
    for (int ks = 0; ks < 8; ++ks) {
        const int kb = ks * 32 + g * 8;
        s16x8 bf[4];
        #pragma unroll
        for (int ct = 0; ct < 4; ++ct) {
            int col = wv * 64 + ct * 16 + cl;
            int bb = (col * 64 + g * 16) ^ ((col & 7) << 4);
            bf[ct] = *reinterpret_cast<const s16x8*>(wb + (size_t)ks * 16384 + bb);
        }
        s16x8 af[2];
        #pragma unroll
        for (int rt = 0; rt < 2; ++rt) {
            int lr = rt * 16 + cl;
            int ab = (lr * 512 + kb * 2) ^ ((lr & 7) << 4);
            af[rt] = *reinterpret_cast<const s16x8*>(s_agg + ab);
        }
        #pragma unroll
        for (int ct = 0; ct < 4; ++ct) {
            acc[0][ct] = __builtin_amdgcn_mfma_f32_16x16x32_bf16(af[0], bf[ct], acc[0][ct], 0, 0, 0);
            acc[1][ct] = __builtin_amdgcn_mfma_f32_16x16x32_bf16(af[1], bf[ct], acc[1][ct], 0, 0, 0);
        }
    }

    #pragma unroll
    for (int rt = 0; rt < 2; ++rt) {
        #pragma unroll
        for (int ct = 0; ct < 4; ++ct) {
            #pragma unroll
            for (int rr = 0; rr < 4; ++rr) {
                int row = node0 + rt * 16 + (l >> 4) * 4 + rr;
                int col = wv * 64 + ct * 16 + cl;
                if (row < N)
                    out[(size_t)row * D + col] = fmaxf(acc[rt][ct][rr], 0.f);
            }
        }
    }
}

// ================= fallback tiers (unchanged) =================

__global__ void k_zero(int* __restrict__ p, int n) {
    int i = blockIdx.x * blockDim.x + threadIdx.x;
    if (i < n) p[i] = 0;
}

__global__ __launch_bounds__(256) void k_f2b(const float* __restrict__ f,
                                             unsigned short* __restrict__ fb, long n8) {
    for (long i = blockIdx.x * 256L + threadIdx.x; i < n8; i += (long)gridDim.x * 256) {
        const float4* p = reinterpret_cast<const float4*>(f + i * 8);
        float4 a = p[0], b = p[1];
        uint4 u;
        u.x = f2bf(a.x) | (f2bf(a.y) << 16);
        u.y = f2bf(a.z) | (f2bf(a.w) << 16);
        u.z = f2bf(b.x) | (f2bf(b.y) << 16);
        u.w = f2bf(b.z) | (f2bf(b.w) << 16);
        reinterpret_cast<uint4*>(fb)[i] = u;
    }
}

__global__ __launch_bounds__(256) void k_wTs(const float* __restrict__ W,
                                             unsigned short* __restrict__ wTs) {
    int col = blockIdx.x;
    int k = threadIdx.x;
    unsigned short v = (unsigned short)f2bf(W[(size_t)k * D + col]);
    int ks = k >> 5;
    int byte = ((col << 6) + (((k >> 3) & 3) << 4) + ((k & 7) << 1)) ^ ((col & 7) << 4);
    *reinterpret_cast<unsigned short*>(
        reinterpret_cast<char*>(wTs) + (size_t)ks * 16384 + byte) = v;
}

__global__ void k_fillcap(const int* __restrict__ src, const int* __restrict__ dst,
                          int* __restrict__ counts, int* __restrict__ buckets,
                          int* __restrict__ ovf, int* __restrict__ ovf_cnt, int E) {
    for (int e = blockIdx.x * blockDim.x + threadIdx.x; e < E;
         e += gridDim.x * blockDim.x) {
        int d = dst[e];
        int pos = atomicAdd(&counts[d], 1);
        if (pos < CAP) {
            buckets[(size_t)d * CAP + pos] = src[e];
        } else {
            int o = atomicAdd(ovf_cnt, 1);
            if (o < MAXOVF) {
                ovf[2 * o + 0] = src[e];
                ovf[2 * o + 1] = d;
            }
        }
    }
}

#define GAT_BODY(LOAD, ACCUM)                                                  \
    int j = 0;                                                                 \
    for (; j + 16 <= cnt; j += 16) {                                           \
        int s[16];                                                             \
        _Pragma("unroll") for (int q = 0; q < 16; ++q) s[q] = bk[j + q];       \
        LOAD(16)                                                               \
        ACCUM(16)                                                              \
    }                                                                          \
    for (; j + 8 <= cnt; j += 8) {                                             \
        int s[8];                                                              \
        _Pragma("unroll") for (int q = 0; q < 8; ++q) s[q] = bk[j + q];        \
        LOAD(8)                                                                \
        ACCUM(8)                                                               \
    }

__global__ __launch_bounds__(256) void g_bf_aggb(const unsigned short* __restrict__ fb,
                                                 const int* __restrict__ counts,
                                                 const int* __restrict__ buckets,
                                                 const int* __restrict__ ovf,
                                                 const int* __restrict__ ovf_cnt,
                                                 unsigned short* __restrict__ aggb, int N) {
    int node = (int)((blockIdx.x * (long)blockDim.x + threadIdx.x) >> 6);
    int ln = threadIdx.x & 63;
    if (node >= N) return;
    int cnt_raw = counts[node];
    int cnt = cnt_raw > CAP ? CAP : cnt_raw;
    const int* bk = buckets + (size_t)node * CAP;
    uint2 u = reinterpret_cast<const uint2*>(fb + (size_t)node * D)[ln];
    float4 acc;
    acc.x = bflo(u.x); acc.y = bfhi(u.x); acc.z = bflo(u.y); acc.w = bfhi(u.y);
#define BLOAD(W_)                                                              \
    uint2 v[W_];                                                               \
    _Pragma("unroll") for (int q = 0; q < W_; ++q)                             \
        v[q] = reinterpret_cast<const uint2*>(fb + (size_t)s[q] * D)[ln];
#define BACC(W_)                                                               \
    _Pragma("unroll") for (int q = 0; q < W_; ++q) {                           \
        acc.x += bflo(v[q].x); acc.y += bfhi(v[q].x);                          \
        acc.z += bflo(v[q].y); acc.w += bfhi(v[q].y);                          \
    }
    GAT_BODY(BLOAD, BACC)
    for (; j < cnt; ++j) {
        uint2 v = reinterpret_cast<const uint2*>(fb + (size_t)bk[j] * D)[ln];
        acc.x += bflo(v.x); acc.y += bfhi(v.x);
        acc.z += bflo(v.y); acc.w += bfhi(v.y);
    }
    if (cnt_raw > CAP) {
        int m = *ovf_cnt;
        if (m > MAXOVF) m = MAXOVF;
        for (int e = 0; e < m; ++e) {
            if (ovf[2 * e + 1] == node) {
                uint2 v = reinterpret_cast<const uint2*>(fb + (size_t)ovf[2 * e] * D)[ln];
                acc.x += bflo(v.x); acc.y += bfhi(v.x);
                acc.z += bflo(v.y); acc.w += bfhi(v.y);
            }
        }
    }
    uint2 w;
    w.x = f2bf(acc.x) | (f2bf(acc.y) << 16);
    w.y = f2bf(acc.z) | (f2bf(acc.w) << 16);
    unsigned short* rowp = aggb + (size_t)node * D;
    int us = (ln * 4) ^ ((node & 7) << 3);
    *reinterpret_cast<uint2*>(rowp + us) = w;
}

__global__ __launch_bounds__(256) void g_f32_out(const float* __restrict__ feat,
                                                 const int* __restrict__ counts,
                                                 const int* __restrict__ buckets,
                                                 const int* __restrict__ ovf,
                                                 const int* __restrict__ ovf_cnt,
                                                 float* __restrict__ out, int N) {
    int node = (int)((blockIdx.x * (long)blockDim.x + threadIdx.x) >> 6);
    int ln = threadIdx.x & 63;
    if (node >= N) return;
    int cnt_raw = counts[node];
    int cnt = cnt_raw > CAP ? CAP : cnt_raw;
    const int* bk = buckets + (size_t)node * CAP;
    float4 acc = reinterpret_cast<const float4*>(feat + (size_t)node * D)[ln];
#define FLOAD(W_)                                                              \
    float4 v[W_];                                                              \
    _Pragma("unroll") for (int q = 0; q < W_; ++q)                             \
        v[q] = reinterpret_cast<const float4*>(feat + (size_t)s[q] * D)[ln];
#define FACC(W_)                                                               \
    _Pragma("unroll") for (int q = 0; q < W_; ++q) {                           \
        acc.x += v[q].x; acc.y += v[q].y; acc.z += v[q].z; acc.w += v[q].w;    \
    }
    GAT_BODY(FLOAD, FACC)
    for (; j < cnt; ++j) {
        float4 v = reinterpret_cast<const float4*>(feat + (size_t)bk[j] * D)[ln];
        acc.x += v.x; acc.y += v.y; acc.z += v.z; acc.w += v.w;
    }
    if (cnt_raw > CAP) {
        int m = *ovf_cnt;
        if (m > MAXOVF) m = MAXOVF;
        for (int e = 0; e < m; ++e) {
            if (ovf[2 * e + 1] == node) {
                float4 v = reinterpret_cast<const float4*>(feat + (size_t)ovf[2 * e] * D)[ln];
                acc.x += v.x; acc.y += v.y; acc.z += v.z; acc.w += v.w;
            }
        }
    }
    reinterpret_cast<float4*>(out + (size_t)node * D)[ln] = acc;
}

__global__ __launch_bounds__(256) void gc_copy(const float* __restrict__ feat,
                                               float* __restrict__ agg, long n4) {
    long i = (long)blockIdx.x * blockDim.x + threadIdx.x;
    if (i < n4)
        reinterpret_cast<float4*>(agg)[i] = reinterpret_cast<const float4*>(feat)[i];
}

__global__ __launch_bounds__(256) void gc_scatter(const float* __restrict__ feat,
                                                  const int* __restrict__ src,
                                                  const int* __restrict__ dst,
                                                  float* __restrict__ agg, int n_edges) {
    int wave = (int)((blockIdx.x * (long)blockDim.x + threadIdx.x) >> 6);
    int lane = threadIdx.x & 63;
    if (wave >= n_edges) return;
    int s = src[wave];
    int d = dst[wave];
    const float4 v = reinterpret_cast<const float4*>(feat + (size_t)s * D)[lane];
    float* p = agg + (size_t)d * D + (size_t)lane * 4;
    atomicAdd(p + 0, v.x);
    atomicAdd(p + 1, v.y);
    atomicAdd(p + 2, v.z);
    atomicAdd(p + 3, v.w);
}

__global__ __launch_bounds__(256) void gemm_mfma_b(const unsigned short* __restrict__ aggb,
                                                   const unsigned short* __restrict__ wTs,
                                                   float* __restrict__ out, int n_rows) {
    __shared__ __align__(16) unsigned char s_a[BM * 512];
    __shared__ __align__(16) unsigned char s_b[16384];
    const int t = threadIdx.x;
    const int row0 = blockIdx.x * BM;
    const int wv = t >> 6;
    const int l = t & 63;
    const char* wb = reinterpret_cast<const char*>(wTs);

    const char* gbase = reinterpret_cast<const char*>(aggb) + (size_t)row0 * 512;
    #pragma unroll
    for (int q = 0; q < 8; ++q) {
        int off = wv * 8192 + q * 1024;
        gload16(gbase + off + l * 16, s_a + off);
    }
    #pragma unroll
    for (int i = 0; i < 4; ++i) {
        int off = wv * 4096 + i * 1024;
        gload16(wb + off + l * 16, s_b + off);
    }
    __syncthreads();

    f32x4 acc[16];
    #pragma unroll
    for (int ct = 0; ct < 16; ++ct) acc[ct] = (f32x4){0.f, 0.f, 0.f, 0.f};

    const int lr = wv * 16 + (l & 15);
    const int g = l >> 4;
    for (int ks = 0; ks < 8; ++ks) {
        const int kb = ks * 32 + g * 8;
        const int ab = (lr * 512 + kb * 2) ^ ((lr & 7) << 4);
        s16x8 af = *reinterpret_cast<const s16x8*>(s_a + ab);
        #pragma unroll
        for (int ct = 0; ct < 16; ++ct) {
            int col = ct * 16 + (l & 15);
            int bb = (col * 64 + g * 16) ^ ((col & 7) << 4);
            s16x8 bf = *reinterpret_cast<const s16x8*>(s_b + bb);
            acc[ct] = __builtin_amdgcn_mfma_f32_16x16x32_bf16(af, bf, acc[ct], 0, 0, 0);
        }
        __syncthreads();
        if (ks < 7) {
            #pragma unroll
            for (int i = 0; i < 4; ++i) {
                int off = wv * 4096 + i * 1024;
                gload16(wb + (size_t)(ks + 1) * 16384 + off + l * 16, s_b + off);
            }
            __syncthreads();
        }
    }

    const int rbase = row0 + wv * 16 + (l >> 4) * 4;
    const int cb = l & 15;
    #pragma unroll
    for (int ct = 0; ct < 16; ++ct) {
        #pragma unroll
        for (int r = 0; r < 4; ++r) {
            int row = rbase + r;
            if (row < n_rows)
                out[(size_t)row * D + ct * 16 + cb] = fmaxf(acc[ct][r], 0.f);
        }
    }
}

__global__ __launch_bounds__(256) void gemm_mfma(const unsigned short* __restrict__ wTs,
                                                 float* __restrict__ out, int n_rows) {
    __shared__ __align__(16) unsigned char s_a[BM * 512];
    __shared__ __align__(16) unsigned char s_b[16384];
    const int t = threadIdx.x;
    const int row0 = blockIdx.x * BM;
    const int wv = t >> 6;
    const int l = t & 63;
    const char* wb = reinterpret_cast<const char*>(wTs);

    #pragma unroll
    for (int i = 0; i < 4; ++i) {
        int off = wv * 4096 + i * 1024;
        gload16(wb + off + l * 16, s_b + off);
    }
    #pragma unroll
    for (int i = 0; i < 16; ++i) {
        int f4 = t + 256 * i;
        int row = f4 >> 6;
        int kc = f4 & 63;
        int grow = row0 + row;
        if (grow >= n_rows) grow = n_rows - 1;
        float4 v = *reinterpret_cast<const float4*>(out + (size_t)grow * D + kc * 4);
        uint2 u;
        u.x = f2bf(v.x) | (f2bf(v.y) << 16);
        u.y = f2bf(v.z) | (f2bf(v.w) << 16);
        int byte = (row * 512 + kc * 8) ^ ((row & 7) << 4);
        *reinterpret_cast<uint2*>(s_a + byte) = u;
    }
    __syncthreads();

    f32x4 acc[16];
    #pragma unroll
    for (int ct = 0; ct < 16; ++ct) acc[ct] = (f32x4){0.f, 0.f, 0.f, 0.f};

    const int lr = wv * 16 + (l & 15);
    const int g = l >> 4;
    for (int ks = 0; ks < 8; ++ks) {
        const int kb = ks * 32 + g * 8;
        const int ab = (lr * 512 + kb * 2) ^ ((lr & 7) << 4);
        s16x8 af = *reinterpret_cast<const s16x8*>(s_a + ab);
        #pragma unroll
        for (int ct = 0; ct < 16; ++ct) {
            int col = ct * 16 + (l & 15);
            int bb = (col * 64 + g * 16) ^ ((col & 7) << 4);
            s16x8 bf = *reinterpret_cast<const s16x8*>(s_b + bb);
            acc[ct] = __builtin_amdgcn_mfma_f32_16x16x32_bf16(af, bf, acc[ct], 0, 0, 0);
        }
        __syncthreads();
        if (ks < 7) {
            #pragma unroll
            for (int i = 0; i < 4; ++i) {
                int off = wv * 4096 + i * 1024;
                gload16(wb + (size_t)(ks + 1) * 16384 + off + l * 16, s_b + off);
            }
            __syncthreads();
        }
    }

    const int rbase = row0 + wv * 16 + (l >> 4) * 4;
    const int cb = l & 15;
    #pragma unroll
    for (int ct = 0; ct < 16; ++ct) {
        #pragma unroll
        for (int r = 0; r < 4; ++r) {
            int row = rbase + r;
            if (row < n_rows)
                out[(size_t)row * D + ct * 16 + cb] = fmaxf(acc[ct][r], 0.f);
        }
    }
}

__global__ __launch_bounds__(256) void gemm_relu(const float* __restrict__ Wm,
                                                 float* __restrict__ out, int n_rows) {
    __shared__ float s_a[32][D];
    const int row0 = blockIdx.x * 32;
    const int c = threadIdx.x;
    {
        const float4* gsrc = reinterpret_cast<const float4*>(out + (size_t)row0 * D);
        float4* ldst = reinterpret_cast<float4*>(&s_a[0][0]);
        #pragma unroll
        for (int i = 0; i < 8; ++i)
            ldst[threadIdx.x + i * 256] = gsrc[threadIdx.x + i * 256];
    }
    __syncthreads();
    float acc[32];
    #pragma unroll
    for (int r = 0; r < 32; ++r) acc[r] = 0.f;
    #pragma unroll 4
    for (int k = 0; k < D; ++k) {
        float w = Wm[(size_t)k * D + c];
        #pragma unroll
        for (int r = 0; r < 32; ++r) acc[r] += s_a[r][k] * w;
    }
    #pragma unroll
    for (int r = 0; r < 32; ++r) {
        int row = row0 + r;
        if (row < n_rows) out[(size_t)row * D + c] = fmaxf(acc[r], 0.f);
    }
}

extern "C" void kernel_launch(void* const* d_in, const int* in_sizes, int n_in,
                              void* d_out, int out_size, void* d_ws, size_t ws_size,
                              hipStream_t stream) {
    const float* feat = (const float*)d_in[0];
    const float* W    = (const float*)d_in[1];
    const int*   src  = (const int*)d_in[2];
    const int*   dst  = (const int*)d_in[3];
    float* out = (float*)d_out;

    const int N = in_sizes[0] / D;  // 100000
    const int E = in_sizes[2];      // 1600000
    const int Npad = ((N + BM - 1) / BM) * BM;
    auto al = [](size_t x) { return (x + 255) & ~(size_t)255; };

    const int nranges = (N + RN - 1) / RN;   // 3125
    const int nparts = (E + PCH - 1) / PCH;  // 196
    const int gemm_blocks = (N + BM - 1) / BM;
    const int gat_blocks = (N + 3) / 4;

    // ---- tier A2 layout: gcur | ovf_cnt | ovf | streams | featb | wTs
    const size_t hdr_bytes   = ((size_t)nranges + 1 + 2 * MAXOVF) * 4;
    const size_t strm_off    = al(hdr_bytes);
    const size_t strm_sz     = (size_t)nranges * SCAP * 4;
    const size_t a2_featb_off = al(strm_off + strm_sz);
    const size_t featb_sz    = (size_t)N * D * 2;
    const size_t a2_wt_off   = al(a2_featb_off + featb_sz);
    const size_t wt_sz       = (size_t)D * D * 2;
    const size_t need_A2     = a2_wt_off + wt_sz;

    // ---- fallback tier layouts
    const size_t cap_bytes = ((size_t)N + 1 + 2 * MAXOVF + (size_t)N * CAP) * 4;
    const size_t featb_off = al(cap_bytes);
    const size_t wt_off    = al(featb_off + featb_sz);
    const size_t aggb_off  = al(wt_off + wt_sz);
    const size_t aggb_sz   = (size_t)Npad * D * 2;
    const size_t need_A    = aggb_off + aggb_sz;

    if (ws_size >= need_A2 && nranges <= NRANGES_MAX &&
        nparts + 128 + 256 <= NPP) {
        char* base = (char*)d_ws;
        int* gcur    = (int*)base;
        int* ovf_cnt = gcur + nranges;
        int* ovf     = ovf_cnt + 1;
        int* streams = (int*)(base + strm_off);
        unsigned short* featb = (unsigned short*)(base + a2_featb_off);
        unsigned short* wTs   = (unsigned short*)(base + a2_wt_off);

        hipMemsetAsync(gcur, 0, ((size_t)nranges + 1) * 4, stream);
        k_pp<<<NPP, 512, 0, stream>>>(feat, featb, W, wTs, src, dst, gcur,
                                      streams, ovf, ovf_cnt, E, nranges,
                                      (long)N * D / 8);
        k_sgg<<<nranges, SGT, 0, stream>>>(featb, gcur, streams, ovf, ovf_cnt,
                                           wTs, out, N);
    } else if (ws_size >= need_A) {
        char* base = (char*)d_ws;
        int* counts  = (int*)base;
        int* ovf_cnt = counts + N;
        int* ovf     = ovf_cnt + 1;
        int* buckets = ovf + 2 * MAXOVF;
        unsigned short* featb = (unsigned short*)(base + featb_off);
        unsigned short* wTs   = (unsigned short*)(base + wt_off);
        unsigned short* aggb  = (unsigned short*)(base + aggb_off);

        k_zero<<<(N + 1 + 255) / 256, 256, 0, stream>>>(counts, N + 1);
        k_f2b<<<2048, 256, 0, stream>>>(feat, featb, (long)N * D / 8);
        k_wTs<<<D, 256, 0, stream>>>(W, wTs);
        k_fillcap<<<2048, 256, 0, stream>>>(src, dst, counts, buckets, ovf, ovf_cnt, E);
        g_bf_aggb<<<gat_blocks, 256, 0, stream>>>(featb, counts, buckets, ovf, ovf_cnt, aggb, N);
        gemm_mfma_b<<<gemm_blocks, 256, 0, stream>>>(aggb, wTs, out, N);
    } else if (ws_size >= cap_bytes) {
        char* base = (char*)d_ws;
        int* counts  = (int*)base;
        int* ovf_cnt = counts + N;
        int* ovf     = ovf_cnt + 1;
        int* buckets = ovf + 2 * MAXOVF;
        unsigned short* wTs = (unsigned short*)(((uintptr_t)buckets + 255) & ~(uintptr_t)255);

        k_zero<<<(N + 1 + 255) / 256, 256, 0, stream>>>(counts, N + 1);
        k_fillcap<<<2048, 256, 0, stream>>>(src, dst, counts, buckets, ovf, ovf_cnt, E);
        g_f32_out<<<gat_blocks, 256, 0, stream>>>(feat, counts, buckets, ovf, ovf_cnt, out, N);
        k_wTs<<<D, 256, 0, stream>>>(W, wTs);
        gemm_mfma<<<gemm_blocks, 256, 0, stream>>>(wTs, out, N);
    } else {
        long n4 = (long)N * D / 4;
        gc_copy<<<(int)((n4 + 255) / 256), 256, 0, stream>>>(feat, out, n4);
        gc_scatter<<<(E + 3) / 4, 256, 0, stream>>>(feat, src, dst, out, E);
        gemm_relu<<<(N + 31) / 32, 256, 0, stream>>>(W, out, N);
    }
}